// Round 1
// baseline (1448.457 us; speedup 1.0000x reference)
//
#include <hip/hip_runtime.h>
#include <hip/hip_bf16.h>
#include <math.h>

// Problem constants
#define MM 2048        // B*W flattened rows
#define BATCH 2
#define SEQ 1024
#define DMODEL 512
#define DINNER 1024
#define DSTATE 16
#define DTRANK 32
#define DFF 2048

// ---------------------------------------------------------------------------
// Generic fp32 GEMM: C[M,N] = epi(A[M,K] @ W[N,K]^T + bias)
// Requires M%64==0, N%64==0, K%16==0 (all shapes here satisfy this).
// EPI: 0=none, 1=relu, 2=softplus
// ---------------------------------------------------------------------------
template<int EPI>
__global__ __launch_bounds__(256) void gemm_kernel(
    int M, int N, int K,
    const float* __restrict__ A, int lda,
    const float* __restrict__ B, int ldb,
    const float* __restrict__ bias,
    float* __restrict__ C, int ldc)
{
    __shared__ float As[16][64];
    __shared__ float Bs[16][64];
    const int tid = threadIdx.x;
    const int tx = tid & 15, ty = tid >> 4;
    const int bm = blockIdx.y * 64, bn = blockIdx.x * 64;
    const int lm = tid & 63;        // loader row within tile
    const int lk = (tid >> 6) * 4;  // loader k offset: 0,4,8,12
    const float* Arow = A + (size_t)(bm + lm) * lda + lk;
    const float* Brow = B + (size_t)(bn + lm) * ldb + lk;
    float acc[4][4] = {};
    for (int k0 = 0; k0 < K; k0 += 16) {
        float4 av = *(const float4*)(Arow + k0);
        float4 bv = *(const float4*)(Brow + k0);
        __syncthreads();
        As[lk+0][lm] = av.x; As[lk+1][lm] = av.y; As[lk+2][lm] = av.z; As[lk+3][lm] = av.w;
        Bs[lk+0][lm] = bv.x; Bs[lk+1][lm] = bv.y; Bs[lk+2][lm] = bv.z; Bs[lk+3][lm] = bv.w;
        __syncthreads();
        #pragma unroll
        for (int k = 0; k < 16; ++k) {
            float4 a = *(const float4*)(&As[k][ty*4]);
            float4 b = *(const float4*)(&Bs[k][tx*4]);
            float ar[4] = {a.x,a.y,a.z,a.w};
            float br[4] = {b.x,b.y,b.z,b.w};
            #pragma unroll
            for (int i = 0; i < 4; ++i)
                #pragma unroll
                for (int j = 0; j < 4; ++j)
                    acc[i][j] = fmaf(ar[i], br[j], acc[i][j]);
        }
    }
    const int row0 = bm + ty*4, col0 = bn + tx*4;
    #pragma unroll
    for (int i = 0; i < 4; ++i) {
        float4 o;
        float v[4];
        #pragma unroll
        for (int j = 0; j < 4; ++j) {
            float t = acc[i][j];
            if (bias) t += bias[col0 + j];
            if (EPI == 1) t = fmaxf(t, 0.f);
            if (EPI == 2) t = fmaxf(t, 0.f) + log1pf(__expf(-fabsf(t)));
            v[j] = t;
        }
        o.x = v[0]; o.y = v[1]; o.z = v[2]; o.w = v[3];
        *(float4*)(C + (size_t)(row0 + i) * ldc + col0) = o;
    }
}

// ---------------------------------------------------------------------------
// Depthwise causal (dir=0) / anti-causal (dir=1) conv over L, + bias + silu.
// xz: [M, 2048] (first 1024 cols are the conv input channel block)
// out xm_act: [M, 1024]
// fwd:  xc[p] = sum_j xm[p-3+j] * Wc[c][j]      (taps p-3..p)
// bwd:  xc[p] = sum_j xm[p+3-j] * Wc[c][j]      (taps p..p+3, reversed kernel)
// ---------------------------------------------------------------------------
__global__ __launch_bounds__(256) void conv_silu_kernel(
    const float* __restrict__ xz,
    const float* __restrict__ convW,
    const float* __restrict__ convb,
    float* __restrict__ xm_act,
    int dir)
{
    int gid = blockIdx.x * 256 + threadIdx.x;   // over M*1024
    int c = gid & (DINNER - 1);
    int m = gid >> 10;
    int b = m >> 10;           // SEQ = 1024
    int l = m & (SEQ - 1);
    float4 wv = *(const float4*)(convW + c * 4);
    float w[4] = {wv.x, wv.y, wv.z, wv.w};
    float acc = convb[c];
    #pragma unroll
    for (int j = 0; j < 4; ++j) {
        int p = dir ? (l + 3 - j) : (l - 3 + j);
        if (p >= 0 && p < SEQ)
            acc = fmaf(xz[(size_t)(b * SEQ + p) * 2048 + c], w[j], acc);
    }
    float sig = 1.f / (1.f + __expf(-acc));
    xm_act[(size_t)m * DINNER + c] = acc * sig;
}

// ---------------------------------------------------------------------------
// Selective scan, both directions. Thread = (channel d, state s).
// Block: 256 threads = 16 channels x 16 states. Grid: (64, B, 2dirs).
// Fuses dA/dBu computation, recurrence, y = sum_s h*C, +xm*D, *silu(z).
// ---------------------------------------------------------------------------
__global__ __launch_bounds__(256) void scan_kernel(
    const float* __restrict__ delta_f, const float* __restrict__ delta_b,
    const float* __restrict__ xm_f,    const float* __restrict__ xm_b,
    const float* __restrict__ dbc_f,   const float* __restrict__ dbc_b,
    const float* __restrict__ xz_f,    const float* __restrict__ xz_b,
    const float* __restrict__ fA_log,  const float* __restrict__ bA_log,
    const float* __restrict__ fD,      const float* __restrict__ bD,
    float* __restrict__ y_f,           float* __restrict__ y_b)
{
    const int tid = threadIdx.x;
    const int s = tid & 15;
    const int dloc = tid >> 4;
    const int d = blockIdx.x * 16 + dloc;
    const int b = blockIdx.y;
    const int dir = blockIdx.z;

    const float* delta = dir ? delta_b : delta_f;
    const float* xm    = dir ? xm_b    : xm_f;
    const float* dbc   = dir ? dbc_b   : dbc_f;
    const float* xz    = dir ? xz_b    : xz_f;
    const float* Alog  = dir ? bA_log  : fA_log;
    const float* Dv    = dir ? bD      : fD;
    float* yout        = dir ? y_b     : y_f;

    const float A  = -__expf(Alog[d * DSTATE + s]);
    const float Dp = Dv[d];
    float h = 0.f;

    for (int i = 0; i < SEQ; ++i) {
        const int lt = dir ? (SEQ - 1 - i) : i;
        const size_t m = (size_t)b * SEQ + lt;
        float dl = delta[m * DINNER + d];
        float xv = xm[m * DINNER + d];
        float Bv = dbc[m * 64 + DTRANK + s];
        float Cv = dbc[m * 64 + DTRANK + DSTATE + s];
        float dA = __expf(dl * A);
        h = fmaf(dA, h, dl * Bv * xv);
        float part = h * Cv;
        part += __shfl_xor(part, 1);
        part += __shfl_xor(part, 2);
        part += __shfl_xor(part, 4);
        part += __shfl_xor(part, 8);
        if (s == 0) {
            float z = xz[m * 2048 + DINNER + d];
            float sig = 1.f / (1.f + __expf(-z));
            float yv = part + xv * Dp;
            yout[m * DINNER + d] = yv * (z * sig);
        }
    }
}

// ---------------------------------------------------------------------------
// out[m,:] = LN(xf+pf; g1,b1) + LN(xf+pb; g2,b2), feature dim 512.
// One block per row, 256 threads x 2 features each.
// ---------------------------------------------------------------------------
__global__ __launch_bounds__(256) void ln_combine_kernel(
    const float* __restrict__ xf,
    const float* __restrict__ pf, const float* __restrict__ pb,
    const float* __restrict__ g1, const float* __restrict__ b1,
    const float* __restrict__ g2, const float* __restrict__ b2,
    float* __restrict__ out)
{
    const int m = blockIdx.x;
    const int tid = threadIdx.x;
    const float* xr = xf + (size_t)m * DMODEL;
    const float* p1 = pf + (size_t)m * DMODEL;
    const float* p2 = pb + (size_t)m * DMODEL;
    float v1a = xr[tid] + p1[tid];
    float v1b = xr[tid + 256] + p1[tid + 256];
    float v2a = xr[tid] + p2[tid];
    float v2b = xr[tid + 256] + p2[tid + 256];
    float s1 = v1a + v1b, q1 = v1a*v1a + v1b*v1b;
    float s2 = v2a + v2b, q2 = v2a*v2a + v2b*v2b;
    #pragma unroll
    for (int off = 32; off; off >>= 1) {
        s1 += __shfl_xor(s1, off); q1 += __shfl_xor(q1, off);
        s2 += __shfl_xor(s2, off); q2 += __shfl_xor(q2, off);
    }
    __shared__ float sm[4][4];
    const int w = tid >> 6;
    if ((tid & 63) == 0) { sm[w][0] = s1; sm[w][1] = q1; sm[w][2] = s2; sm[w][3] = q2; }
    __syncthreads();
    s1 = sm[0][0] + sm[1][0] + sm[2][0] + sm[3][0];
    q1 = sm[0][1] + sm[1][1] + sm[2][1] + sm[3][1];
    s2 = sm[0][2] + sm[1][2] + sm[2][2] + sm[3][2];
    q2 = sm[0][3] + sm[1][3] + sm[2][3] + sm[3][3];
    const float inv = 1.f / DMODEL;
    float mu1 = s1 * inv, mu2 = s2 * inv;
    float rs1 = rsqrtf(q1 * inv - mu1 * mu1 + 1e-5f);
    float rs2 = rsqrtf(q2 * inv - mu2 * mu2 + 1e-5f);
    float* orow = out + (size_t)m * DMODEL;
    orow[tid]       = (v1a - mu1) * rs1 * g1[tid]       + b1[tid]
                    + (v2a - mu2) * rs2 * g2[tid]       + b2[tid];
    orow[tid + 256] = (v1b - mu1) * rs1 * g1[tid + 256] + b1[tid + 256]
                    + (v2b - mu2) * rs2 * g2[tid + 256] + b2[tid + 256];
}

// ---------------------------------------------------------------------------
// out[m,:] = LN(2*ff[m,:]; g,b)   (ff+ff in the reference)
// ---------------------------------------------------------------------------
__global__ __launch_bounds__(256) void ln_final_kernel(
    const float* __restrict__ ff,
    const float* __restrict__ g, const float* __restrict__ b,
    float* __restrict__ out)
{
    const int m = blockIdx.x;
    const int tid = threadIdx.x;
    const float* fr = ff + (size_t)m * DMODEL;
    float va = 2.f * fr[tid];
    float vb = 2.f * fr[tid + 256];
    float s = va + vb, q = va*va + vb*vb;
    #pragma unroll
    for (int off = 32; off; off >>= 1) {
        s += __shfl_xor(s, off); q += __shfl_xor(q, off);
    }
    __shared__ float sm[4][2];
    const int w = tid >> 6;
    if ((tid & 63) == 0) { sm[w][0] = s; sm[w][1] = q; }
    __syncthreads();
    s = sm[0][0] + sm[1][0] + sm[2][0] + sm[3][0];
    q = sm[0][1] + sm[1][1] + sm[2][1] + sm[3][1];
    const float inv = 1.f / DMODEL;
    float mu = s * inv;
    float rs = rsqrtf(q * inv - mu * mu + 1e-5f);
    float* orow = out + (size_t)m * DMODEL;
    orow[tid]       = (va - mu) * rs * g[tid]       + b[tid];
    orow[tid + 256] = (vb - mu) * rs * g[tid + 256] + b[tid + 256];
}

// ---------------------------------------------------------------------------
extern "C" void kernel_launch(void* const* d_in, const int* in_sizes, int n_in,
                              void* d_out, int out_size, void* d_ws, size_t ws_size,
                              hipStream_t stream)
{
    const float* x         = (const float*)d_in[0];
    const float* fm_in_W   = (const float*)d_in[1];
    const float* fm_conv_W = (const float*)d_in[2];
    const float* fm_conv_b = (const float*)d_in[3];
    const float* fm_xproj_W= (const float*)d_in[4];
    const float* fm_dt_W   = (const float*)d_in[5];
    const float* fm_dt_b   = (const float*)d_in[6];
    const float* fm_A_log  = (const float*)d_in[7];
    const float* fm_D      = (const float*)d_in[8];
    const float* fm_out_W  = (const float*)d_in[9];
    const float* bm_in_W   = (const float*)d_in[10];
    const float* bm_conv_W = (const float*)d_in[11];
    const float* bm_conv_b = (const float*)d_in[12];
    const float* bm_xproj_W= (const float*)d_in[13];
    const float* bm_dt_W   = (const float*)d_in[14];
    const float* bm_dt_b   = (const float*)d_in[15];
    const float* bm_A_log  = (const float*)d_in[16];
    const float* bm_D      = (const float*)d_in[17];
    const float* bm_out_W  = (const float*)d_in[18];
    const float* ln1_g     = (const float*)d_in[19];
    const float* ln1_b     = (const float*)d_in[20];
    const float* ln2_g     = (const float*)d_in[21];
    const float* ln2_b     = (const float*)d_in[22];
    const float* ln3_g     = (const float*)d_in[23];
    const float* ln3_b     = (const float*)d_in[24];
    const float* ff_W1     = (const float*)d_in[25];
    const float* ff_b1     = (const float*)d_in[26];
    const float* ff_W2     = (const float*)d_in[27];
    const float* ff_b2     = (const float*)d_in[28];
    float* out = (float*)d_out;

    // Workspace layout (floats). h_ff / ff2 reuse the xz regions (dead after scan).
    float* ws = (float*)d_ws;
    float* xz_f   = ws;                          // M*2048
    float* xz_b   = xz_f   + (size_t)MM * 2048;  // M*2048
    float* xm_f   = xz_b   + (size_t)MM * 2048;  // M*1024
    float* xm_b   = xm_f   + (size_t)MM * DINNER;
    float* delta_f= xm_b   + (size_t)MM * DINNER;
    float* delta_b= delta_f+ (size_t)MM * DINNER;
    float* y_f    = delta_b+ (size_t)MM * DINNER;
    float* y_b    = y_f    + (size_t)MM * DINNER;
    float* dbc_f  = y_b    + (size_t)MM * DINNER; // M*64
    float* dbc_b  = dbc_f  + (size_t)MM * 64;
    float* proj_f = dbc_b  + (size_t)MM * 64;     // M*512
    float* proj_b = proj_f + (size_t)MM * DMODEL;
    float* outsum = proj_b + (size_t)MM * DMODEL;
    float* h_ff   = xz_f;   // reuse: M*2048
    float* ff2    = xz_b;   // reuse: M*512

    // 1. in-proj GEMMs (no flip needed: GEMM commutes with flip)
    gemm_kernel<0><<<dim3(2048/64, MM/64), 256, 0, stream>>>(
        MM, 2048, DMODEL, x, DMODEL, fm_in_W, DMODEL, nullptr, xz_f, 2048);
    gemm_kernel<0><<<dim3(2048/64, MM/64), 256, 0, stream>>>(
        MM, 2048, DMODEL, x, DMODEL, bm_in_W, DMODEL, nullptr, xz_b, 2048);

    // 2. depthwise conv + silu (causal fwd, anti-causal bwd)
    conv_silu_kernel<<<(MM * DINNER) / 256, 256, 0, stream>>>(
        xz_f, fm_conv_W, fm_conv_b, xm_f, 0);
    conv_silu_kernel<<<(MM * DINNER) / 256, 256, 0, stream>>>(
        xz_b, bm_conv_W, bm_conv_b, xm_b, 1);

    // 3. x-proj: dbc = xm @ xproj_W^T  [M,64]
    gemm_kernel<0><<<dim3(64/64, MM/64), 256, 0, stream>>>(
        MM, 64, DINNER, xm_f, DINNER, fm_xproj_W, DINNER, nullptr, dbc_f, 64);
    gemm_kernel<0><<<dim3(64/64, MM/64), 256, 0, stream>>>(
        MM, 64, DINNER, xm_b, DINNER, bm_xproj_W, DINNER, nullptr, dbc_b, 64);

    // 4. delta = softplus(dt @ dt_W^T + dt_b)  [M,1024]
    gemm_kernel<2><<<dim3(DINNER/64, MM/64), 256, 0, stream>>>(
        MM, DINNER, DTRANK, dbc_f, 64, fm_dt_W, DTRANK, fm_dt_b, delta_f, DINNER);
    gemm_kernel<2><<<dim3(DINNER/64, MM/64), 256, 0, stream>>>(
        MM, DINNER, DTRANK, dbc_b, 64, bm_dt_W, DTRANK, bm_dt_b, delta_b, DINNER);

    // 5. selective scan (both dirs), fused y-epilogue
    scan_kernel<<<dim3(DINNER/16, BATCH, 2), 256, 0, stream>>>(
        delta_f, delta_b, xm_f, xm_b, dbc_f, dbc_b, xz_f, xz_b,
        fm_A_log, bm_A_log, fm_D, bm_D, y_f, y_b);

    // 6. out-proj GEMMs [M,512]
    gemm_kernel<0><<<dim3(DMODEL/64, MM/64), 256, 0, stream>>>(
        MM, DMODEL, DINNER, y_f, DINNER, fm_out_W, DINNER, nullptr, proj_f, DMODEL);
    gemm_kernel<0><<<dim3(DMODEL/64, MM/64), 256, 0, stream>>>(
        MM, DMODEL, DINNER, y_b, DINNER, bm_out_W, DINNER, nullptr, proj_b, DMODEL);

    // 7. out = LN(xf+fwd) + LN(xf+bwd)
    ln_combine_kernel<<<MM, 256, 0, stream>>>(
        x, proj_f, proj_b, ln1_g, ln1_b, ln2_g, ln2_b, outsum);

    // 8. FF: h = relu(out @ W1^T + b1); ff2 = h @ W2^T + b2
    gemm_kernel<1><<<dim3(DFF/64, MM/64), 256, 0, stream>>>(
        MM, DFF, DMODEL, outsum, DMODEL, ff_W1, DMODEL, ff_b1, h_ff, DFF);
    gemm_kernel<0><<<dim3(DMODEL/64, MM/64), 256, 0, stream>>>(
        MM, DMODEL, DFF, h_ff, DFF, ff_W2, DFF, ff_b2, ff2, DMODEL);

    // 9. final LN(2*ff)
    ln_final_kernel<<<MM, 256, 0, stream>>>(ff2, ln3_g, ln3_b, out);
}

// Round 2
// 838.056 us; speedup vs baseline: 1.7284x; 1.7284x over previous
//
#include <hip/hip_runtime.h>
#include <hip/hip_bf16.h>
#include <math.h>

// Problem constants
#define MM 2048        // B*W flattened rows
#define BATCH 2
#define SEQ 1024
#define DMODEL 512
#define DINNER 1024
#define DSTATE 16
#define DTRANK 32
#define DFF 2048

// Chunked-scan constants
#define NCHUNK 16
#define CHUNK 64            // SEQ / NCHUNK
#define UNR 8               // load-prefetch unroll inside a chunk
#define GTOT 65536          // 2 dirs * BATCH * DINNER * DSTATE

// ---------------------------------------------------------------------------
// Generic fp32 GEMM: C[M,N] = epi(A[M,K] @ W[N,K]^T + bias)
// Requires M%64==0, N%64==0, K%16==0 (all shapes here satisfy this).
// EPI: 0=none, 1=relu, 2=softplus
// ---------------------------------------------------------------------------
template<int EPI>
__global__ __launch_bounds__(256) void gemm_kernel(
    int M, int N, int K,
    const float* __restrict__ A, int lda,
    const float* __restrict__ B, int ldb,
    const float* __restrict__ bias,
    float* __restrict__ C, int ldc)
{
    __shared__ float As[16][64];
    __shared__ float Bs[16][64];
    const int tid = threadIdx.x;
    const int tx = tid & 15, ty = tid >> 4;
    const int bm = blockIdx.y * 64, bn = blockIdx.x * 64;
    const int lm = tid & 63;        // loader row within tile
    const int lk = (tid >> 6) * 4;  // loader k offset: 0,4,8,12
    const float* Arow = A + (size_t)(bm + lm) * lda + lk;
    const float* Brow = B + (size_t)(bn + lm) * ldb + lk;
    float acc[4][4] = {};
    for (int k0 = 0; k0 < K; k0 += 16) {
        float4 av = *(const float4*)(Arow + k0);
        float4 bv = *(const float4*)(Brow + k0);
        __syncthreads();
        As[lk+0][lm] = av.x; As[lk+1][lm] = av.y; As[lk+2][lm] = av.z; As[lk+3][lm] = av.w;
        Bs[lk+0][lm] = bv.x; Bs[lk+1][lm] = bv.y; Bs[lk+2][lm] = bv.z; Bs[lk+3][lm] = bv.w;
        __syncthreads();
        #pragma unroll
        for (int k = 0; k < 16; ++k) {
            float4 a = *(const float4*)(&As[k][ty*4]);
            float4 b = *(const float4*)(&Bs[k][tx*4]);
            float ar[4] = {a.x,a.y,a.z,a.w};
            float br[4] = {b.x,b.y,b.z,b.w};
            #pragma unroll
            for (int i = 0; i < 4; ++i)
                #pragma unroll
                for (int j = 0; j < 4; ++j)
                    acc[i][j] = fmaf(ar[i], br[j], acc[i][j]);
        }
    }
    const int row0 = bm + ty*4, col0 = bn + tx*4;
    #pragma unroll
    for (int i = 0; i < 4; ++i) {
        float4 o;
        float v[4];
        #pragma unroll
        for (int j = 0; j < 4; ++j) {
            float t = acc[i][j];
            if (bias) t += bias[col0 + j];
            if (EPI == 1) t = fmaxf(t, 0.f);
            if (EPI == 2) t = fmaxf(t, 0.f) + log1pf(__expf(-fabsf(t)));
            v[j] = t;
        }
        o.x = v[0]; o.y = v[1]; o.z = v[2]; o.w = v[3];
        *(float4*)(C + (size_t)(row0 + i) * ldc + col0) = o;
    }
}

// ---------------------------------------------------------------------------
// Depthwise causal (dir=0) / anti-causal (dir=1) conv over L, + bias + silu.
// ---------------------------------------------------------------------------
__global__ __launch_bounds__(256) void conv_silu_kernel(
    const float* __restrict__ xz,
    const float* __restrict__ convW,
    const float* __restrict__ convb,
    float* __restrict__ xm_act,
    int dir)
{
    int gid = blockIdx.x * 256 + threadIdx.x;   // over M*1024
    int c = gid & (DINNER - 1);
    int m = gid >> 10;
    int b = m >> 10;           // SEQ = 1024
    int l = m & (SEQ - 1);
    float4 wv = *(const float4*)(convW + c * 4);
    float w[4] = {wv.x, wv.y, wv.z, wv.w};
    float acc = convb[c];
    #pragma unroll
    for (int j = 0; j < 4; ++j) {
        int p = dir ? (l + 3 - j) : (l - 3 + j);
        if (p >= 0 && p < SEQ)
            acc = fmaf(xz[(size_t)(b * SEQ + p) * 2048 + c], w[j], acc);
    }
    float sig = 1.f / (1.f + __expf(-acc));
    xm_act[(size_t)m * DINNER + c] = acc * sig;
}

// ---------------------------------------------------------------------------
// Chunked selective scan, phase 1: per-chunk (P = prod dA, Hl = local scan).
// Block: 256 = 16 channels x 16 states. Grid: (DINNER/16, BATCH*NCHUNK, 2).
// ---------------------------------------------------------------------------
__global__ __launch_bounds__(256) void scan_phase1_kernel(
    const float* __restrict__ delta_f, const float* __restrict__ delta_b,
    const float* __restrict__ xm_f,    const float* __restrict__ xm_b,
    const float* __restrict__ dbc_f,   const float* __restrict__ dbc_b,
    const float* __restrict__ fA_log,  const float* __restrict__ bA_log,
    float* __restrict__ Pout, float* __restrict__ Hout)
{
    const int tid = threadIdx.x;
    const int s = tid & 15;
    const int dloc = tid >> 4;
    const int d = blockIdx.x * 16 + dloc;
    const int b = blockIdx.y / NCHUNK;
    const int c = blockIdx.y % NCHUNK;
    const int dir = blockIdx.z;

    const float* delta = dir ? delta_b : delta_f;
    const float* xm    = dir ? xm_b    : xm_f;
    const float* dbc   = dir ? dbc_b   : dbc_f;
    const float* Alog  = dir ? bA_log  : fA_log;

    const float A = -__expf(Alog[d * DSTATE + s]);
    float h = 0.f, Pacc = 1.f;
    const int i0 = c * CHUNK;
    for (int ii = 0; ii < CHUNK; ii += UNR) {
        float dl[UNR], xv[UNR], Bv[UNR];
        #pragma unroll
        for (int u = 0; u < UNR; ++u) {
            int i = i0 + ii + u;
            int lt = dir ? (SEQ - 1 - i) : i;
            size_t m = (size_t)b * SEQ + lt;
            dl[u] = delta[m * DINNER + d];
            xv[u] = xm[m * DINNER + d];
            Bv[u] = dbc[m * 64 + DTRANK + s];
        }
        #pragma unroll
        for (int u = 0; u < UNR; ++u) {
            float dA = __expf(dl[u] * A);
            Pacc *= dA;
            h = fmaf(dA, h, dl[u] * Bv[u] * xv[u]);
        }
    }
    const int g = ((dir * BATCH + b) * DINNER + d) * DSTATE + s;
    Pout[(size_t)c * GTOT + g] = Pacc;
    Hout[(size_t)c * GTOT + g] = h;
}

// ---------------------------------------------------------------------------
// Phase 2: sequential combine over chunks -> carry (h entering each chunk).
// One thread per (dir,b,d,s) = GTOT threads.
// ---------------------------------------------------------------------------
__global__ __launch_bounds__(256) void scan_carry_kernel(
    const float* __restrict__ P, const float* __restrict__ H,
    float* __restrict__ carry)
{
    const int g = blockIdx.x * 256 + threadIdx.x;
    float h = 0.f;
    #pragma unroll
    for (int c = 0; c < NCHUNK; ++c) {
        carry[(size_t)c * GTOT + g] = h;
        h = fmaf(P[(size_t)c * GTOT + g], h, H[(size_t)c * GTOT + g]);
    }
}

// ---------------------------------------------------------------------------
// Phase 3: rescan each chunk from its carry, fused y = sum_s h*C, +xm*D,
// *silu(z) epilogue. Same grid as phase 1.
// ---------------------------------------------------------------------------
__global__ __launch_bounds__(256) void scan_phase3_kernel(
    const float* __restrict__ delta_f, const float* __restrict__ delta_b,
    const float* __restrict__ xm_f,    const float* __restrict__ xm_b,
    const float* __restrict__ dbc_f,   const float* __restrict__ dbc_b,
    const float* __restrict__ xz_f,    const float* __restrict__ xz_b,
    const float* __restrict__ fA_log,  const float* __restrict__ bA_log,
    const float* __restrict__ fD,      const float* __restrict__ bD,
    const float* __restrict__ carry,
    float* __restrict__ y_f,           float* __restrict__ y_b)
{
    const int tid = threadIdx.x;
    const int s = tid & 15;
    const int dloc = tid >> 4;
    const int d = blockIdx.x * 16 + dloc;
    const int b = blockIdx.y / NCHUNK;
    const int c = blockIdx.y % NCHUNK;
    const int dir = blockIdx.z;

    const float* delta = dir ? delta_b : delta_f;
    const float* xm    = dir ? xm_b    : xm_f;
    const float* dbc   = dir ? dbc_b   : dbc_f;
    const float* xz    = dir ? xz_b    : xz_f;
    const float* Alog  = dir ? bA_log  : fA_log;
    const float* Dv    = dir ? bD      : fD;
    float* yout        = dir ? y_b     : y_f;

    const float A  = -__expf(Alog[d * DSTATE + s]);
    const float Dp = Dv[d];
    const int g = ((dir * BATCH + b) * DINNER + d) * DSTATE + s;
    float h = carry[(size_t)c * GTOT + g];

    const int i0 = c * CHUNK;
    for (int ii = 0; ii < CHUNK; ii += UNR) {
        float dl[UNR], xv[UNR], Bv[UNR], Cv[UNR], zv[UNR];
        #pragma unroll
        for (int u = 0; u < UNR; ++u) {
            int i = i0 + ii + u;
            int lt = dir ? (SEQ - 1 - i) : i;
            size_t m = (size_t)b * SEQ + lt;
            dl[u] = delta[m * DINNER + d];
            xv[u] = xm[m * DINNER + d];
            Bv[u] = dbc[m * 64 + DTRANK + s];
            Cv[u] = dbc[m * 64 + DTRANK + DSTATE + s];
        }
        if (s == 0) {
            #pragma unroll
            for (int u = 0; u < UNR; ++u) {
                int i = i0 + ii + u;
                int lt = dir ? (SEQ - 1 - i) : i;
                size_t m = (size_t)b * SEQ + lt;
                zv[u] = xz[m * 2048 + DINNER + d];
            }
        }
        #pragma unroll
        for (int u = 0; u < UNR; ++u) {
            float dA = __expf(dl[u] * A);
            h = fmaf(dA, h, dl[u] * Bv[u] * xv[u]);
            float part = h * Cv[u];
            part += __shfl_xor(part, 1);
            part += __shfl_xor(part, 2);
            part += __shfl_xor(part, 4);
            part += __shfl_xor(part, 8);
            if (s == 0) {
                int i = i0 + ii + u;
                int lt = dir ? (SEQ - 1 - i) : i;
                size_t m = (size_t)b * SEQ + lt;
                float z = zv[u];
                float sig = 1.f / (1.f + __expf(-z));
                float yv = part + xv[u] * Dp;
                yout[m * DINNER + d] = yv * (z * sig);
            }
        }
    }
}

// ---------------------------------------------------------------------------
// out[m,:] = LN(xf+pf; g1,b1) + LN(xf+pb; g2,b2), feature dim 512.
// ---------------------------------------------------------------------------
__global__ __launch_bounds__(256) void ln_combine_kernel(
    const float* __restrict__ xf,
    const float* __restrict__ pf, const float* __restrict__ pb,
    const float* __restrict__ g1, const float* __restrict__ b1,
    const float* __restrict__ g2, const float* __restrict__ b2,
    float* __restrict__ out)
{
    const int m = blockIdx.x;
    const int tid = threadIdx.x;
    const float* xr = xf + (size_t)m * DMODEL;
    const float* p1 = pf + (size_t)m * DMODEL;
    const float* p2 = pb + (size_t)m * DMODEL;
    float v1a = xr[tid] + p1[tid];
    float v1b = xr[tid + 256] + p1[tid + 256];
    float v2a = xr[tid] + p2[tid];
    float v2b = xr[tid + 256] + p2[tid + 256];
    float s1 = v1a + v1b, q1 = v1a*v1a + v1b*v1b;
    float s2 = v2a + v2b, q2 = v2a*v2a + v2b*v2b;
    #pragma unroll
    for (int off = 32; off; off >>= 1) {
        s1 += __shfl_xor(s1, off); q1 += __shfl_xor(q1, off);
        s2 += __shfl_xor(s2, off); q2 += __shfl_xor(q2, off);
    }
    __shared__ float sm[4][4];
    const int w = tid >> 6;
    if ((tid & 63) == 0) { sm[w][0] = s1; sm[w][1] = q1; sm[w][2] = s2; sm[w][3] = q2; }
    __syncthreads();
    s1 = sm[0][0] + sm[1][0] + sm[2][0] + sm[3][0];
    q1 = sm[0][1] + sm[1][1] + sm[2][1] + sm[3][1];
    s2 = sm[0][2] + sm[1][2] + sm[2][2] + sm[3][2];
    q2 = sm[0][3] + sm[1][3] + sm[2][3] + sm[3][3];
    const float inv = 1.f / DMODEL;
    float mu1 = s1 * inv, mu2 = s2 * inv;
    float rs1 = rsqrtf(q1 * inv - mu1 * mu1 + 1e-5f);
    float rs2 = rsqrtf(q2 * inv - mu2 * mu2 + 1e-5f);
    float* orow = out + (size_t)m * DMODEL;
    orow[tid]       = (v1a - mu1) * rs1 * g1[tid]       + b1[tid]
                    + (v2a - mu2) * rs2 * g2[tid]       + b2[tid];
    orow[tid + 256] = (v1b - mu1) * rs1 * g1[tid + 256] + b1[tid + 256]
                    + (v2b - mu2) * rs2 * g2[tid + 256] + b2[tid + 256];
}

// ---------------------------------------------------------------------------
// out[m,:] = LN(2*ff[m,:]; g,b)
// ---------------------------------------------------------------------------
__global__ __launch_bounds__(256) void ln_final_kernel(
    const float* __restrict__ ff,
    const float* __restrict__ g, const float* __restrict__ b,
    float* __restrict__ out)
{
    const int m = blockIdx.x;
    const int tid = threadIdx.x;
    const float* fr = ff + (size_t)m * DMODEL;
    float va = 2.f * fr[tid];
    float vb = 2.f * fr[tid + 256];
    float s = va + vb, q = va*va + vb*vb;
    #pragma unroll
    for (int off = 32; off; off >>= 1) {
        s += __shfl_xor(s, off); q += __shfl_xor(q, off);
    }
    __shared__ float sm[4][2];
    const int w = tid >> 6;
    if ((tid & 63) == 0) { sm[w][0] = s; sm[w][1] = q; }
    __syncthreads();
    s = sm[0][0] + sm[1][0] + sm[2][0] + sm[3][0];
    q = sm[0][1] + sm[1][1] + sm[2][1] + sm[3][1];
    const float inv = 1.f / DMODEL;
    float mu = s * inv;
    float rs = rsqrtf(q * inv - mu * mu + 1e-5f);
    float* orow = out + (size_t)m * DMODEL;
    orow[tid]       = (va - mu) * rs * g[tid]       + b[tid];
    orow[tid + 256] = (vb - mu) * rs * g[tid + 256] + b[tid + 256];
}

// ---------------------------------------------------------------------------
extern "C" void kernel_launch(void* const* d_in, const int* in_sizes, int n_in,
                              void* d_out, int out_size, void* d_ws, size_t ws_size,
                              hipStream_t stream)
{
    const float* x         = (const float*)d_in[0];
    const float* fm_in_W   = (const float*)d_in[1];
    const float* fm_conv_W = (const float*)d_in[2];
    const float* fm_conv_b = (const float*)d_in[3];
    const float* fm_xproj_W= (const float*)d_in[4];
    const float* fm_dt_W   = (const float*)d_in[5];
    const float* fm_dt_b   = (const float*)d_in[6];
    const float* fm_A_log  = (const float*)d_in[7];
    const float* fm_D      = (const float*)d_in[8];
    const float* fm_out_W  = (const float*)d_in[9];
    const float* bm_in_W   = (const float*)d_in[10];
    const float* bm_conv_W = (const float*)d_in[11];
    const float* bm_conv_b = (const float*)d_in[12];
    const float* bm_xproj_W= (const float*)d_in[13];
    const float* bm_dt_W   = (const float*)d_in[14];
    const float* bm_dt_b   = (const float*)d_in[15];
    const float* bm_A_log  = (const float*)d_in[16];
    const float* bm_D      = (const float*)d_in[17];
    const float* bm_out_W  = (const float*)d_in[18];
    const float* ln1_g     = (const float*)d_in[19];
    const float* ln1_b     = (const float*)d_in[20];
    const float* ln2_g     = (const float*)d_in[21];
    const float* ln2_b     = (const float*)d_in[22];
    const float* ln3_g     = (const float*)d_in[23];
    const float* ln3_b     = (const float*)d_in[24];
    const float* ff_W1     = (const float*)d_in[25];
    const float* ff_b1     = (const float*)d_in[26];
    const float* ff_W2     = (const float*)d_in[27];
    const float* ff_b2     = (const float*)d_in[28];
    float* out = (float*)d_out;

    // Workspace layout (floats).
    float* ws = (float*)d_ws;
    float* xz_f   = ws;                          // M*2048
    float* xz_b   = xz_f   + (size_t)MM * 2048;  // M*2048
    float* xm_f   = xz_b   + (size_t)MM * 2048;  // M*1024
    float* xm_b   = xm_f   + (size_t)MM * DINNER;
    float* delta_f= xm_b   + (size_t)MM * DINNER;
    float* delta_b= delta_f+ (size_t)MM * DINNER;
    float* y_f    = delta_b+ (size_t)MM * DINNER;
    float* y_b    = y_f    + (size_t)MM * DINNER;
    float* dbc_f  = y_b    + (size_t)MM * DINNER; // M*64
    float* dbc_b  = dbc_f  + (size_t)MM * 64;
    float* proj_f = dbc_b  + (size_t)MM * 64;     // M*512
    float* proj_b = proj_f + (size_t)MM * DMODEL;
    float* outsum = proj_b + (size_t)MM * DMODEL;
    float* h_ff   = xz_f;   // reuse: M*2048 (dead after scan)
    float* ff2    = xz_b;   // reuse: M*512
    // Scan scratch reuses proj/outsum regions (dead until after phase 3):
    // NCHUNK*GTOT = 16*65536 = 1,048,576 floats = MM*DMODEL exactly.
    float* scanP  = proj_f;
    float* scanH  = proj_b;
    float* scanCy = outsum;

    // 1. in-proj GEMMs (GEMM commutes with flip)
    gemm_kernel<0><<<dim3(2048/64, MM/64), 256, 0, stream>>>(
        MM, 2048, DMODEL, x, DMODEL, fm_in_W, DMODEL, nullptr, xz_f, 2048);
    gemm_kernel<0><<<dim3(2048/64, MM/64), 256, 0, stream>>>(
        MM, 2048, DMODEL, x, DMODEL, bm_in_W, DMODEL, nullptr, xz_b, 2048);

    // 2. depthwise conv + silu (causal fwd, anti-causal bwd)
    conv_silu_kernel<<<(MM * DINNER) / 256, 256, 0, stream>>>(
        xz_f, fm_conv_W, fm_conv_b, xm_f, 0);
    conv_silu_kernel<<<(MM * DINNER) / 256, 256, 0, stream>>>(
        xz_b, bm_conv_W, bm_conv_b, xm_b, 1);

    // 3. x-proj: dbc = xm @ xproj_W^T  [M,64]
    gemm_kernel<0><<<dim3(64/64, MM/64), 256, 0, stream>>>(
        MM, 64, DINNER, xm_f, DINNER, fm_xproj_W, DINNER, nullptr, dbc_f, 64);
    gemm_kernel<0><<<dim3(64/64, MM/64), 256, 0, stream>>>(
        MM, 64, DINNER, xm_b, DINNER, bm_xproj_W, DINNER, nullptr, dbc_b, 64);

    // 4. delta = softplus(dt @ dt_W^T + dt_b)  [M,1024]
    gemm_kernel<2><<<dim3(DINNER/64, MM/64), 256, 0, stream>>>(
        MM, DINNER, DTRANK, dbc_f, 64, fm_dt_W, DTRANK, fm_dt_b, delta_f, DINNER);
    gemm_kernel<2><<<dim3(DINNER/64, MM/64), 256, 0, stream>>>(
        MM, DINNER, DTRANK, dbc_b, 64, bm_dt_W, DTRANK, bm_dt_b, delta_b, DINNER);

    // 5. chunked selective scan (both dirs)
    scan_phase1_kernel<<<dim3(DINNER/16, BATCH*NCHUNK, 2), 256, 0, stream>>>(
        delta_f, delta_b, xm_f, xm_b, dbc_f, dbc_b,
        fm_A_log, bm_A_log, scanP, scanH);
    scan_carry_kernel<<<GTOT/256, 256, 0, stream>>>(scanP, scanH, scanCy);
    scan_phase3_kernel<<<dim3(DINNER/16, BATCH*NCHUNK, 2), 256, 0, stream>>>(
        delta_f, delta_b, xm_f, xm_b, dbc_f, dbc_b, xz_f, xz_b,
        fm_A_log, bm_A_log, fm_D, bm_D, scanCy, y_f, y_b);

    // 6. out-proj GEMMs [M,512] (overwrite scanP/scanH — dead now)
    gemm_kernel<0><<<dim3(DMODEL/64, MM/64), 256, 0, stream>>>(
        MM, DMODEL, DINNER, y_f, DINNER, fm_out_W, DINNER, nullptr, proj_f, DMODEL);
    gemm_kernel<0><<<dim3(DMODEL/64, MM/64), 256, 0, stream>>>(
        MM, DMODEL, DINNER, y_b, DINNER, bm_out_W, DINNER, nullptr, proj_b, DMODEL);

    // 7. out = LN(xf+fwd) + LN(xf+bwd) (overwrites scanCy — dead now)
    ln_combine_kernel<<<MM, 256, 0, stream>>>(
        x, proj_f, proj_b, ln1_g, ln1_b, ln2_g, ln2_b, outsum);

    // 8. FF: h = relu(out @ W1^T + b1); ff2 = h @ W2^T + b2
    gemm_kernel<1><<<dim3(DFF/64, MM/64), 256, 0, stream>>>(
        MM, DFF, DMODEL, outsum, DMODEL, ff_W1, DMODEL, ff_b1, h_ff, DFF);
    gemm_kernel<0><<<dim3(DMODEL/64, MM/64), 256, 0, stream>>>(
        MM, DMODEL, DFF, h_ff, DFF, ff_W2, DFF, ff_b2, ff2, DMODEL);

    // 9. final LN(2*ff)
    ln_final_kernel<<<MM, 256, 0, stream>>>(ff2, ln3_g, ln3_b, out);
}

// Round 3
// 542.712 us; speedup vs baseline: 2.6689x; 1.5442x over previous
//
#include <hip/hip_runtime.h>
#include <hip/hip_bf16.h>
#include <math.h>

// Problem constants
#define MM 2048        // B*W flattened rows
#define BATCH 2
#define SEQ 1024
#define DMODEL 512
#define DINNER 1024
#define DSTATE 16
#define DTRANK 32
#define DFF 2048

// Chunked-scan constants
#define NCHUNK 16
#define CHUNK 64
#define UNR 8
#define GTOT 65536          // 2 dirs * BATCH * DINNER * DSTATE

typedef short bf16x8 __attribute__((ext_vector_type(8)));
typedef float floatx4 __attribute__((ext_vector_type(4)));
typedef unsigned short ushort8v __attribute__((ext_vector_type(8)));

__device__ __forceinline__ unsigned short f2bf(float f) {
    union { float f; unsigned u; } v; v.f = f;
    unsigned r = v.u + 0x7FFF + ((v.u >> 16) & 1);
    return (unsigned short)(r >> 16);
}

#define GLOAD_LDS16(gp, lp) __builtin_amdgcn_global_load_lds( \
    (const __attribute__((address_space(1))) unsigned int*)(gp), \
    (__attribute__((address_space(3))) unsigned int*)(lp), 16, 0, 0)

// ---------------------------------------------------------------------------
// bf16 MFMA GEMM: C[M,N] = epi(A[M,K] @ W[N,K]^T + bias)
// A, W bf16; accumulate fp32. 128x128 tile, BK=32, 4 waves x (4x4) 16x16x32.
// EPI: 0=none, 1=relu. OUTBF16: output dtype.
// M%128==0, N%128==0, K%32==0.
// ---------------------------------------------------------------------------
template<int EPI, int OUTBF16>
__global__ __launch_bounds__(256) void gemm_mfma_kernel(
    int M, int N, int K,
    const unsigned short* __restrict__ A, int lda,
    const unsigned short* __restrict__ B, int ldb,
    const float* __restrict__ bias,
    void* __restrict__ Cout, int ldc)
{
    __shared__ unsigned short As[128 * 32];   // [row][k], row stride 32 elems = 64 B
    __shared__ unsigned short Bs[128 * 32];
    const int tid  = threadIdx.x;
    const int wave = tid >> 6;
    const int lane = tid & 63;
    const int bm = blockIdx.y * 128;
    const int bn = blockIdx.x * 128;

    // staging decomposition: wave w, call q in {0,1}: covers rows (w*2+q)*16..+16
    const int strow = lane >> 2;        // 0..15
    const int stk   = (lane & 3) * 8;   // k element offset 0,8,16,24

    // fragment decomposition: wave grid 2x2, each wave does 64x64
    const int wr = wave >> 1, wc = wave & 1;
    const int frow = lane & 15;
    const int fk   = (lane >> 4) * 8;

    floatx4 acc[4][4];
    #pragma unroll
    for (int i = 0; i < 4; ++i)
        #pragma unroll
        for (int j = 0; j < 4; ++j)
            acc[i][j] = (floatx4){0.f, 0.f, 0.f, 0.f};

    for (int k0 = 0; k0 < K; k0 += 32) {
        __syncthreads();   // previous iter's LDS reads complete before overwrite
        #pragma unroll
        for (int q = 0; q < 2; ++q) {
            int r = (wave * 2 + q) * 16 + strow;
            GLOAD_LDS16(A + (size_t)(bm + r) * lda + k0 + stk,
                        As + (wave * 2 + q) * 512);
        }
        #pragma unroll
        for (int q = 0; q < 2; ++q) {
            int r = (wave * 2 + q) * 16 + strow;
            GLOAD_LDS16(B + (size_t)(bn + r) * ldb + k0 + stk,
                        Bs + (wave * 2 + q) * 512);
        }
        __syncthreads();   // staging visible (vmcnt(0) drained before barrier)

        bf16x8 af[4], bfr[4];
        #pragma unroll
        for (int i = 0; i < 4; ++i)
            af[i] = *(const bf16x8*)(As + (wr * 64 + i * 16 + frow) * 32 + fk);
        #pragma unroll
        for (int j = 0; j < 4; ++j)
            bfr[j] = *(const bf16x8*)(Bs + (wc * 64 + j * 16 + frow) * 32 + fk);
        #pragma unroll
        for (int i = 0; i < 4; ++i)
            #pragma unroll
            for (int j = 0; j < 4; ++j)
                acc[i][j] = __builtin_amdgcn_mfma_f32_16x16x32_bf16(
                    af[i], bfr[j], acc[i][j], 0, 0, 0);
    }

    // epilogue: D row=(lane>>4)*4+reg, col=lane&15 within each 16x16 tile
    const int orow0 = bm + wr * 64 + (lane >> 4) * 4;
    const int ocol0 = bn + wc * 64 + (lane & 15);
    #pragma unroll
    for (int j = 0; j < 4; ++j) {
        const int col = ocol0 + j * 16;
        const float bv = bias ? bias[col] : 0.f;
        #pragma unroll
        for (int i = 0; i < 4; ++i) {
            #pragma unroll
            for (int r = 0; r < 4; ++r) {
                int row = orow0 + i * 16 + r;
                float t = acc[i][j][r] + bv;
                if (EPI == 1) t = fmaxf(t, 0.f);
                if (OUTBF16)
                    ((unsigned short*)Cout)[(size_t)row * ldc + col] = f2bf(t);
                else
                    ((float*)Cout)[(size_t)row * ldc + col] = t;
            }
        }
    }
}

// ---------------------------------------------------------------------------
// fp32 GEMM (kept for small shapes): C[M,N] = epi(A @ W^T + bias)
// EPI: 0=none, 2=softplus
// ---------------------------------------------------------------------------
template<int EPI>
__global__ __launch_bounds__(256) void gemm_kernel(
    int M, int N, int K,
    const float* __restrict__ A, int lda,
    const float* __restrict__ B, int ldb,
    const float* __restrict__ bias,
    float* __restrict__ C, int ldc)
{
    __shared__ float As[16][64];
    __shared__ float Bs[16][64];
    const int tid = threadIdx.x;
    const int tx = tid & 15, ty = tid >> 4;
    const int bm = blockIdx.y * 64, bn = blockIdx.x * 64;
    const int lm = tid & 63;
    const int lk = (tid >> 6) * 4;
    const float* Arow = A + (size_t)(bm + lm) * lda + lk;
    const float* Brow = B + (size_t)(bn + lm) * ldb + lk;
    float acc[4][4] = {};
    for (int k0 = 0; k0 < K; k0 += 16) {
        float4 av = *(const float4*)(Arow + k0);
        float4 bv = *(const float4*)(Brow + k0);
        __syncthreads();
        As[lk+0][lm] = av.x; As[lk+1][lm] = av.y; As[lk+2][lm] = av.z; As[lk+3][lm] = av.w;
        Bs[lk+0][lm] = bv.x; Bs[lk+1][lm] = bv.y; Bs[lk+2][lm] = bv.z; Bs[lk+3][lm] = bv.w;
        __syncthreads();
        #pragma unroll
        for (int k = 0; k < 16; ++k) {
            float4 a = *(const float4*)(&As[k][ty*4]);
            float4 b = *(const float4*)(&Bs[k][tx*4]);
            float ar[4] = {a.x,a.y,a.z,a.w};
            float br[4] = {b.x,b.y,b.z,b.w};
            #pragma unroll
            for (int i = 0; i < 4; ++i)
                #pragma unroll
                for (int j = 0; j < 4; ++j)
                    acc[i][j] = fmaf(ar[i], br[j], acc[i][j]);
        }
    }
    const int row0 = bm + ty*4, col0 = bn + tx*4;
    #pragma unroll
    for (int i = 0; i < 4; ++i) {
        float4 o;
        float v[4];
        #pragma unroll
        for (int j = 0; j < 4; ++j) {
            float t = acc[i][j];
            if (bias) t += bias[col0 + j];
            if (EPI == 2) t = fmaxf(t, 0.f) + log1pf(__expf(-fabsf(t)));
            v[j] = t;
        }
        o.x = v[0]; o.y = v[1]; o.z = v[2]; o.w = v[3];
        *(float4*)(C + (size_t)(row0 + i) * ldc + col0) = o;
    }
}

// ---------------------------------------------------------------------------
// fp32 -> bf16 cast, 8 elems/thread. n % 2048 == 0 for all uses.
// ---------------------------------------------------------------------------
__global__ __launch_bounds__(256) void cast_f2b_kernel(
    const float* __restrict__ in, unsigned short* __restrict__ out, int n)
{
    int i = (blockIdx.x * 256 + threadIdx.x) * 8;
    if (i >= n) return;
    float4 a = *(const float4*)(in + i);
    float4 b = *(const float4*)(in + i + 4);
    ushort8v o;
    o[0] = f2bf(a.x); o[1] = f2bf(a.y); o[2] = f2bf(a.z); o[3] = f2bf(a.w);
    o[4] = f2bf(b.x); o[5] = f2bf(b.y); o[6] = f2bf(b.z); o[7] = f2bf(b.w);
    *(ushort8v*)(out + i) = o;
}

// ---------------------------------------------------------------------------
// Depthwise causal (dir=0) / anti-causal (dir=1) conv + bias + silu.
// ---------------------------------------------------------------------------
__global__ __launch_bounds__(256) void conv_silu_kernel(
    const float* __restrict__ xz,
    const float* __restrict__ convW,
    const float* __restrict__ convb,
    float* __restrict__ xm_act,
    int dir)
{
    int gid = blockIdx.x * 256 + threadIdx.x;
    int c = gid & (DINNER - 1);
    int m = gid >> 10;
    int b = m >> 10;
    int l = m & (SEQ - 1);
    float4 wv = *(const float4*)(convW + c * 4);
    float w[4] = {wv.x, wv.y, wv.z, wv.w};
    float acc = convb[c];
    #pragma unroll
    for (int j = 0; j < 4; ++j) {
        int p = dir ? (l + 3 - j) : (l - 3 + j);
        if (p >= 0 && p < SEQ)
            acc = fmaf(xz[(size_t)(b * SEQ + p) * 2048 + c], w[j], acc);
    }
    float sig = 1.f / (1.f + __expf(-acc));
    xm_act[(size_t)m * DINNER + c] = acc * sig;
}

// ---------------------------------------------------------------------------
// Chunked scan phase 1: per-chunk (P = prod dA, H = local scan end state).
// ---------------------------------------------------------------------------
__global__ __launch_bounds__(256) void scan_phase1_kernel(
    const float* __restrict__ delta_f, const float* __restrict__ delta_b,
    const float* __restrict__ xm_f,    const float* __restrict__ xm_b,
    const float* __restrict__ dbc_f,   const float* __restrict__ dbc_b,
    const float* __restrict__ fA_log,  const float* __restrict__ bA_log,
    float* __restrict__ Pout, float* __restrict__ Hout)
{
    const int tid = threadIdx.x;
    const int s = tid & 15;
    const int dloc = tid >> 4;
    const int d = blockIdx.x * 16 + dloc;
    const int b = blockIdx.y / NCHUNK;
    const int c = blockIdx.y % NCHUNK;
    const int dir = blockIdx.z;

    const float* delta = dir ? delta_b : delta_f;
    const float* xm    = dir ? xm_b    : xm_f;
    const float* dbc   = dir ? dbc_b   : dbc_f;
    const float* Alog  = dir ? bA_log  : fA_log;

    const float A = -__expf(Alog[d * DSTATE + s]);
    float h = 0.f, Pacc = 1.f;
    const int i0 = c * CHUNK;
    for (int ii = 0; ii < CHUNK; ii += UNR) {
        float dl[UNR], xv[UNR], Bv[UNR];
        #pragma unroll
        for (int u = 0; u < UNR; ++u) {
            int i = i0 + ii + u;
            int lt = dir ? (SEQ - 1 - i) : i;
            size_t m = (size_t)b * SEQ + lt;
            dl[u] = delta[m * DINNER + d];
            xv[u] = xm[m * DINNER + d];
            Bv[u] = dbc[m * 64 + DTRANK + s];
        }
        #pragma unroll
        for (int u = 0; u < UNR; ++u) {
            float dA = __expf(dl[u] * A);
            Pacc *= dA;
            h = fmaf(dA, h, dl[u] * Bv[u] * xv[u]);
        }
    }
    const int g = ((dir * BATCH + b) * DINNER + d) * DSTATE + s;
    Pout[(size_t)c * GTOT + g] = Pacc;
    Hout[(size_t)c * GTOT + g] = h;
}

// ---------------------------------------------------------------------------
// Phase 2: sequential combine over chunks.
// ---------------------------------------------------------------------------
__global__ __launch_bounds__(256) void scan_carry_kernel(
    const float* __restrict__ P, const float* __restrict__ H,
    float* __restrict__ carry)
{
    const int g = blockIdx.x * 256 + threadIdx.x;
    float h = 0.f;
    #pragma unroll
    for (int c = 0; c < NCHUNK; ++c) {
        carry[(size_t)c * GTOT + g] = h;
        h = fmaf(P[(size_t)c * GTOT + g], h, H[(size_t)c * GTOT + g]);
    }
}

// ---------------------------------------------------------------------------
// Phase 3: rescan from carry, fused y-epilogue, writes y as bf16.
// ---------------------------------------------------------------------------
__global__ __launch_bounds__(256) void scan_phase3_kernel(
    const float* __restrict__ delta_f, const float* __restrict__ delta_b,
    const float* __restrict__ xm_f,    const float* __restrict__ xm_b,
    const float* __restrict__ dbc_f,   const float* __restrict__ dbc_b,
    const float* __restrict__ xz_f,    const float* __restrict__ xz_b,
    const float* __restrict__ fA_log,  const float* __restrict__ bA_log,
    const float* __restrict__ fD,      const float* __restrict__ bD,
    const float* __restrict__ carry,
    unsigned short* __restrict__ y_f,  unsigned short* __restrict__ y_b)
{
    const int tid = threadIdx.x;
    const int s = tid & 15;
    const int dloc = tid >> 4;
    const int d = blockIdx.x * 16 + dloc;
    const int b = blockIdx.y / NCHUNK;
    const int c = blockIdx.y % NCHUNK;
    const int dir = blockIdx.z;

    const float* delta = dir ? delta_b : delta_f;
    const float* xm    = dir ? xm_b    : xm_f;
    const float* dbc   = dir ? dbc_b   : dbc_f;
    const float* xz    = dir ? xz_b    : xz_f;
    const float* Alog  = dir ? bA_log  : fA_log;
    const float* Dv    = dir ? bD      : fD;
    unsigned short* yout = dir ? y_b   : y_f;

    const float A  = -__expf(Alog[d * DSTATE + s]);
    const float Dp = Dv[d];
    const int g = ((dir * BATCH + b) * DINNER + d) * DSTATE + s;
    float h = carry[(size_t)c * GTOT + g];

    const int i0 = c * CHUNK;
    for (int ii = 0; ii < CHUNK; ii += UNR) {
        float dl[UNR], xv[UNR], Bv[UNR], Cv[UNR], zv[UNR];
        #pragma unroll
        for (int u = 0; u < UNR; ++u) {
            int i = i0 + ii + u;
            int lt = dir ? (SEQ - 1 - i) : i;
            size_t m = (size_t)b * SEQ + lt;
            dl[u] = delta[m * DINNER + d];
            xv[u] = xm[m * DINNER + d];
            Bv[u] = dbc[m * 64 + DTRANK + s];
            Cv[u] = dbc[m * 64 + DTRANK + DSTATE + s];
        }
        if (s == 0) {
            #pragma unroll
            for (int u = 0; u < UNR; ++u) {
                int i = i0 + ii + u;
                int lt = dir ? (SEQ - 1 - i) : i;
                size_t m = (size_t)b * SEQ + lt;
                zv[u] = xz[m * 2048 + DINNER + d];
            }
        }
        #pragma unroll
        for (int u = 0; u < UNR; ++u) {
            float dA = __expf(dl[u] * A);
            h = fmaf(dA, h, dl[u] * Bv[u] * xv[u]);
            float part = h * Cv[u];
            part += __shfl_xor(part, 1);
            part += __shfl_xor(part, 2);
            part += __shfl_xor(part, 4);
            part += __shfl_xor(part, 8);
            if (s == 0) {
                int i = i0 + ii + u;
                int lt = dir ? (SEQ - 1 - i) : i;
                size_t m = (size_t)b * SEQ + lt;
                float z = zv[u];
                float sig = 1.f / (1.f + __expf(-z));
                float yv = part + xv[u] * Dp;
                yout[m * DINNER + d] = f2bf(yv * (z * sig));
            }
        }
    }
}

// ---------------------------------------------------------------------------
// out[m,:] = LN(xf+pf; g1,b1) + LN(xf+pb; g2,b2), written as bf16.
// ---------------------------------------------------------------------------
__global__ __launch_bounds__(256) void ln_combine_kernel(
    const float* __restrict__ xf,
    const float* __restrict__ pf, const float* __restrict__ pb,
    const float* __restrict__ g1, const float* __restrict__ b1,
    const float* __restrict__ g2, const float* __restrict__ b2,
    unsigned short* __restrict__ out)
{
    const int m = blockIdx.x;
    const int tid = threadIdx.x;
    const float* xr = xf + (size_t)m * DMODEL;
    const float* p1 = pf + (size_t)m * DMODEL;
    const float* p2 = pb + (size_t)m * DMODEL;
    float v1a = xr[tid] + p1[tid];
    float v1b = xr[tid + 256] + p1[tid + 256];
    float v2a = xr[tid] + p2[tid];
    float v2b = xr[tid + 256] + p2[tid + 256];
    float s1 = v1a + v1b, q1 = v1a*v1a + v1b*v1b;
    float s2 = v2a + v2b, q2 = v2a*v2a + v2b*v2b;
    #pragma unroll
    for (int off = 32; off; off >>= 1) {
        s1 += __shfl_xor(s1, off); q1 += __shfl_xor(q1, off);
        s2 += __shfl_xor(s2, off); q2 += __shfl_xor(q2, off);
    }
    __shared__ float sm[4][4];
    const int w = tid >> 6;
    if ((tid & 63) == 0) { sm[w][0] = s1; sm[w][1] = q1; sm[w][2] = s2; sm[w][3] = q2; }
    __syncthreads();
    s1 = sm[0][0] + sm[1][0] + sm[2][0] + sm[3][0];
    q1 = sm[0][1] + sm[1][1] + sm[2][1] + sm[3][1];
    s2 = sm[0][2] + sm[1][2] + sm[2][2] + sm[3][2];
    q2 = sm[0][3] + sm[1][3] + sm[2][3] + sm[3][3];
    const float inv = 1.f / DMODEL;
    float mu1 = s1 * inv, mu2 = s2 * inv;
    float rs1 = rsqrtf(q1 * inv - mu1 * mu1 + 1e-5f);
    float rs2 = rsqrtf(q2 * inv - mu2 * mu2 + 1e-5f);
    unsigned short* orow = out + (size_t)m * DMODEL;
    orow[tid]       = f2bf((v1a - mu1) * rs1 * g1[tid]       + b1[tid]
                         + (v2a - mu2) * rs2 * g2[tid]       + b2[tid]);
    orow[tid + 256] = f2bf((v1b - mu1) * rs1 * g1[tid + 256] + b1[tid + 256]
                         + (v2b - mu2) * rs2 * g2[tid + 256] + b2[tid + 256]);
}

// ---------------------------------------------------------------------------
// out[m,:] = LN(2*ff[m,:]; g,b)
// ---------------------------------------------------------------------------
__global__ __launch_bounds__(256) void ln_final_kernel(
    const float* __restrict__ ff,
    const float* __restrict__ g, const float* __restrict__ b,
    float* __restrict__ out)
{
    const int m = blockIdx.x;
    const int tid = threadIdx.x;
    const float* fr = ff + (size_t)m * DMODEL;
    float va = 2.f * fr[tid];
    float vb = 2.f * fr[tid + 256];
    float s = va + vb, q = va*va + vb*vb;
    #pragma unroll
    for (int off = 32; off; off >>= 1) {
        s += __shfl_xor(s, off); q += __shfl_xor(q, off);
    }
    __shared__ float sm[4][2];
    const int w = tid >> 6;
    if ((tid & 63) == 0) { sm[w][0] = s; sm[w][1] = q; }
    __syncthreads();
    s = sm[0][0] + sm[1][0] + sm[2][0] + sm[3][0];
    q = sm[0][1] + sm[1][1] + sm[2][1] + sm[3][1];
    const float inv = 1.f / DMODEL;
    float mu = s * inv;
    float rs = rsqrtf(q * inv - mu * mu + 1e-5f);
    float* orow = out + (size_t)m * DMODEL;
    orow[tid]       = (va - mu) * rs * g[tid]       + b[tid];
    orow[tid + 256] = (vb - mu) * rs * g[tid + 256] + b[tid + 256];
}

// ---------------------------------------------------------------------------
extern "C" void kernel_launch(void* const* d_in, const int* in_sizes, int n_in,
                              void* d_out, int out_size, void* d_ws, size_t ws_size,
                              hipStream_t stream)
{
    const float* x         = (const float*)d_in[0];
    const float* fm_in_W   = (const float*)d_in[1];
    const float* fm_conv_W = (const float*)d_in[2];
    const float* fm_conv_b = (const float*)d_in[3];
    const float* fm_xproj_W= (const float*)d_in[4];
    const float* fm_dt_W   = (const float*)d_in[5];
    const float* fm_dt_b   = (const float*)d_in[6];
    const float* fm_A_log  = (const float*)d_in[7];
    const float* fm_D      = (const float*)d_in[8];
    const float* fm_out_W  = (const float*)d_in[9];
    const float* bm_in_W   = (const float*)d_in[10];
    const float* bm_conv_W = (const float*)d_in[11];
    const float* bm_conv_b = (const float*)d_in[12];
    const float* bm_xproj_W= (const float*)d_in[13];
    const float* bm_dt_W   = (const float*)d_in[14];
    const float* bm_dt_b   = (const float*)d_in[15];
    const float* bm_A_log  = (const float*)d_in[16];
    const float* bm_D      = (const float*)d_in[17];
    const float* bm_out_W  = (const float*)d_in[18];
    const float* ln1_g     = (const float*)d_in[19];
    const float* ln1_b     = (const float*)d_in[20];
    const float* ln2_g     = (const float*)d_in[21];
    const float* ln2_b     = (const float*)d_in[22];
    const float* ln3_g     = (const float*)d_in[23];
    const float* ln3_b     = (const float*)d_in[24];
    const float* ff_W1     = (const float*)d_in[25];
    const float* ff_b1     = (const float*)d_in[26];
    const float* ff_W2     = (const float*)d_in[27];
    const float* ff_b2     = (const float*)d_in[28];
    float* out = (float*)d_out;

    // ---- Workspace layout (units: floats) ----
    float* ws = (float*)d_ws;
    float* xz_f   = ws;                           // 4,194,304
    float* xz_b   = xz_f   + (size_t)MM * 2048;   // 4,194,304
    float* xm_f   = xz_b   + (size_t)MM * 2048;   // 2,097,152
    float* xm_b   = xm_f   + (size_t)MM * DINNER;
    float* delta_f= xm_b   + (size_t)MM * DINNER; // 2,097,152
    float* delta_b= delta_f+ (size_t)MM * DINNER;
    float* dbc_f  = delta_b+ (size_t)MM * DINNER; // 131,072
    float* dbc_b  = dbc_f  + (size_t)MM * 64;
    float* scanP  = dbc_b  + (size_t)MM * 64;     // 1,048,576 (later proj_f)
    float* scanH  = scanP  + (size_t)NCHUNK * GTOT; // 1,048,576 (later proj_b)
    float* scanCy = scanH  + (size_t)NCHUNK * GTOT; // 1,048,576 (later ff2)
    float* ybf_f_r= scanCy + (size_t)NCHUNK * GTOT; // 1,048,576 fl (2M bf16)
    float* ybf_b_r= ybf_f_r+ (size_t)MM * DINNER / 2;
    // total: 22.3M floats (< round-2 footprint)

    float* proj_f = scanP;
    float* proj_b = scanH;
    float* ff2    = scanCy;
    unsigned short* ybf_f = (unsigned short*)ybf_f_r;
    unsigned short* ybf_b = (unsigned short*)ybf_b_r;

    // bf16 overlays in dead regions:
    // pre-in-proj casts live in delta_f/delta_b area (written only at step 4)
    unsigned short* x_bf      = (unsigned short*)delta_f;                 // 1,048,576 el
    unsigned short* fm_inW_bf = x_bf + (size_t)MM * DMODEL;               // 1,048,576 el
    unsigned short* bm_inW_bf = fm_inW_bf + (size_t)2048 * DMODEL;        // 1,048,576 el
    // (3,145,728 ushorts = 1,572,864 floats <= delta_f+delta_b = 4,194,304 fl; uses
    //  delta_f fully? 1.57M fl < 2.10M fl -> fits inside delta_f region alone)

    // post-scan casts live in xz_f / xz_b (dead after phase3)
    unsigned short* fm_outW_bf = (unsigned short*)xz_f;                   // 524,288 el
    unsigned short* bm_outW_bf = fm_outW_bf + (size_t)DMODEL * DINNER;    // 524,288 el
    unsigned short* W1_bf      = bm_outW_bf + (size_t)DMODEL * DINNER;    // 1,048,576 el
    unsigned short* W2_bf      = W1_bf + (size_t)DFF * DMODEL;            // 1,048,576 el
    unsigned short* outsum_bf  = W2_bf + (size_t)DMODEL * DFF;            // 1,048,576 el
    unsigned short* h_bf       = (unsigned short*)xz_b;                   // 4,194,304 el

    // ---- 0. bf16 casts for in-proj ----
    cast_f2b_kernel<<<(MM*DMODEL)/2048, 256, 0, stream>>>(x, x_bf, MM*DMODEL);
    cast_f2b_kernel<<<(2048*DMODEL)/2048, 256, 0, stream>>>(fm_in_W, fm_inW_bf, 2048*DMODEL);
    cast_f2b_kernel<<<(2048*DMODEL)/2048, 256, 0, stream>>>(bm_in_W, bm_inW_bf, 2048*DMODEL);

    // ---- 1. in-proj GEMMs (bf16 MFMA, fp32 out) ----
    gemm_mfma_kernel<0,0><<<dim3(2048/128, MM/128), 256, 0, stream>>>(
        MM, 2048, DMODEL, x_bf, DMODEL, fm_inW_bf, DMODEL, nullptr, xz_f, 2048);
    gemm_mfma_kernel<0,0><<<dim3(2048/128, MM/128), 256, 0, stream>>>(
        MM, 2048, DMODEL, x_bf, DMODEL, bm_inW_bf, DMODEL, nullptr, xz_b, 2048);

    // ---- 2. depthwise conv + silu ----
    conv_silu_kernel<<<(MM * DINNER) / 256, 256, 0, stream>>>(
        xz_f, fm_conv_W, fm_conv_b, xm_f, 0);
    conv_silu_kernel<<<(MM * DINNER) / 256, 256, 0, stream>>>(
        xz_b, bm_conv_W, bm_conv_b, xm_b, 1);

    // ---- 3. x-proj (fp32): dbc = xm @ xproj_W^T  [M,64] ----
    gemm_kernel<0><<<dim3(1, MM/64), 256, 0, stream>>>(
        MM, 64, DINNER, xm_f, DINNER, fm_xproj_W, DINNER, nullptr, dbc_f, 64);
    gemm_kernel<0><<<dim3(1, MM/64), 256, 0, stream>>>(
        MM, 64, DINNER, xm_b, DINNER, bm_xproj_W, DINNER, nullptr, dbc_b, 64);

    // ---- 4. delta = softplus(dt @ dt_W^T + dt_b) (fp32) ----
    gemm_kernel<2><<<dim3(DINNER/64, MM/64), 256, 0, stream>>>(
        MM, DINNER, DTRANK, dbc_f, 64, fm_dt_W, DTRANK, fm_dt_b, delta_f, DINNER);
    gemm_kernel<2><<<dim3(DINNER/64, MM/64), 256, 0, stream>>>(
        MM, DINNER, DTRANK, dbc_b, 64, bm_dt_W, DTRANK, bm_dt_b, delta_b, DINNER);

    // ---- 5. chunked selective scan ----
    scan_phase1_kernel<<<dim3(DINNER/16, BATCH*NCHUNK, 2), 256, 0, stream>>>(
        delta_f, delta_b, xm_f, xm_b, dbc_f, dbc_b,
        fm_A_log, bm_A_log, scanP, scanH);
    scan_carry_kernel<<<GTOT/256, 256, 0, stream>>>(scanP, scanH, scanCy);
    scan_phase3_kernel<<<dim3(DINNER/16, BATCH*NCHUNK, 2), 256, 0, stream>>>(
        delta_f, delta_b, xm_f, xm_b, dbc_f, dbc_b, xz_f, xz_b,
        fm_A_log, bm_A_log, fm_D, bm_D, scanCy, ybf_f, ybf_b);

    // ---- 5b. casts for out-proj / FF weights (xz regions now dead) ----
    cast_f2b_kernel<<<(DMODEL*DINNER)/2048, 256, 0, stream>>>(fm_out_W, fm_outW_bf, DMODEL*DINNER);
    cast_f2b_kernel<<<(DMODEL*DINNER)/2048, 256, 0, stream>>>(bm_out_W, bm_outW_bf, DMODEL*DINNER);
    cast_f2b_kernel<<<(DFF*DMODEL)/2048, 256, 0, stream>>>(ff_W1, W1_bf, DFF*DMODEL);
    cast_f2b_kernel<<<(DMODEL*DFF)/2048, 256, 0, stream>>>(ff_W2, W2_bf, DMODEL*DFF);

    // ---- 6. out-proj GEMMs (bf16 MFMA, fp32 out) ----
    gemm_mfma_kernel<0,0><<<dim3(DMODEL/128, MM/128), 256, 0, stream>>>(
        MM, DMODEL, DINNER, ybf_f, DINNER, fm_outW_bf, DINNER, nullptr, proj_f, DMODEL);
    gemm_mfma_kernel<0,0><<<dim3(DMODEL/128, MM/128), 256, 0, stream>>>(
        MM, DMODEL, DINNER, ybf_b, DINNER, bm_outW_bf, DINNER, nullptr, proj_b, DMODEL);

    // ---- 7. out = LN(xf+fwd) + LN(xf+bwd), bf16 out ----
    ln_combine_kernel<<<MM, 256, 0, stream>>>(
        x, proj_f, proj_b, ln1_g, ln1_b, ln2_g, ln2_b, outsum_bf);

    // ---- 8. FF (bf16 MFMA): h = relu(out@W1^T+b1) -> bf16; ff2 = h@W2^T+b2 ----
    gemm_mfma_kernel<1,1><<<dim3(DFF/128, MM/128), 256, 0, stream>>>(
        MM, DFF, DMODEL, outsum_bf, DMODEL, W1_bf, DMODEL, ff_b1, h_bf, DFF);
    gemm_mfma_kernel<0,0><<<dim3(DMODEL/128, MM/128), 256, 0, stream>>>(
        MM, DMODEL, DFF, h_bf, DFF, W2_bf, DFF, ff_b2, ff2, DMODEL);

    // ---- 9. final LN(2*ff) ----
    ln_final_kernel<<<MM, 256, 0, stream>>>(ff2, ln3_g, ln3_b, out);
}

// Round 4
// 486.273 us; speedup vs baseline: 2.9787x; 1.1161x over previous
//
#include <hip/hip_runtime.h>
#include <hip/hip_bf16.h>
#include <math.h>

// Problem constants
#define MM 2048        // B*W flattened rows
#define BATCH 2
#define SEQ 1024
#define DMODEL 512
#define DINNER 1024
#define DSTATE 16
#define DTRANK 32
#define DFF 2048

// Chunked-scan constants
#define NCHUNK 16
#define CHUNK 64
#define GTOT 65536          // 2 dirs * BATCH * DINNER * DSTATE

typedef short bf16x8 __attribute__((ext_vector_type(8)));
typedef float floatx4 __attribute__((ext_vector_type(4)));
typedef unsigned short ushort8v __attribute__((ext_vector_type(8)));

__device__ __forceinline__ unsigned short f2bf(float f) {
    union { float f; unsigned u; } v; v.f = f;
    unsigned r = v.u + 0x7FFF + ((v.u >> 16) & 1);
    return (unsigned short)(r >> 16);
}
__device__ __forceinline__ float bf2f(unsigned short u) {
    union { unsigned u; float f; } v; v.u = ((unsigned)u) << 16; return v.f;
}

#define GLOAD_LDS16(gp, lp) __builtin_amdgcn_global_load_lds( \
    (const __attribute__((address_space(1))) unsigned int*)(gp), \
    (__attribute__((address_space(3))) unsigned int*)(lp), 16, 0, 0)

// ---------------------------------------------------------------------------
// bf16 MFMA GEMM: C[M,N] = epi(A[M,K] @ W[N,K]^T + bias)
// 128x128 tile, BK=32, 4 waves x (4x4) 16x16x32. EPI: 0=none, 1=relu.
// ---------------------------------------------------------------------------
template<int EPI, int OUTBF16>
__global__ __launch_bounds__(256) void gemm_mfma_kernel(
    int M, int N, int K,
    const unsigned short* __restrict__ A, int lda,
    const unsigned short* __restrict__ B, int ldb,
    const float* __restrict__ bias,
    void* __restrict__ Cout, int ldc)
{
    __shared__ unsigned short As[128 * 32];
    __shared__ unsigned short Bs[128 * 32];
    const int tid  = threadIdx.x;
    const int wave = tid >> 6;
    const int lane = tid & 63;
    const int bm = blockIdx.y * 128;
    const int bn = blockIdx.x * 128;

    const int strow = lane >> 2;
    const int stk   = (lane & 3) * 8;
    const int wr = wave >> 1, wc = wave & 1;
    const int frow = lane & 15;
    const int fk   = (lane >> 4) * 8;

    floatx4 acc[4][4];
    #pragma unroll
    for (int i = 0; i < 4; ++i)
        #pragma unroll
        for (int j = 0; j < 4; ++j)
            acc[i][j] = (floatx4){0.f, 0.f, 0.f, 0.f};

    for (int k0 = 0; k0 < K; k0 += 32) {
        __syncthreads();
        #pragma unroll
        for (int q = 0; q < 2; ++q) {
            int r = (wave * 2 + q) * 16 + strow;
            GLOAD_LDS16(A + (size_t)(bm + r) * lda + k0 + stk,
                        As + (wave * 2 + q) * 512);
        }
        #pragma unroll
        for (int q = 0; q < 2; ++q) {
            int r = (wave * 2 + q) * 16 + strow;
            GLOAD_LDS16(B + (size_t)(bn + r) * ldb + k0 + stk,
                        Bs + (wave * 2 + q) * 512);
        }
        __syncthreads();

        bf16x8 af[4], bfr[4];
        #pragma unroll
        for (int i = 0; i < 4; ++i)
            af[i] = *(const bf16x8*)(As + (wr * 64 + i * 16 + frow) * 32 + fk);
        #pragma unroll
        for (int j = 0; j < 4; ++j)
            bfr[j] = *(const bf16x8*)(Bs + (wc * 64 + j * 16 + frow) * 32 + fk);
        #pragma unroll
        for (int i = 0; i < 4; ++i)
            #pragma unroll
            for (int j = 0; j < 4; ++j)
                acc[i][j] = __builtin_amdgcn_mfma_f32_16x16x32_bf16(
                    af[i], bfr[j], acc[i][j], 0, 0, 0);
    }

    const int orow0 = bm + wr * 64 + (lane >> 4) * 4;
    const int ocol0 = bn + wc * 64 + (lane & 15);
    #pragma unroll
    for (int j = 0; j < 4; ++j) {
        const int col = ocol0 + j * 16;
        const float bv = bias ? bias[col] : 0.f;
        #pragma unroll
        for (int i = 0; i < 4; ++i) {
            #pragma unroll
            for (int r = 0; r < 4; ++r) {
                int row = orow0 + i * 16 + r;
                float t = acc[i][j][r] + bv;
                if (EPI == 1) t = fmaxf(t, 0.f);
                if (OUTBF16)
                    ((unsigned short*)Cout)[(size_t)row * ldc + col] = f2bf(t);
                else
                    ((float*)Cout)[(size_t)row * ldc + col] = t;
            }
        }
    }
}

// ---------------------------------------------------------------------------
// xproj MFMA: both dirs in one dispatch. Tile 128(m) x 64(n), K=DINNER.
// Writes dbc[m][64] and dbcT[64][MM].
// ---------------------------------------------------------------------------
__global__ __launch_bounds__(256) void xproj_mfma_kernel(
    const unsigned short* __restrict__ A_f, const unsigned short* __restrict__ A_b,
    const unsigned short* __restrict__ Wf,  const unsigned short* __restrict__ Wb,
    float* __restrict__ dbc_f, float* __restrict__ dbc_b,
    float* __restrict__ dbcT_f, float* __restrict__ dbcT_b)
{
    __shared__ unsigned short As[128 * 32];
    __shared__ unsigned short Bs[64 * 32];
    const int tid = threadIdx.x, wave = tid >> 6, lane = tid & 63;
    const int bm = blockIdx.x * 128;
    const int dir = blockIdx.y;
    const unsigned short* A = dir ? A_b : A_f;
    const unsigned short* W = dir ? Wb  : Wf;
    float* dbc  = dir ? dbc_b  : dbc_f;
    float* dbcT = dir ? dbcT_b : dbcT_f;

    const int strow = lane >> 2;
    const int stk   = (lane & 3) * 8;
    const int frow = lane & 15;
    const int fk   = (lane >> 4) * 8;

    floatx4 acc[2][4];
    #pragma unroll
    for (int i = 0; i < 2; ++i)
        #pragma unroll
        for (int j = 0; j < 4; ++j)
            acc[i][j] = (floatx4){0.f, 0.f, 0.f, 0.f};

    for (int k0 = 0; k0 < DINNER; k0 += 32) {
        __syncthreads();
        #pragma unroll
        for (int q = 0; q < 2; ++q) {
            int r = (wave * 2 + q) * 16 + strow;
            GLOAD_LDS16(A + (size_t)(bm + r) * DINNER + k0 + stk,
                        As + (wave * 2 + q) * 512);
        }
        {
            int r = wave * 16 + strow;
            GLOAD_LDS16(W + (size_t)r * DINNER + k0 + stk, Bs + wave * 512);
        }
        __syncthreads();

        bf16x8 af[2], bfr[4];
        #pragma unroll
        for (int i = 0; i < 2; ++i)
            af[i] = *(const bf16x8*)(As + (wave * 32 + i * 16 + frow) * 32 + fk);
        #pragma unroll
        for (int j = 0; j < 4; ++j)
            bfr[j] = *(const bf16x8*)(Bs + (j * 16 + frow) * 32 + fk);
        #pragma unroll
        for (int i = 0; i < 2; ++i)
            #pragma unroll
            for (int j = 0; j < 4; ++j)
                acc[i][j] = __builtin_amdgcn_mfma_f32_16x16x32_bf16(
                    af[i], bfr[j], acc[i][j], 0, 0, 0);
    }

    const int orow0 = bm + wave * 32 + (lane >> 4) * 4;
    #pragma unroll
    for (int j = 0; j < 4; ++j) {
        const int col = (lane & 15) + j * 16;
        #pragma unroll
        for (int i = 0; i < 2; ++i) {
            #pragma unroll
            for (int r = 0; r < 4; ++r) {
                int row = orow0 + i * 16 + r;
                float t = acc[i][j][r];
                dbc[(size_t)row * 64 + col] = t;
                dbcT[(size_t)col * MM + row] = t;
            }
        }
    }
}

// ---------------------------------------------------------------------------
// fp32 GEMM (dt-proj only): C[M,N] = epi(A[M,K] @ B[N,K]^T + biasR[row])
// EPI: 2=softplus
// ---------------------------------------------------------------------------
template<int EPI>
__global__ __launch_bounds__(256) void gemm_kernel(
    int M, int N, int K,
    const float* __restrict__ A, int lda,
    const float* __restrict__ B, int ldb,
    const float* __restrict__ biasR,
    float* __restrict__ C, int ldc)
{
    __shared__ float As[16][64];
    __shared__ float Bs[16][64];
    const int tid = threadIdx.x;
    const int tx = tid & 15, ty = tid >> 4;
    const int bm = blockIdx.y * 64, bn = blockIdx.x * 64;
    const int lm = tid & 63;
    const int lk = (tid >> 6) * 4;
    const float* Arow = A + (size_t)(bm + lm) * lda + lk;
    const float* Brow = B + (size_t)(bn + lm) * ldb + lk;
    float acc[4][4] = {};
    for (int k0 = 0; k0 < K; k0 += 16) {
        float4 av = *(const float4*)(Arow + k0);
        float4 bv = *(const float4*)(Brow + k0);
        __syncthreads();
        As[lk+0][lm] = av.x; As[lk+1][lm] = av.y; As[lk+2][lm] = av.z; As[lk+3][lm] = av.w;
        Bs[lk+0][lm] = bv.x; Bs[lk+1][lm] = bv.y; Bs[lk+2][lm] = bv.z; Bs[lk+3][lm] = bv.w;
        __syncthreads();
        #pragma unroll
        for (int k = 0; k < 16; ++k) {
            float4 a = *(const float4*)(&As[k][ty*4]);
            float4 b = *(const float4*)(&Bs[k][tx*4]);
            float ar[4] = {a.x,a.y,a.z,a.w};
            float br[4] = {b.x,b.y,b.z,b.w};
            #pragma unroll
            for (int i = 0; i < 4; ++i)
                #pragma unroll
                for (int j = 0; j < 4; ++j)
                    acc[i][j] = fmaf(ar[i], br[j], acc[i][j]);
        }
    }
    const int row0 = bm + ty*4, col0 = bn + tx*4;
    #pragma unroll
    for (int i = 0; i < 4; ++i) {
        float br = biasR ? biasR[row0 + i] : 0.f;
        float4 o;
        float v[4];
        #pragma unroll
        for (int j = 0; j < 4; ++j) {
            float t = acc[i][j] + br;
            if (EPI == 2) t = fmaxf(t, 0.f) + log1pf(__expf(-fabsf(t)));
            v[j] = t;
        }
        o.x = v[0]; o.y = v[1]; o.z = v[2]; o.w = v[3];
        *(float4*)(C + (size_t)(row0 + i) * ldc + col0) = o;
    }
}

// ---------------------------------------------------------------------------
// fp32 -> bf16 cast, 8 elems/thread.
// ---------------------------------------------------------------------------
__global__ __launch_bounds__(256) void cast_f2b_kernel(
    const float* __restrict__ in, unsigned short* __restrict__ out, int n)
{
    int i = (blockIdx.x * 256 + threadIdx.x) * 8;
    if (i >= n) return;
    float4 a = *(const float4*)(in + i);
    float4 b = *(const float4*)(in + i + 4);
    ushort8v o;
    o[0] = f2bf(a.x); o[1] = f2bf(a.y); o[2] = f2bf(a.z); o[3] = f2bf(a.w);
    o[4] = f2bf(b.x); o[5] = f2bf(b.y); o[6] = f2bf(b.z); o[7] = f2bf(b.w);
    *(ushort8v*)(out + i) = o;
}

// ---------------------------------------------------------------------------
// Depthwise conv + bias + silu -> bf16 xm[m][d].
// ---------------------------------------------------------------------------
__global__ __launch_bounds__(256) void conv_silu_kernel(
    const float* __restrict__ xz,
    const float* __restrict__ convW,
    const float* __restrict__ convb,
    unsigned short* __restrict__ xm_bf,
    int dir)
{
    int gid = blockIdx.x * 256 + threadIdx.x;
    int c = gid & (DINNER - 1);
    int m = gid >> 10;
    int b = m >> 10;
    int l = m & (SEQ - 1);
    float4 wv = *(const float4*)(convW + c * 4);
    float w[4] = {wv.x, wv.y, wv.z, wv.w};
    float acc = convb[c];
    #pragma unroll
    for (int j = 0; j < 4; ++j) {
        int p = dir ? (l + 3 - j) : (l - 3 + j);
        if (p >= 0 && p < SEQ)
            acc = fmaf(xz[(size_t)(b * SEQ + p) * 2048 + c], w[j], acc);
    }
    float sig = 1.f / (1.f + __expf(-acc));
    xm_bf[(size_t)m * DINNER + c] = f2bf(acc * sig);
}

// ---------------------------------------------------------------------------
// bf16 transpose: in[R][C] -> out[C][R]. Tile 32x32.
// ---------------------------------------------------------------------------
__global__ __launch_bounds__(256) void transpose_bf16_kernel(
    const unsigned short* __restrict__ in, unsigned short* __restrict__ out,
    int R, int C)
{
    __shared__ unsigned short t[32][34];
    const int c0 = blockIdx.x * 32, r0 = blockIdx.y * 32;
    const int tx = threadIdx.x & 31, ty = threadIdx.x >> 5;
    #pragma unroll
    for (int rr = 0; rr < 32; rr += 8)
        t[ty + rr][tx] = in[(size_t)(r0 + ty + rr) * C + c0 + tx];
    __syncthreads();
    #pragma unroll
    for (int rr = 0; rr < 32; rr += 8)
        out[(size_t)(c0 + ty + rr) * R + r0 + tx] = t[tx][ty + rr];
}

// ---------------------------------------------------------------------------
// Scan phase 1 (templated direction): per-chunk P = prod dA, H = local end h.
// Streams in [channel][time] layout, float4/ushort8 over 8 timesteps.
// ---------------------------------------------------------------------------
template<int DIR>
__global__ __launch_bounds__(256) void scan_phase1_kernel(
    const float* __restrict__ deltaT, const unsigned short* __restrict__ xmT,
    const float* __restrict__ dbcT,   const float* __restrict__ Alog,
    float* __restrict__ Pout, float* __restrict__ Hout)
{
    const int tid = threadIdx.x;
    const int s = tid & 15;
    const int dloc = tid >> 4;
    const int d = blockIdx.x * 16 + dloc;
    const int b = blockIdx.y / NCHUNK;
    const int c = blockIdx.y % NCHUNK;

    const float A = -__expf(Alog[d * DSTATE + s]);
    const float* dRow = deltaT + (size_t)d * MM + b * SEQ;
    const unsigned short* xRow = xmT + (size_t)d * MM + b * SEQ;
    const float* bRow = dbcT + (size_t)(DTRANK + s) * MM + b * SEQ;

    float h = 0.f, P = 1.f;
    const int segBase = DIR ? (SEQ - CHUNK - c * CHUNK) : (c * CHUNK);
    for (int ii = 0; ii < CHUNK; ii += 8) {
        const int off = DIR ? (segBase + (CHUNK - 8) - ii) : (segBase + ii);
        float4 d0 = *(const float4*)(dRow + off);
        float4 d1 = *(const float4*)(dRow + off + 4);
        float4 b0 = *(const float4*)(bRow + off);
        float4 b1 = *(const float4*)(bRow + off + 4);
        ushort8v x8 = *(const ushort8v*)(xRow + off);
        float dl[8] = {d0.x,d0.y,d0.z,d0.w,d1.x,d1.y,d1.z,d1.w};
        float Bv[8] = {b0.x,b0.y,b0.z,b0.w,b1.x,b1.y,b1.z,b1.w};
        #pragma unroll
        for (int u = 0; u < 8; ++u) {
            const int t = DIR ? (7 - u) : u;
            float dA = __expf(dl[t] * A);
            P *= dA;
            h = fmaf(dA, h, dl[t] * Bv[t] * bf2f(x8[t]));
        }
    }
    const int g = ((DIR * BATCH + b) * DINNER + d) * DSTATE + s;
    Pout[(size_t)c * GTOT + g] = P;
    Hout[(size_t)c * GTOT + g] = h;
}

// ---------------------------------------------------------------------------
// Phase 2: sequential combine over chunks.
// ---------------------------------------------------------------------------
__global__ __launch_bounds__(256) void scan_carry_kernel(
    const float* __restrict__ P, const float* __restrict__ H,
    float* __restrict__ carry)
{
    const int g = blockIdx.x * 256 + threadIdx.x;
    float h = 0.f;
    #pragma unroll
    for (int c = 0; c < NCHUNK; ++c) {
        carry[(size_t)c * GTOT + g] = h;
        h = fmaf(P[(size_t)c * GTOT + g], h, H[(size_t)c * GTOT + g]);
    }
}

// ---------------------------------------------------------------------------
// Phase 3: rescan from carry; writes raw y (pre-silu(z)) as fp32 yT[d][m].
// ---------------------------------------------------------------------------
template<int DIR>
__global__ __launch_bounds__(256) void scan_phase3_kernel(
    const float* __restrict__ deltaT, const unsigned short* __restrict__ xmT,
    const float* __restrict__ dbcT,   const float* __restrict__ Alog,
    const float* __restrict__ Dv,     const float* __restrict__ carry,
    float* __restrict__ yT)
{
    const int tid = threadIdx.x;
    const int s = tid & 15;
    const int dloc = tid >> 4;
    const int d = blockIdx.x * 16 + dloc;
    const int b = blockIdx.y / NCHUNK;
    const int c = blockIdx.y % NCHUNK;

    const float A  = -__expf(Alog[d * DSTATE + s]);
    const float Dp = Dv[d];
    const float* dRow = deltaT + (size_t)d * MM + b * SEQ;
    const unsigned short* xRow = xmT + (size_t)d * MM + b * SEQ;
    const float* bRow = dbcT + (size_t)(DTRANK + s) * MM + b * SEQ;
    const float* cRow = dbcT + (size_t)(DTRANK + DSTATE + s) * MM + b * SEQ;
    float* yRow = yT + (size_t)d * MM + b * SEQ;

    const int g = ((DIR * BATCH + b) * DINNER + d) * DSTATE + s;
    float h = carry[(size_t)c * GTOT + g];

    const int segBase = DIR ? (SEQ - CHUNK - c * CHUNK) : (c * CHUNK);
    for (int ii = 0; ii < CHUNK; ii += 8) {
        const int off = DIR ? (segBase + (CHUNK - 8) - ii) : (segBase + ii);
        float4 d0 = *(const float4*)(dRow + off);
        float4 d1 = *(const float4*)(dRow + off + 4);
        float4 b0 = *(const float4*)(bRow + off);
        float4 b1 = *(const float4*)(bRow + off + 4);
        float4 c0 = *(const float4*)(cRow + off);
        float4 c1 = *(const float4*)(cRow + off + 4);
        ushort8v x8 = *(const ushort8v*)(xRow + off);
        float dl[8] = {d0.x,d0.y,d0.z,d0.w,d1.x,d1.y,d1.z,d1.w};
        float Bv[8] = {b0.x,b0.y,b0.z,b0.w,b1.x,b1.y,b1.z,b1.w};
        float Cv[8] = {c0.x,c0.y,c0.z,c0.w,c1.x,c1.y,c1.z,c1.w};
        float yv[8];
        #pragma unroll
        for (int u = 0; u < 8; ++u) {
            const int t = DIR ? (7 - u) : u;
            float xv = bf2f(x8[t]);
            float dA = __expf(dl[t] * A);
            h = fmaf(dA, h, dl[t] * Bv[t] * xv);
            float part = h * Cv[t];
            part += __shfl_xor(part, 1);
            part += __shfl_xor(part, 2);
            part += __shfl_xor(part, 4);
            part += __shfl_xor(part, 8);
            yv[t] = fmaf(xv, Dp, part);
        }
        if (s == 0) {
            *(float4*)(yRow + off)     = (float4){yv[0], yv[1], yv[2], yv[3]};
            *(float4*)(yRow + off + 4) = (float4){yv[4], yv[5], yv[6], yv[7]};
        }
    }
}

// ---------------------------------------------------------------------------
// y_bf[m][d] = f2bf( yT[d][m] * silu(z[m][d]) ), z from xz col 1024+d.
// Fused transpose via LDS tile.
// ---------------------------------------------------------------------------
__global__ __launch_bounds__(256) void y_silu_transpose_kernel(
    const float* __restrict__ yT, const float* __restrict__ xz,
    unsigned short* __restrict__ y_bf)
{
    __shared__ float t[32][33];
    const int m0 = blockIdx.x * 32, d0 = blockIdx.y * 32;
    const int tx = threadIdx.x & 31, ty = threadIdx.x >> 5;
    #pragma unroll
    for (int rr = 0; rr < 32; rr += 8)
        t[ty + rr][tx] = yT[(size_t)(d0 + ty + rr) * MM + m0 + tx];
    __syncthreads();
    #pragma unroll
    for (int rr = 0; rr < 32; rr += 8) {
        int m = m0 + ty + rr, d = d0 + tx;
        float z = xz[(size_t)m * 2048 + DINNER + d];
        float sig = 1.f / (1.f + __expf(-z));
        y_bf[(size_t)m * DINNER + d] = f2bf(t[tx][ty + rr] * (z * sig));
    }
}

// ---------------------------------------------------------------------------
// out[m,:] = LN(xf+pf; g1,b1) + LN(xf+pb; g2,b2), written as bf16.
// ---------------------------------------------------------------------------
__global__ __launch_bounds__(256) void ln_combine_kernel(
    const float* __restrict__ xf,
    const float* __restrict__ pf, const float* __restrict__ pb,
    const float* __restrict__ g1, const float* __restrict__ b1,
    const float* __restrict__ g2, const float* __restrict__ b2,
    unsigned short* __restrict__ out)
{
    const int m = blockIdx.x;
    const int tid = threadIdx.x;
    const float* xr = xf + (size_t)m * DMODEL;
    const float* p1 = pf + (size_t)m * DMODEL;
    const float* p2 = pb + (size_t)m * DMODEL;
    float v1a = xr[tid] + p1[tid];
    float v1b = xr[tid + 256] + p1[tid + 256];
    float v2a = xr[tid] + p2[tid];
    float v2b = xr[tid + 256] + p2[tid + 256];
    float s1 = v1a + v1b, q1 = v1a*v1a + v1b*v1b;
    float s2 = v2a + v2b, q2 = v2a*v2a + v2b*v2b;
    #pragma unroll
    for (int off = 32; off; off >>= 1) {
        s1 += __shfl_xor(s1, off); q1 += __shfl_xor(q1, off);
        s2 += __shfl_xor(s2, off); q2 += __shfl_xor(q2, off);
    }
    __shared__ float sm[4][4];
    const int w = tid >> 6;
    if ((tid & 63) == 0) { sm[w][0] = s1; sm[w][1] = q1; sm[w][2] = s2; sm[w][3] = q2; }
    __syncthreads();
    s1 = sm[0][0] + sm[1][0] + sm[2][0] + sm[3][0];
    q1 = sm[0][1] + sm[1][1] + sm[2][1] + sm[3][1];
    s2 = sm[0][2] + sm[1][2] + sm[2][2] + sm[3][2];
    q2 = sm[0][3] + sm[1][3] + sm[2][3] + sm[3][3];
    const float inv = 1.f / DMODEL;
    float mu1 = s1 * inv, mu2 = s2 * inv;
    float rs1 = rsqrtf(q1 * inv - mu1 * mu1 + 1e-5f);
    float rs2 = rsqrtf(q2 * inv - mu2 * mu2 + 1e-5f);
    unsigned short* orow = out + (size_t)m * DMODEL;
    orow[tid]       = f2bf((v1a - mu1) * rs1 * g1[tid]       + b1[tid]
                         + (v2a - mu2) * rs2 * g2[tid]       + b2[tid]);
    orow[tid + 256] = f2bf((v1b - mu1) * rs1 * g1[tid + 256] + b1[tid + 256]
                         + (v2b - mu2) * rs2 * g2[tid + 256] + b2[tid + 256]);
}

// ---------------------------------------------------------------------------
// out[m,:] = LN(2*ff[m,:]; g,b)
// ---------------------------------------------------------------------------
__global__ __launch_bounds__(256) void ln_final_kernel(
    const float* __restrict__ ff,
    const float* __restrict__ g, const float* __restrict__ b,
    float* __restrict__ out)
{
    const int m = blockIdx.x;
    const int tid = threadIdx.x;
    const float* fr = ff + (size_t)m * DMODEL;
    float va = 2.f * fr[tid];
    float vb = 2.f * fr[tid + 256];
    float s = va + vb, q = va*va + vb*vb;
    #pragma unroll
    for (int off = 32; off; off >>= 1) {
        s += __shfl_xor(s, off); q += __shfl_xor(q, off);
    }
    __shared__ float sm[4][2];
    const int w = tid >> 6;
    if ((tid & 63) == 0) { sm[w][0] = s; sm[w][1] = q; }
    __syncthreads();
    s = sm[0][0] + sm[1][0] + sm[2][0] + sm[3][0];
    q = sm[0][1] + sm[1][1] + sm[2][1] + sm[3][1];
    const float inv = 1.f / DMODEL;
    float mu = s * inv;
    float rs = rsqrtf(q * inv - mu * mu + 1e-5f);
    float* orow = out + (size_t)m * DMODEL;
    orow[tid]       = (va - mu) * rs * g[tid]       + b[tid];
    orow[tid + 256] = (vb - mu) * rs * g[tid + 256] + b[tid + 256];
}

// ---------------------------------------------------------------------------
extern "C" void kernel_launch(void* const* d_in, const int* in_sizes, int n_in,
                              void* d_out, int out_size, void* d_ws, size_t ws_size,
                              hipStream_t stream)
{
    const float* x         = (const float*)d_in[0];
    const float* fm_in_W   = (const float*)d_in[1];
    const float* fm_conv_W = (const float*)d_in[2];
    const float* fm_conv_b = (const float*)d_in[3];
    const float* fm_xproj_W= (const float*)d_in[4];
    const float* fm_dt_W   = (const float*)d_in[5];
    const float* fm_dt_b   = (const float*)d_in[6];
    const float* fm_A_log  = (const float*)d_in[7];
    const float* fm_D      = (const float*)d_in[8];
    const float* fm_out_W  = (const float*)d_in[9];
    const float* bm_in_W   = (const float*)d_in[10];
    const float* bm_conv_W = (const float*)d_in[11];
    const float* bm_conv_b = (const float*)d_in[12];
    const float* bm_xproj_W= (const float*)d_in[13];
    const float* bm_dt_W   = (const float*)d_in[14];
    const float* bm_dt_b   = (const float*)d_in[15];
    const float* bm_A_log  = (const float*)d_in[16];
    const float* bm_D      = (const float*)d_in[17];
    const float* bm_out_W  = (const float*)d_in[18];
    const float* ln1_g     = (const float*)d_in[19];
    const float* ln1_b     = (const float*)d_in[20];
    const float* ln2_g     = (const float*)d_in[21];
    const float* ln2_b     = (const float*)d_in[22];
    const float* ln3_g     = (const float*)d_in[23];
    const float* ln3_b     = (const float*)d_in[24];
    const float* ff_W1     = (const float*)d_in[25];
    const float* ff_b1     = (const float*)d_in[26];
    const float* ff_W2     = (const float*)d_in[27];
    const float* ff_b2     = (const float*)d_in[28];
    float* out = (float*)d_out;

    // ---- Workspace (units: floats; ~98 MB total) ----
    float* ws = (float*)d_ws;
    size_t o = 0;
    float* xz_f = ws + o;  o += (size_t)MM * 2048;
    float* xz_b = ws + o;  o += (size_t)MM * 2048;
    unsigned short* xm_bf_f = (unsigned short*)(ws + o); o += (size_t)MM * DINNER / 2;
    unsigned short* xm_bf_b = (unsigned short*)(ws + o); o += (size_t)MM * DINNER / 2;
    unsigned short* xmT_f   = (unsigned short*)(ws + o); o += (size_t)MM * DINNER / 2;
    unsigned short* xmT_b   = (unsigned short*)(ws + o); o += (size_t)MM * DINNER / 2;
    float* deltaT_f = ws + o; o += (size_t)MM * DINNER;
    float* deltaT_b = ws + o; o += (size_t)MM * DINNER;
    float* dbc_f    = ws + o; o += (size_t)MM * 64;
    float* dbc_b    = ws + o; o += (size_t)MM * 64;
    float* dbcT_f   = ws + o; o += (size_t)MM * 64;
    float* dbcT_b   = ws + o; o += (size_t)MM * 64;
    float* yT_f     = ws + o; o += (size_t)MM * DINNER;
    float* yT_b     = ws + o; o += (size_t)MM * DINNER;
    unsigned short* ybf_f = (unsigned short*)(ws + o); o += (size_t)MM * DINNER / 2;
    unsigned short* ybf_b = (unsigned short*)(ws + o); o += (size_t)MM * DINNER / 2;
    float* scanP  = ws + o; o += (size_t)NCHUNK * GTOT / 16; // 1,048,576 fl
    float* scanH  = ws + o; o += (size_t)NCHUNK * GTOT / 16;
    float* scanCy = ws + o; o += (size_t)NCHUNK * GTOT / 16;

    // Overlays:
    // Pre-GEMM casts live in scanP/scanH (dead until phase1):
    unsigned short* x_bf       = (unsigned short*)scanP;
    unsigned short* fm_inW_bf  = x_bf + (size_t)MM * DMODEL;
    unsigned short* bm_inW_bf  = fm_inW_bf + (size_t)2048 * DMODEL;
    unsigned short* fm_xpW_bf  = bm_inW_bf + (size_t)2048 * DMODEL;
    unsigned short* bm_xpW_bf  = fm_xpW_bf + (size_t)64 * DINNER;
    // Post-scan: proj/ff2 reuse scan scratch; W casts reuse xz_f; h_bf reuses yT.
    float* proj_f = scanP;
    float* proj_b = scanH;
    float* ff2    = scanCy;
    unsigned short* fm_outW_bf = (unsigned short*)xz_f;
    unsigned short* bm_outW_bf = fm_outW_bf + (size_t)DMODEL * DINNER;
    unsigned short* W1_bf      = bm_outW_bf + (size_t)DMODEL * DINNER;
    unsigned short* W2_bf      = W1_bf + (size_t)DFF * DMODEL;
    unsigned short* outsum_bf  = (unsigned short*)xz_b;
    unsigned short* h_bf       = (unsigned short*)yT_f;

    // ---- 0. bf16 casts (inputs to first GEMMs) ----
    cast_f2b_kernel<<<(MM*DMODEL)/2048, 256, 0, stream>>>(x, x_bf, MM*DMODEL);
    cast_f2b_kernel<<<(2048*DMODEL)/2048, 256, 0, stream>>>(fm_in_W, fm_inW_bf, 2048*DMODEL);
    cast_f2b_kernel<<<(2048*DMODEL)/2048, 256, 0, stream>>>(bm_in_W, bm_inW_bf, 2048*DMODEL);
    cast_f2b_kernel<<<(64*DINNER)/2048, 256, 0, stream>>>(fm_xproj_W, fm_xpW_bf, 64*DINNER);
    cast_f2b_kernel<<<(64*DINNER)/2048, 256, 0, stream>>>(bm_xproj_W, bm_xpW_bf, 64*DINNER);

    // ---- 1. in-proj GEMMs ----
    gemm_mfma_kernel<0,0><<<dim3(2048/128, MM/128), 256, 0, stream>>>(
        MM, 2048, DMODEL, x_bf, DMODEL, fm_inW_bf, DMODEL, nullptr, xz_f, 2048);
    gemm_mfma_kernel<0,0><<<dim3(2048/128, MM/128), 256, 0, stream>>>(
        MM, 2048, DMODEL, x_bf, DMODEL, bm_inW_bf, DMODEL, nullptr, xz_b, 2048);

    // ---- 2. conv + silu -> bf16 xm[m][d]; transpose -> xmT[d][m] ----
    conv_silu_kernel<<<(MM * DINNER) / 256, 256, 0, stream>>>(
        xz_f, fm_conv_W, fm_conv_b, xm_bf_f, 0);
    conv_silu_kernel<<<(MM * DINNER) / 256, 256, 0, stream>>>(
        xz_b, bm_conv_W, bm_conv_b, xm_bf_b, 1);
    transpose_bf16_kernel<<<dim3(DINNER/32, MM/32), 256, 0, stream>>>(
        xm_bf_f, xmT_f, MM, DINNER);
    transpose_bf16_kernel<<<dim3(DINNER/32, MM/32), 256, 0, stream>>>(
        xm_bf_b, xmT_b, MM, DINNER);

    // ---- 3. x-proj (MFMA, both dirs): dbc[m][64] + dbcT[64][m] ----
    xproj_mfma_kernel<<<dim3(MM/128, 2), 256, 0, stream>>>(
        xm_bf_f, xm_bf_b, fm_xpW_bf, bm_xpW_bf, dbc_f, dbc_b, dbcT_f, dbcT_b);

    // ---- 4. dt-proj (fp32, writes deltaT[d][m] directly, softplus) ----
    gemm_kernel<2><<<dim3(MM/64, DINNER/64), 256, 0, stream>>>(
        DINNER, MM, DTRANK, fm_dt_W, DTRANK, dbc_f, 64, fm_dt_b, deltaT_f, MM);
    gemm_kernel<2><<<dim3(MM/64, DINNER/64), 256, 0, stream>>>(
        DINNER, MM, DTRANK, bm_dt_W, DTRANK, dbc_b, 64, bm_dt_b, deltaT_b, MM);

    // ---- 5. chunked selective scan ----
    scan_phase1_kernel<0><<<dim3(DINNER/16, BATCH*NCHUNK), 256, 0, stream>>>(
        deltaT_f, xmT_f, dbcT_f, fm_A_log, scanP, scanH);
    scan_phase1_kernel<1><<<dim3(DINNER/16, BATCH*NCHUNK), 256, 0, stream>>>(
        deltaT_b, xmT_b, dbcT_b, bm_A_log, scanP, scanH);
    scan_carry_kernel<<<GTOT/256, 256, 0, stream>>>(scanP, scanH, scanCy);
    scan_phase3_kernel<0><<<dim3(DINNER/16, BATCH*NCHUNK), 256, 0, stream>>>(
        deltaT_f, xmT_f, dbcT_f, fm_A_log, fm_D, scanCy, yT_f);
    scan_phase3_kernel<1><<<dim3(DINNER/16, BATCH*NCHUNK), 256, 0, stream>>>(
        deltaT_b, xmT_b, dbcT_b, bm_A_log, bm_D, scanCy, yT_b);

    // ---- 6. y * silu(z), transpose -> y_bf[m][d] ----
    y_silu_transpose_kernel<<<dim3(MM/32, DINNER/32), 256, 0, stream>>>(
        yT_f, xz_f, ybf_f);
    y_silu_transpose_kernel<<<dim3(MM/32, DINNER/32), 256, 0, stream>>>(
        yT_b, xz_b, ybf_b);

    // ---- 6b. weight casts (xz now dead) ----
    cast_f2b_kernel<<<(DMODEL*DINNER)/2048, 256, 0, stream>>>(fm_out_W, fm_outW_bf, DMODEL*DINNER);
    cast_f2b_kernel<<<(DMODEL*DINNER)/2048, 256, 0, stream>>>(bm_out_W, bm_outW_bf, DMODEL*DINNER);
    cast_f2b_kernel<<<(DFF*DMODEL)/2048, 256, 0, stream>>>(ff_W1, W1_bf, DFF*DMODEL);
    cast_f2b_kernel<<<(DMODEL*DFF)/2048, 256, 0, stream>>>(ff_W2, W2_bf, DMODEL*DFF);

    // ---- 7. out-proj GEMMs ----
    gemm_mfma_kernel<0,0><<<dim3(DMODEL/128, MM/128), 256, 0, stream>>>(
        MM, DMODEL, DINNER, ybf_f, DINNER, fm_outW_bf, DINNER, nullptr, proj_f, DMODEL);
    gemm_mfma_kernel<0,0><<<dim3(DMODEL/128, MM/128), 256, 0, stream>>>(
        MM, DMODEL, DINNER, ybf_b, DINNER, bm_outW_bf, DINNER, nullptr, proj_b, DMODEL);

    // ---- 8. out = LN(xf+fwd) + LN(xf+bwd) -> bf16 ----
    ln_combine_kernel<<<MM, 256, 0, stream>>>(
        x, proj_f, proj_b, ln1_g, ln1_b, ln2_g, ln2_b, outsum_bf);

    // ---- 9. FF ----
    gemm_mfma_kernel<1,1><<<dim3(DFF/128, MM/128), 256, 0, stream>>>(
        MM, DFF, DMODEL, outsum_bf, DMODEL, W1_bf, DMODEL, ff_b1, h_bf, DFF);
    gemm_mfma_kernel<0,0><<<dim3(DMODEL/128, MM/128), 256, 0, stream>>>(
        MM, DMODEL, DFF, h_bf, DFF, W2_bf, DFF, ff_b2, ff2, DMODEL);

    // ---- 10. final LN(2*ff) ----
    ln_final_kernel<<<MM, 256, 0, stream>>>(ff2, ln3_g, ln3_b, out);
}

// Round 5
// 432.255 us; speedup vs baseline: 3.3509x; 1.1250x over previous
//
#include <hip/hip_runtime.h>
#include <hip/hip_bf16.h>
#include <math.h>

// Problem constants
#define MM 2048        // B*W flattened rows
#define BATCH 2
#define SEQ 1024
#define DMODEL 512
#define DINNER 1024
#define DSTATE 16
#define DTRANK 32
#define DFF 2048

// Chunked-scan constants
#define NCHUNK 16
#define CHUNK 64
#define GTOT 65536          // 2 dirs * BATCH * DINNER * DSTATE

typedef short bf16x8 __attribute__((ext_vector_type(8)));
typedef float floatx4 __attribute__((ext_vector_type(4)));
typedef unsigned short ushort8v __attribute__((ext_vector_type(8)));

__device__ __forceinline__ unsigned short f2bf(float f) {
    union { float f; unsigned u; } v; v.f = f;
    unsigned r = v.u + 0x7FFF + ((v.u >> 16) & 1);
    return (unsigned short)(r >> 16);
}
__device__ __forceinline__ float bf2f(unsigned short u) {
    union { unsigned u; float f; } v; v.u = ((unsigned)u) << 16; return v.f;
}

#define GLOAD_LDS16(gp, lp) __builtin_amdgcn_global_load_lds( \
    (const __attribute__((address_space(1))) unsigned int*)(gp), \
    (__attribute__((address_space(3))) unsigned int*)(lp), 16, 0, 0)

// LDS tile layout (bank-conflict-free): per 16-row group of a 32-k tile,
// slot (kc, row) at ushort offset g*512 + kc*128 + row*8.  Staging lane
// decomposition (row=lane&15, kc=lane>>4) produces exactly this under the
// wave-uniform base + lane*16B rule; fragment reads at frow*16B span banks
// 4*frow%32 -> 2-way aliasing only (free).

// ---------------------------------------------------------------------------
// Batched direct bf16 MFMA GEMM: C[z][M,N] = epi(A[z] @ B[z]^T + bias)
// 128x128 tile, BK=32, 4 waves x (4x4) 16x16x32. blockIdx.z picks problem.
// ---------------------------------------------------------------------------
template<int EPI, int OUTBF16>
__global__ __launch_bounds__(256) void gemm_mfma_batch(
    int M, int N, int K,
    const unsigned short* __restrict__ A0, const unsigned short* __restrict__ A1, int lda,
    const unsigned short* __restrict__ B0, const unsigned short* __restrict__ B1, int ldb,
    const float* __restrict__ bias,
    void* __restrict__ C0, void* __restrict__ C1, int ldc)
{
    __shared__ unsigned short As[128 * 32];
    __shared__ unsigned short Bs[128 * 32];
    const int z = blockIdx.z;
    const unsigned short* A = z ? A1 : A0;
    const unsigned short* B = z ? B1 : B0;
    void* Cout = z ? C1 : C0;
    const int tid  = threadIdx.x;
    const int wave = tid >> 6;
    const int lane = tid & 63;
    const int bm = blockIdx.y * 128;
    const int bn = blockIdx.x * 128;

    const int strow = lane & 15;        // row within 16-row group
    const int stkc  = lane >> 4;        // k-chunk 0..3
    const int wr = wave >> 1, wc = wave & 1;
    const int frow = lane & 15;
    const int fkc  = lane >> 4;

    floatx4 acc[4][4];
    #pragma unroll
    for (int i = 0; i < 4; ++i)
        #pragma unroll
        for (int j = 0; j < 4; ++j)
            acc[i][j] = (floatx4){0.f, 0.f, 0.f, 0.f};

    for (int k0 = 0; k0 < K; k0 += 32) {
        __syncthreads();
        #pragma unroll
        for (int q = 0; q < 2; ++q) {
            int g = wave * 2 + q;
            GLOAD_LDS16(A + (size_t)(bm + g * 16 + strow) * lda + k0 + stkc * 8,
                        As + g * 512);
        }
        #pragma unroll
        for (int q = 0; q < 2; ++q) {
            int g = wave * 2 + q;
            GLOAD_LDS16(B + (size_t)(bn + g * 16 + strow) * ldb + k0 + stkc * 8,
                        Bs + g * 512);
        }
        __syncthreads();

        bf16x8 af[4], bfr[4];
        #pragma unroll
        for (int i = 0; i < 4; ++i)
            af[i] = *(const bf16x8*)(As + (wr * 4 + i) * 512 + fkc * 128 + frow * 8);
        #pragma unroll
        for (int j = 0; j < 4; ++j)
            bfr[j] = *(const bf16x8*)(Bs + (wc * 4 + j) * 512 + fkc * 128 + frow * 8);
        #pragma unroll
        for (int i = 0; i < 4; ++i)
            #pragma unroll
            for (int j = 0; j < 4; ++j)
                acc[i][j] = __builtin_amdgcn_mfma_f32_16x16x32_bf16(
                    af[i], bfr[j], acc[i][j], 0, 0, 0);
    }

    const int orow0 = bm + wr * 64 + (lane >> 4) * 4;
    const int ocol0 = bn + wc * 64 + (lane & 15);
    #pragma unroll
    for (int j = 0; j < 4; ++j) {
        const int col = ocol0 + j * 16;
        const float bv = bias ? bias[col] : 0.f;
        #pragma unroll
        for (int i = 0; i < 4; ++i) {
            #pragma unroll
            for (int r = 0; r < 4; ++r) {
                int row = orow0 + i * 16 + r;
                float t = acc[i][j][r] + bv;
                if (EPI == 1) t = fmaxf(t, 0.f);
                if (OUTBF16)
                    ((unsigned short*)Cout)[(size_t)row * ldc + col] = f2bf(t);
                else
                    ((float*)Cout)[(size_t)row * ldc + col] = t;
            }
        }
    }
}

// ---------------------------------------------------------------------------
// Split-K batched MFMA GEMM -> fp32 partials part[z][M*ldc].
// z = dir*NSPLIT + split.
// ---------------------------------------------------------------------------
template<int NSPLIT>
__global__ __launch_bounds__(256) void gemm_mfma_splitk(
    int M, int N, int K,
    const unsigned short* __restrict__ A0, const unsigned short* __restrict__ A1, int lda,
    const unsigned short* __restrict__ B0, const unsigned short* __restrict__ B1, int ldb,
    float* __restrict__ part, int ldc)
{
    __shared__ unsigned short As[128 * 32];
    __shared__ unsigned short Bs[128 * 32];
    const int z = blockIdx.z;
    const int dir = z / NSPLIT, sp = z % NSPLIT;
    const unsigned short* A = dir ? A1 : A0;
    const unsigned short* B = dir ? B1 : B0;
    float* Cp = part + (size_t)z * M * ldc;
    const int kbeg = sp * (K / NSPLIT);
    const int kend = kbeg + (K / NSPLIT);
    const int tid  = threadIdx.x;
    const int wave = tid >> 6;
    const int lane = tid & 63;
    const int bm = blockIdx.y * 128;
    const int bn = blockIdx.x * 128;

    const int strow = lane & 15;
    const int stkc  = lane >> 4;
    const int wr = wave >> 1, wc = wave & 1;
    const int frow = lane & 15;
    const int fkc  = lane >> 4;

    floatx4 acc[4][4];
    #pragma unroll
    for (int i = 0; i < 4; ++i)
        #pragma unroll
        for (int j = 0; j < 4; ++j)
            acc[i][j] = (floatx4){0.f, 0.f, 0.f, 0.f};

    for (int k0 = kbeg; k0 < kend; k0 += 32) {
        __syncthreads();
        #pragma unroll
        for (int q = 0; q < 2; ++q) {
            int g = wave * 2 + q;
            GLOAD_LDS16(A + (size_t)(bm + g * 16 + strow) * lda + k0 + stkc * 8,
                        As + g * 512);
        }
        #pragma unroll
        for (int q = 0; q < 2; ++q) {
            int g = wave * 2 + q;
            GLOAD_LDS16(B + (size_t)(bn + g * 16 + strow) * ldb + k0 + stkc * 8,
                        Bs + g * 512);
        }
        __syncthreads();

        bf16x8 af[4], bfr[4];
        #pragma unroll
        for (int i = 0; i < 4; ++i)
            af[i] = *(const bf16x8*)(As + (wr * 4 + i) * 512 + fkc * 128 + frow * 8);
        #pragma unroll
        for (int j = 0; j < 4; ++j)
            bfr[j] = *(const bf16x8*)(Bs + (wc * 4 + j) * 512 + fkc * 128 + frow * 8);
        #pragma unroll
        for (int i = 0; i < 4; ++i)
            #pragma unroll
            for (int j = 0; j < 4; ++j)
                acc[i][j] = __builtin_amdgcn_mfma_f32_16x16x32_bf16(
                    af[i], bfr[j], acc[i][j], 0, 0, 0);
    }

    const int orow0 = bm + wr * 64 + (lane >> 4) * 4;
    const int ocol0 = bn + wc * 64 + (lane & 15);
    #pragma unroll
    for (int j = 0; j < 4; ++j) {
        const int col = ocol0 + j * 16;
        #pragma unroll
        for (int i = 0; i < 4; ++i)
            #pragma unroll
            for (int r = 0; r < 4; ++r)
                Cp[(size_t)(orow0 + i * 16 + r) * ldc + col] = acc[i][j][r];
    }
}

// ---------------------------------------------------------------------------
// Split-K reduce: out[i] = sum_s part[s][i] (+ bias[i%ldc]). fp32 out.
// ---------------------------------------------------------------------------
__global__ __launch_bounds__(256) void reduce_splitk_kernel(
    const float* __restrict__ part, int nsplit, int elems, int ldc,
    const float* __restrict__ bias, float* __restrict__ out)
{
    int i = (blockIdx.x * 256 + threadIdx.x) * 4;
    if (i >= elems) return;
    float4 a = *(const float4*)(part + i);
    for (int s = 1; s < nsplit; ++s) {
        float4 t = *(const float4*)(part + (size_t)s * elems + i);
        a.x += t.x; a.y += t.y; a.z += t.z; a.w += t.w;
    }
    if (bias) {
        int c = i % ldc;
        a.x += bias[c]; a.y += bias[c + 1]; a.z += bias[c + 2]; a.w += bias[c + 3];
    }
    *(float4*)(out + i) = a;
}

// ---------------------------------------------------------------------------
// xproj split-K MFMA: tile 128(m) x 64(n), K slice 256.
// grid (MM/128, 8); blockIdx.y = dir*4 + split. Writes part[(dir*4+s)][m][64].
// ---------------------------------------------------------------------------
__global__ __launch_bounds__(256) void xproj_splitk_kernel(
    const unsigned short* __restrict__ A_f, const unsigned short* __restrict__ A_b,
    const unsigned short* __restrict__ Wf,  const unsigned short* __restrict__ Wb,
    float* __restrict__ part)
{
    __shared__ unsigned short As[128 * 32];
    __shared__ unsigned short Bs[64 * 32];
    const int tid = threadIdx.x, wave = tid >> 6, lane = tid & 63;
    const int bm = blockIdx.x * 128;
    const int dir = blockIdx.y >> 2, sp = blockIdx.y & 3;
    const unsigned short* A = dir ? A_b : A_f;
    const unsigned short* W = dir ? Wb  : Wf;
    float* Cp = part + (size_t)blockIdx.y * MM * 64;
    const int kbeg = sp * 256, kend = kbeg + 256;

    const int strow = lane & 15;
    const int stkc  = lane >> 4;
    const int frow = lane & 15;
    const int fkc  = lane >> 4;

    floatx4 acc[2][4];
    #pragma unroll
    for (int i = 0; i < 2; ++i)
        #pragma unroll
        for (int j = 0; j < 4; ++j)
            acc[i][j] = (floatx4){0.f, 0.f, 0.f, 0.f};

    for (int k0 = kbeg; k0 < kend; k0 += 32) {
        __syncthreads();
        #pragma unroll
        for (int q = 0; q < 2; ++q) {
            int g = wave * 2 + q;
            GLOAD_LDS16(A + (size_t)(bm + g * 16 + strow) * DINNER + k0 + stkc * 8,
                        As + g * 512);
        }
        GLOAD_LDS16(W + (size_t)(wave * 16 + strow) * DINNER + k0 + stkc * 8,
                    Bs + wave * 512);
        __syncthreads();

        bf16x8 af[2], bfr[4];
        #pragma unroll
        for (int i = 0; i < 2; ++i)
            af[i] = *(const bf16x8*)(As + (wave * 2 + i) * 512 + fkc * 128 + frow * 8);
        #pragma unroll
        for (int j = 0; j < 4; ++j)
            bfr[j] = *(const bf16x8*)(Bs + j * 512 + fkc * 128 + frow * 8);
        #pragma unroll
        for (int i = 0; i < 2; ++i)
            #pragma unroll
            for (int j = 0; j < 4; ++j)
                acc[i][j] = __builtin_amdgcn_mfma_f32_16x16x32_bf16(
                    af[i], bfr[j], acc[i][j], 0, 0, 0);
    }

    const int orow0 = bm + wave * 32 + (lane >> 4) * 4;
    #pragma unroll
    for (int j = 0; j < 4; ++j) {
        const int col = (lane & 15) + j * 16;
        #pragma unroll
        for (int i = 0; i < 2; ++i)
            #pragma unroll
            for (int r = 0; r < 4; ++r)
                Cp[(size_t)(orow0 + i * 16 + r) * 64 + col] = acc[i][j][r];
    }
}

// ---------------------------------------------------------------------------
// xproj reduce: dbc[m][64] = sum of 4 parts; also writes dbcT[64][MM].
// grid (MM*64/1024, 2).
// ---------------------------------------------------------------------------
__global__ __launch_bounds__(256) void xproj_reduce_kernel(
    const float* __restrict__ part,
    float* __restrict__ dbc_f, float* __restrict__ dbc_b,
    float* __restrict__ dbcT_f, float* __restrict__ dbcT_b)
{
    const int dir = blockIdx.y;
    const int i = (blockIdx.x * 256 + threadIdx.x) * 4;
    const float* p = part + (size_t)dir * 4 * (MM * 64);
    float4 a = *(const float4*)(p + i);
    #pragma unroll
    for (int s = 1; s < 4; ++s) {
        float4 t = *(const float4*)(p + (size_t)s * (MM * 64) + i);
        a.x += t.x; a.y += t.y; a.z += t.z; a.w += t.w;
    }
    float* dbc  = dir ? dbc_b  : dbc_f;
    float* dbcT = dir ? dbcT_b : dbcT_f;
    *(float4*)(dbc + i) = a;
    const int m = i >> 6, c = i & 63;
    dbcT[(size_t)(c + 0) * MM + m] = a.x;
    dbcT[(size_t)(c + 1) * MM + m] = a.y;
    dbcT[(size_t)(c + 2) * MM + m] = a.z;
    dbcT[(size_t)(c + 3) * MM + m] = a.w;
}

// ---------------------------------------------------------------------------
// fp32 GEMM (dt-proj only): C[M,N] = softplus(A[M,K] @ B[N,K]^T + biasR[row])
// ---------------------------------------------------------------------------
template<int EPI>
__global__ __launch_bounds__(256) void gemm_kernel(
    int M, int N, int K,
    const float* __restrict__ A, int lda,
    const float* __restrict__ B, int ldb,
    const float* __restrict__ biasR,
    float* __restrict__ C, int ldc)
{
    __shared__ float As[16][64];
    __shared__ float Bs[16][64];
    const int tid = threadIdx.x;
    const int tx = tid & 15, ty = tid >> 4;
    const int bm = blockIdx.y * 64, bn = blockIdx.x * 64;
    const int lm = tid & 63;
    const int lk = (tid >> 6) * 4;
    const float* Arow = A + (size_t)(bm + lm) * lda + lk;
    const float* Brow = B + (size_t)(bn + lm) * ldb + lk;
    float acc[4][4] = {};
    for (int k0 = 0; k0 < K; k0 += 16) {
        float4 av = *(const float4*)(Arow + k0);
        float4 bv = *(const float4*)(Brow + k0);
        __syncthreads();
        As[lk+0][lm] = av.x; As[lk+1][lm] = av.y; As[lk+2][lm] = av.z; As[lk+3][lm] = av.w;
        Bs[lk+0][lm] = bv.x; Bs[lk+1][lm] = bv.y; Bs[lk+2][lm] = bv.z; Bs[lk+3][lm] = bv.w;
        __syncthreads();
        #pragma unroll
        for (int k = 0; k < 16; ++k) {
            float4 a = *(const float4*)(&As[k][ty*4]);
            float4 b = *(const float4*)(&Bs[k][tx*4]);
            float ar[4] = {a.x,a.y,a.z,a.w};
            float br[4] = {b.x,b.y,b.z,b.w};
            #pragma unroll
            for (int i = 0; i < 4; ++i)
                #pragma unroll
                for (int j = 0; j < 4; ++j)
                    acc[i][j] = fmaf(ar[i], br[j], acc[i][j]);
        }
    }
    const int row0 = bm + ty*4, col0 = bn + tx*4;
    #pragma unroll
    for (int i = 0; i < 4; ++i) {
        float br = biasR ? biasR[row0 + i] : 0.f;
        float4 o;
        float v[4];
        #pragma unroll
        for (int j = 0; j < 4; ++j) {
            float t = acc[i][j] + br;
            if (EPI == 2) t = fmaxf(t, 0.f) + log1pf(__expf(-fabsf(t)));
            v[j] = t;
        }
        o.x = v[0]; o.y = v[1]; o.z = v[2]; o.w = v[3];
        *(float4*)(C + (size_t)(row0 + i) * ldc + col0) = o;
    }
}

// ---------------------------------------------------------------------------
// fp32 -> bf16 cast, 8 elems/thread.
// ---------------------------------------------------------------------------
__global__ __launch_bounds__(256) void cast_f2b_kernel(
    const float* __restrict__ in, unsigned short* __restrict__ out, int n)
{
    int i = (blockIdx.x * 256 + threadIdx.x) * 8;
    if (i >= n) return;
    float4 a = *(const float4*)(in + i);
    float4 b = *(const float4*)(in + i + 4);
    ushort8v o;
    o[0] = f2bf(a.x); o[1] = f2bf(a.y); o[2] = f2bf(a.z); o[3] = f2bf(a.w);
    o[4] = f2bf(b.x); o[5] = f2bf(b.y); o[6] = f2bf(b.z); o[7] = f2bf(b.w);
    *(ushort8v*)(out + i) = o;
}

// ---------------------------------------------------------------------------
// Depthwise conv + bias + silu -> bf16 xm[m][d].
// ---------------------------------------------------------------------------
__global__ __launch_bounds__(256) void conv_silu_kernel(
    const float* __restrict__ xz,
    const float* __restrict__ convW,
    const float* __restrict__ convb,
    unsigned short* __restrict__ xm_bf,
    int dir)
{
    int gid = blockIdx.x * 256 + threadIdx.x;
    int c = gid & (DINNER - 1);
    int m = gid >> 10;
    int b = m >> 10;
    int l = m & (SEQ - 1);
    float4 wv = *(const float4*)(convW + c * 4);
    float w[4] = {wv.x, wv.y, wv.z, wv.w};
    float acc = convb[c];
    #pragma unroll
    for (int j = 0; j < 4; ++j) {
        int p = dir ? (l + 3 - j) : (l - 3 + j);
        if (p >= 0 && p < SEQ)
            acc = fmaf(xz[(size_t)(b * SEQ + p) * 2048 + c], w[j], acc);
    }
    float sig = 1.f / (1.f + __expf(-acc));
    xm_bf[(size_t)m * DINNER + c] = f2bf(acc * sig);
}

// ---------------------------------------------------------------------------
// bf16 transpose: in[R][C] -> out[C][R]. Tile 32x32.
// ---------------------------------------------------------------------------
__global__ __launch_bounds__(256) void transpose_bf16_kernel(
    const unsigned short* __restrict__ in, unsigned short* __restrict__ out,
    int R, int C)
{
    __shared__ unsigned short t[32][34];
    const int c0 = blockIdx.x * 32, r0 = blockIdx.y * 32;
    const int tx = threadIdx.x & 31, ty = threadIdx.x >> 5;
    #pragma unroll
    for (int rr = 0; rr < 32; rr += 8)
        t[ty + rr][tx] = in[(size_t)(r0 + ty + rr) * C + c0 + tx];
    __syncthreads();
    #pragma unroll
    for (int rr = 0; rr < 32; rr += 8)
        out[(size_t)(c0 + ty + rr) * R + r0 + tx] = t[tx][ty + rr];
}

// ---------------------------------------------------------------------------
// Scan phase 1 (templated direction).
// ---------------------------------------------------------------------------
template<int DIR>
__global__ __launch_bounds__(256) void scan_phase1_kernel(
    const float* __restrict__ deltaT, const unsigned short* __restrict__ xmT,
    const float* __restrict__ dbcT,   const float* __restrict__ Alog,
    float* __restrict__ Pout, float* __restrict__ Hout)
{
    const int tid = threadIdx.x;
    const int s = tid & 15;
    const int dloc = tid >> 4;
    const int d = blockIdx.x * 16 + dloc;
    const int b = blockIdx.y / NCHUNK;
    const int c = blockIdx.y % NCHUNK;

    const float A = -__expf(Alog[d * DSTATE + s]);
    const float* dRow = deltaT + (size_t)d * MM + b * SEQ;
    const unsigned short* xRow = xmT + (size_t)d * MM + b * SEQ;
    const float* bRow = dbcT + (size_t)(DTRANK + s) * MM + b * SEQ;

    float h = 0.f, P = 1.f;
    const int segBase = DIR ? (SEQ - CHUNK - c * CHUNK) : (c * CHUNK);
    for (int ii = 0; ii < CHUNK; ii += 8) {
        const int off = DIR ? (segBase + (CHUNK - 8) - ii) : (segBase + ii);
        float4 d0 = *(const float4*)(dRow + off);
        float4 d1 = *(const float4*)(dRow + off + 4);
        float4 b0 = *(const float4*)(bRow + off);
        float4 b1 = *(const float4*)(bRow + off + 4);
        ushort8v x8 = *(const ushort8v*)(xRow + off);
        float dl[8] = {d0.x,d0.y,d0.z,d0.w,d1.x,d1.y,d1.z,d1.w};
        float Bv[8] = {b0.x,b0.y,b0.z,b0.w,b1.x,b1.y,b1.z,b1.w};
        #pragma unroll
        for (int u = 0; u < 8; ++u) {
            const int t = DIR ? (7 - u) : u;
            float dA = __expf(dl[t] * A);
            P *= dA;
            h = fmaf(dA, h, dl[t] * Bv[t] * bf2f(x8[t]));
        }
    }
    const int g = ((DIR * BATCH + b) * DINNER + d) * DSTATE + s;
    Pout[(size_t)c * GTOT + g] = P;
    Hout[(size_t)c * GTOT + g] = h;
}

// ---------------------------------------------------------------------------
// Phase 2: sequential combine over chunks.
// ---------------------------------------------------------------------------
__global__ __launch_bounds__(256) void scan_carry_kernel(
    const float* __restrict__ P, const float* __restrict__ H,
    float* __restrict__ carry)
{
    const int g = blockIdx.x * 256 + threadIdx.x;
    float h = 0.f;
    #pragma unroll
    for (int c = 0; c < NCHUNK; ++c) {
        carry[(size_t)c * GTOT + g] = h;
        h = fmaf(P[(size_t)c * GTOT + g], h, H[(size_t)c * GTOT + g]);
    }
}

// ---------------------------------------------------------------------------
// Phase 3: rescan from carry; writes raw y (pre-silu(z)) as fp32 yT[d][m].
// ---------------------------------------------------------------------------
template<int DIR>
__global__ __launch_bounds__(256) void scan_phase3_kernel(
    const float* __restrict__ deltaT, const unsigned short* __restrict__ xmT,
    const float* __restrict__ dbcT,   const float* __restrict__ Alog,
    const float* __restrict__ Dv,     const float* __restrict__ carry,
    float* __restrict__ yT)
{
    const int tid = threadIdx.x;
    const int s = tid & 15;
    const int dloc = tid >> 4;
    const int d = blockIdx.x * 16 + dloc;
    const int b = blockIdx.y / NCHUNK;
    const int c = blockIdx.y % NCHUNK;

    const float A  = -__expf(Alog[d * DSTATE + s]);
    const float Dp = Dv[d];
    const float* dRow = deltaT + (size_t)d * MM + b * SEQ;
    const unsigned short* xRow = xmT + (size_t)d * MM + b * SEQ;
    const float* bRow = dbcT + (size_t)(DTRANK + s) * MM + b * SEQ;
    const float* cRow = dbcT + (size_t)(DTRANK + DSTATE + s) * MM + b * SEQ;
    float* yRow = yT + (size_t)d * MM + b * SEQ;

    const int g = ((DIR * BATCH + b) * DINNER + d) * DSTATE + s;
    float h = carry[(size_t)c * GTOT + g];

    const int segBase = DIR ? (SEQ - CHUNK - c * CHUNK) : (c * CHUNK);
    for (int ii = 0; ii < CHUNK; ii += 8) {
        const int off = DIR ? (segBase + (CHUNK - 8) - ii) : (segBase + ii);
        float4 d0 = *(const float4*)(dRow + off);
        float4 d1 = *(const float4*)(dRow + off + 4);
        float4 b0 = *(const float4*)(bRow + off);
        float4 b1 = *(const float4*)(bRow + off + 4);
        float4 c0 = *(const float4*)(cRow + off);
        float4 c1 = *(const float4*)(cRow + off + 4);
        ushort8v x8 = *(const ushort8v*)(xRow + off);
        float dl[8] = {d0.x,d0.y,d0.z,d0.w,d1.x,d1.y,d1.z,d1.w};
        float Bv[8] = {b0.x,b0.y,b0.z,b0.w,b1.x,b1.y,b1.z,b1.w};
        float Cv[8] = {c0.x,c0.y,c0.z,c0.w,c1.x,c1.y,c1.z,c1.w};
        float yv[8];
        #pragma unroll
        for (int u = 0; u < 8; ++u) {
            const int t = DIR ? (7 - u) : u;
            float xv = bf2f(x8[t]);
            float dA = __expf(dl[t] * A);
            h = fmaf(dA, h, dl[t] * Bv[t] * xv);
            float part = h * Cv[t];
            part += __shfl_xor(part, 1);
            part += __shfl_xor(part, 2);
            part += __shfl_xor(part, 4);
            part += __shfl_xor(part, 8);
            yv[t] = fmaf(xv, Dp, part);
        }
        if (s == 0) {
            *(float4*)(yRow + off)     = (float4){yv[0], yv[1], yv[2], yv[3]};
            *(float4*)(yRow + off + 4) = (float4){yv[4], yv[5], yv[6], yv[7]};
        }
    }
}

// ---------------------------------------------------------------------------
// y_bf[m][d] = f2bf( yT[d][m] * silu(z[m][d]) ), z from xz col 1024+d.
// ---------------------------------------------------------------------------
__global__ __launch_bounds__(256) void y_silu_transpose_kernel(
    const float* __restrict__ yT, const float* __restrict__ xz,
    unsigned short* __restrict__ y_bf)
{
    __shared__ float t[32][33];
    const int m0 = blockIdx.x * 32, d0 = blockIdx.y * 32;
    const int tx = threadIdx.x & 31, ty = threadIdx.x >> 5;
    #pragma unroll
    for (int rr = 0; rr < 32; rr += 8)
        t[ty + rr][tx] = yT[(size_t)(d0 + ty + rr) * MM + m0 + tx];
    __syncthreads();
    #pragma unroll
    for (int rr = 0; rr < 32; rr += 8) {
        int m = m0 + ty + rr, d = d0 + tx;
        float z = xz[(size_t)m * 2048 + DINNER + d];
        float sig = 1.f / (1.f + __expf(-z));
        y_bf[(size_t)m * DINNER + d] = f2bf(t[tx][ty + rr] * (z * sig));
    }
}

// ---------------------------------------------------------------------------
// out[m,:] = LN(xf+pf; g1,b1) + LN(xf+pb; g2,b2), written as bf16.
// ---------------------------------------------------------------------------
__global__ __launch_bounds__(256) void ln_combine_kernel(
    const float* __restrict__ xf,
    const float* __restrict__ pf, const float* __restrict__ pb,
    const float* __restrict__ g1, const float* __restrict__ b1,
    const float* __restrict__ g2, const float* __restrict__ b2,
    unsigned short* __restrict__ out)
{
    const int m = blockIdx.x;
    const int tid = threadIdx.x;
    const float* xr = xf + (size_t)m * DMODEL;
    const float* p1 = pf + (size_t)m * DMODEL;
    const float* p2 = pb + (size_t)m * DMODEL;
    float v1a = xr[tid] + p1[tid];
    float v1b = xr[tid + 256] + p1[tid + 256];
    float v2a = xr[tid] + p2[tid];
    float v2b = xr[tid + 256] + p2[tid + 256];
    float s1 = v1a + v1b, q1 = v1a*v1a + v1b*v1b;
    float s2 = v2a + v2b, q2 = v2a*v2a + v2b*v2b;
    #pragma unroll
    for (int off = 32; off; off >>= 1) {
        s1 += __shfl_xor(s1, off); q1 += __shfl_xor(q1, off);
        s2 += __shfl_xor(s2, off); q2 += __shfl_xor(q2, off);
    }
    __shared__ float sm[4][4];
    const int w = tid >> 6;
    if ((tid & 63) == 0) { sm[w][0] = s1; sm[w][1] = q1; sm[w][2] = s2; sm[w][3] = q2; }
    __syncthreads();
    s1 = sm[0][0] + sm[1][0] + sm[2][0] + sm[3][0];
    q1 = sm[0][1] + sm[1][1] + sm[2][1] + sm[3][1];
    s2 = sm[0][2] + sm[1][2] + sm[2][2] + sm[3][2];
    q2 = sm[0][3] + sm[1][3] + sm[2][3] + sm[3][3];
    const float inv = 1.f / DMODEL;
    float mu1 = s1 * inv, mu2 = s2 * inv;
    float rs1 = rsqrtf(q1 * inv - mu1 * mu1 + 1e-5f);
    float rs2 = rsqrtf(q2 * inv - mu2 * mu2 + 1e-5f);
    unsigned short* orow = out + (size_t)m * DMODEL;
    orow[tid]       = f2bf((v1a - mu1) * rs1 * g1[tid]       + b1[tid]
                         + (v2a - mu2) * rs2 * g2[tid]       + b2[tid]);
    orow[tid + 256] = f2bf((v1b - mu1) * rs1 * g1[tid + 256] + b1[tid + 256]
                         + (v2b - mu2) * rs2 * g2[tid + 256] + b2[tid + 256]);
}

// ---------------------------------------------------------------------------
// out[m,:] = LN(2*ff[m,:]; g,b)
// ---------------------------------------------------------------------------
__global__ __launch_bounds__(256) void ln_final_kernel(
    const float* __restrict__ ff,
    const float* __restrict__ g, const float* __restrict__ b,
    float* __restrict__ out)
{
    const int m = blockIdx.x;
    const int tid = threadIdx.x;
    const float* fr = ff + (size_t)m * DMODEL;
    float va = 2.f * fr[tid];
    float vb = 2.f * fr[tid + 256];
    float s = va + vb, q = va*va + vb*vb;
    #pragma unroll
    for (int off = 32; off; off >>= 1) {
        s += __shfl_xor(s, off); q += __shfl_xor(q, off);
    }
    __shared__ float sm[4][2];
    const int w = tid >> 6;
    if ((tid & 63) == 0) { sm[w][0] = s; sm[w][1] = q; }
    __syncthreads();
    s = sm[0][0] + sm[1][0] + sm[2][0] + sm[3][0];
    q = sm[0][1] + sm[1][1] + sm[2][1] + sm[3][1];
    const float inv = 1.f / DMODEL;
    float mu = s * inv;
    float rs = rsqrtf(q * inv - mu * mu + 1e-5f);
    float* orow = out + (size_t)m * DMODEL;
    orow[tid]       = (va - mu) * rs * g[tid]       + b[tid];
    orow[tid + 256] = (vb - mu) * rs * g[tid + 256] + b[tid + 256];
}

// ---------------------------------------------------------------------------
extern "C" void kernel_launch(void* const* d_in, const int* in_sizes, int n_in,
                              void* d_out, int out_size, void* d_ws, size_t ws_size,
                              hipStream_t stream)
{
    const float* x         = (const float*)d_in[0];
    const float* fm_in_W   = (const float*)d_in[1];
    const float* fm_conv_W = (const float*)d_in[2];
    const float* fm_conv_b = (const float*)d_in[3];
    const float* fm_xproj_W= (const float*)d_in[4];
    const float* fm_dt_W   = (const float*)d_in[5];
    const float* fm_dt_b   = (const float*)d_in[6];
    const float* fm_A_log  = (const float*)d_in[7];
    const float* fm_D      = (const float*)d_in[8];
    const float* fm_out_W  = (const float*)d_in[9];
    const float* bm_in_W   = (const float*)d_in[10];
    const float* bm_conv_W = (const float*)d_in[11];
    const float* bm_conv_b = (const float*)d_in[12];
    const float* bm_xproj_W= (const float*)d_in[13];
    const float* bm_dt_W   = (const float*)d_in[14];
    const float* bm_dt_b   = (const float*)d_in[15];
    const float* bm_A_log  = (const float*)d_in[16];
    const float* bm_D      = (const float*)d_in[17];
    const float* bm_out_W  = (const float*)d_in[18];
    const float* ln1_g     = (const float*)d_in[19];
    const float* ln1_b     = (const float*)d_in[20];
    const float* ln2_g     = (const float*)d_in[21];
    const float* ln2_b     = (const float*)d_in[22];
    const float* ln3_g     = (const float*)d_in[23];
    const float* ln3_b     = (const float*)d_in[24];
    const float* ff_W1     = (const float*)d_in[25];
    const float* ff_b1     = (const float*)d_in[26];
    const float* ff_W2     = (const float*)d_in[27];
    const float* ff_b2     = (const float*)d_in[28];
    float* out = (float*)d_out;

    // ---- Workspace (units: floats) ----
    float* ws = (float*)d_ws;
    size_t o = 0;
    float* xz_f = ws + o;  o += (size_t)MM * 2048;
    float* xz_b = ws + o;  o += (size_t)MM * 2048;
    unsigned short* xm_bf_f = (unsigned short*)(ws + o); o += (size_t)MM * DINNER / 2;
    unsigned short* xm_bf_b = (unsigned short*)(ws + o); o += (size_t)MM * DINNER / 2;
    unsigned short* xmT_f   = (unsigned short*)(ws + o); o += (size_t)MM * DINNER / 2;
    unsigned short* xmT_b   = (unsigned short*)(ws + o); o += (size_t)MM * DINNER / 2;
    float* deltaT_f = ws + o; o += (size_t)MM * DINNER;   // also split-K partials
    float* deltaT_b = ws + o; o += (size_t)MM * DINNER;   // (4M fl contiguous)
    float* dbc_f    = ws + o; o += (size_t)MM * 64;
    float* dbc_b    = ws + o; o += (size_t)MM * 64;
    float* dbcT_f   = ws + o; o += (size_t)MM * 64;
    float* dbcT_b   = ws + o; o += (size_t)MM * 64;
    float* yT_f     = ws + o; o += (size_t)MM * DINNER;
    float* yT_b     = ws + o; o += (size_t)MM * DINNER;
    unsigned short* ybf_f = (unsigned short*)(ws + o); o += (size_t)MM * DINNER / 2;
    unsigned short* ybf_b = (unsigned short*)(ws + o); o += (size_t)MM * DINNER / 2;
    float* scanP  = ws + o; o += (size_t)NCHUNK * GTOT / 16;
    float* scanH  = ws + o; o += (size_t)NCHUNK * GTOT / 16;
    float* scanCy = ws + o; o += (size_t)NCHUNK * GTOT / 16;

    // Split-K partial scratch = deltaT region (sequentially dead when used):
    //  - xproj partials (1.0M fl) before dt-proj writes deltaT
    //  - out-proj partials (4.2M fl) after scan consumed deltaT
    //  - FF2 partials (4.2M fl) after out-proj reduce
    float* gpart = deltaT_f;

    // Overlays: pre-GEMM casts in scanP/scanH (dead until phase1)
    unsigned short* x_bf       = (unsigned short*)scanP;
    unsigned short* fm_inW_bf  = x_bf + (size_t)MM * DMODEL;
    unsigned short* bm_inW_bf  = fm_inW_bf + (size_t)2048 * DMODEL;
    unsigned short* fm_xpW_bf  = bm_inW_bf + (size_t)2048 * DMODEL;
    unsigned short* bm_xpW_bf  = fm_xpW_bf + (size_t)64 * DINNER;
    // Post-scan overlays
    float* proj_f = scanP;
    float* proj_b = scanH;
    float* ff2    = scanCy;
    unsigned short* fm_outW_bf = (unsigned short*)xz_f;
    unsigned short* bm_outW_bf = fm_outW_bf + (size_t)DMODEL * DINNER;
    unsigned short* W1_bf      = bm_outW_bf + (size_t)DMODEL * DINNER;
    unsigned short* W2_bf      = W1_bf + (size_t)DFF * DMODEL;
    unsigned short* outsum_bf  = (unsigned short*)xz_b;
    unsigned short* h_bf       = (unsigned short*)yT_f;

    // ---- 0. bf16 casts ----
    cast_f2b_kernel<<<(MM*DMODEL)/2048, 256, 0, stream>>>(x, x_bf, MM*DMODEL);
    cast_f2b_kernel<<<(2048*DMODEL)/2048, 256, 0, stream>>>(fm_in_W, fm_inW_bf, 2048*DMODEL);
    cast_f2b_kernel<<<(2048*DMODEL)/2048, 256, 0, stream>>>(bm_in_W, bm_inW_bf, 2048*DMODEL);
    cast_f2b_kernel<<<(64*DINNER)/2048, 256, 0, stream>>>(fm_xproj_W, fm_xpW_bf, 64*DINNER);
    cast_f2b_kernel<<<(64*DINNER)/2048, 256, 0, stream>>>(bm_xproj_W, bm_xpW_bf, 64*DINNER);

    // ---- 1. in-proj GEMMs, both dirs in one dispatch (512 blocks) ----
    gemm_mfma_batch<0,0><<<dim3(2048/128, MM/128, 2), 256, 0, stream>>>(
        MM, 2048, DMODEL, x_bf, x_bf, DMODEL, fm_inW_bf, bm_inW_bf, DMODEL,
        nullptr, xz_f, xz_b, 2048);

    // ---- 2. conv + silu -> bf16 xm[m][d]; transpose -> xmT[d][m] ----
    conv_silu_kernel<<<(MM * DINNER) / 256, 256, 0, stream>>>(
        xz_f, fm_conv_W, fm_conv_b, xm_bf_f, 0);
    conv_silu_kernel<<<(MM * DINNER) / 256, 256, 0, stream>>>(
        xz_b, bm_conv_W, bm_conv_b, xm_bf_b, 1);
    transpose_bf16_kernel<<<dim3(DINNER/32, MM/32), 256, 0, stream>>>(
        xm_bf_f, xmT_f, MM, DINNER);
    transpose_bf16_kernel<<<dim3(DINNER/32, MM/32), 256, 0, stream>>>(
        xm_bf_b, xmT_b, MM, DINNER);

    // ---- 3. x-proj: split-K x4, both dirs (128 blocks) + reduce ----
    xproj_splitk_kernel<<<dim3(MM/128, 8), 256, 0, stream>>>(
        xm_bf_f, xm_bf_b, fm_xpW_bf, bm_xpW_bf, gpart);
    xproj_reduce_kernel<<<dim3((MM*64)/1024, 2), 256, 0, stream>>>(
        gpart, dbc_f, dbc_b, dbcT_f, dbcT_b);

    // ---- 4. dt-proj (fp32, writes deltaT[d][m] directly, softplus) ----
    gemm_kernel<2><<<dim3(MM/64, DINNER/64), 256, 0, stream>>>(
        DINNER, MM, DTRANK, fm_dt_W, DTRANK, dbc_f, 64, fm_dt_b, deltaT_f, MM);
    gemm_kernel<2><<<dim3(MM/64, DINNER/64), 256, 0, stream>>>(
        DINNER, MM, DTRANK, bm_dt_W, DTRANK, dbc_b, 64, bm_dt_b, deltaT_b, MM);

    // ---- 5. chunked selective scan ----
    scan_phase1_kernel<0><<<dim3(DINNER/16, BATCH*NCHUNK), 256, 0, stream>>>(
        deltaT_f, xmT_f, dbcT_f, fm_A_log, scanP, scanH);
    scan_phase1_kernel<1><<<dim3(DINNER/16, BATCH*NCHUNK), 256, 0, stream>>>(
        deltaT_b, xmT_b, dbcT_b, bm_A_log, scanP, scanH);
    scan_carry_kernel<<<GTOT/256, 256, 0, stream>>>(scanP, scanH, scanCy);
    scan_phase3_kernel<0><<<dim3(DINNER/16, BATCH*NCHUNK), 256, 0, stream>>>(
        deltaT_f, xmT_f, dbcT_f, fm_A_log, fm_D, scanCy, yT_f);
    scan_phase3_kernel<1><<<dim3(DINNER/16, BATCH*NCHUNK), 256, 0, stream>>>(
        deltaT_b, xmT_b, dbcT_b, bm_A_log, bm_D, scanCy, yT_b);

    // ---- 6. y * silu(z), transpose -> y_bf[m][d] ----
    y_silu_transpose_kernel<<<dim3(MM/32, DINNER/32), 256, 0, stream>>>(
        yT_f, xz_f, ybf_f);
    y_silu_transpose_kernel<<<dim3(MM/32, DINNER/32), 256, 0, stream>>>(
        yT_b, xz_b, ybf_b);

    // ---- 6b. weight casts (xz now dead) ----
    cast_f2b_kernel<<<(DMODEL*DINNER)/2048, 256, 0, stream>>>(fm_out_W, fm_outW_bf, DMODEL*DINNER);
    cast_f2b_kernel<<<(DMODEL*DINNER)/2048, 256, 0, stream>>>(bm_out_W, bm_outW_bf, DMODEL*DINNER);
    cast_f2b_kernel<<<(DFF*DMODEL)/2048, 256, 0, stream>>>(ff_W1, W1_bf, DFF*DMODEL);
    cast_f2b_kernel<<<(DMODEL*DFF)/2048, 256, 0, stream>>>(ff_W2, W2_bf, DMODEL*DFF);

    // ---- 7. out-proj: dirs x splitK2 (256 blocks) + reduces ----
    gemm_mfma_splitk<2><<<dim3(DMODEL/128, MM/128, 4), 256, 0, stream>>>(
        MM, DMODEL, DINNER, ybf_f, ybf_b, DINNER, fm_outW_bf, bm_outW_bf, DINNER,
        gpart, DMODEL);
    reduce_splitk_kernel<<<(MM*DMODEL)/1024, 256, 0, stream>>>(
        gpart, 2, MM*DMODEL, DMODEL, nullptr, proj_f);
    reduce_splitk_kernel<<<(MM*DMODEL)/1024, 256, 0, stream>>>(
        gpart + (size_t)2*MM*DMODEL, 2, MM*DMODEL, DMODEL, nullptr, proj_b);

    // ---- 8. out = LN(xf+fwd) + LN(xf+bwd) -> bf16 ----
    ln_combine_kernel<<<MM, 256, 0, stream>>>(
        x, proj_f, proj_b, ln1_g, ln1_b, ln2_g, ln2_b, outsum_bf);

    // ---- 9. FF1 (256 blocks, direct) ----
    gemm_mfma_batch<1,1><<<dim3(DFF/128, MM/128, 1), 256, 0, stream>>>(
        MM, DFF, DMODEL, outsum_bf, outsum_bf, DMODEL, W1_bf, W1_bf, DMODEL,
        ff_b1, h_bf, h_bf, DFF);

    // ---- 10. FF2: splitK4 (256 blocks) + reduce w/ bias ----
    gemm_mfma_splitk<4><<<dim3(DMODEL/128, MM/128, 4), 256, 0, stream>>>(
        MM, DMODEL, DFF, h_bf, h_bf, DFF, W2_bf, W2_bf, DFF, gpart, DMODEL);
    reduce_splitk_kernel<<<(MM*DMODEL)/1024, 256, 0, stream>>>(
        gpart, 4, MM*DMODEL, DMODEL, ff_b2, ff2);

    // ---- 11. final LN(2*ff) ----
    ln_final_kernel<<<MM, 256, 0, stream>>>(ff2, ln3_g, ln3_b, out);
}

// Round 6
// 402.313 us; speedup vs baseline: 3.6003x; 1.0744x over previous
//
#include <hip/hip_runtime.h>
#include <hip/hip_bf16.h>
#include <math.h>

// Problem constants
#define MM 2048        // B*W flattened rows
#define BATCH 2
#define SEQ 1024
#define DMODEL 512
#define DINNER 1024
#define DSTATE 16
#define DTRANK 32
#define DFF 2048

// Chunked-scan constants
#define NCHUNK 16
#define CHUNK 64
#define GTOT 65536          // 2 dirs * BATCH * DINNER * DSTATE

typedef short bf16x8 __attribute__((ext_vector_type(8)));
typedef float floatx4 __attribute__((ext_vector_type(4)));
typedef unsigned short ushort8v __attribute__((ext_vector_type(8)));

__device__ __forceinline__ unsigned short f2bf(float f) {
    union { float f; unsigned u; } v; v.f = f;
    unsigned r = v.u + 0x7FFF + ((v.u >> 16) & 1);
    return (unsigned short)(r >> 16);
}
__device__ __forceinline__ float bf2f(unsigned short u) {
    union { unsigned u; float f; } v; v.u = ((unsigned)u) << 16; return v.f;
}

// Sum across each 16-lane DPP row via row_ror adds: VALU-only (no LDS pipe,
// no lgkmcnt waits). After 4 steps every lane in the row holds the row total.
__device__ __forceinline__ float rowsum16(float x) {
    union { float f; int i; } a, b;
    a.f = x;
    b.i = __builtin_amdgcn_update_dpp(0, a.i, 0x128, 0xF, 0xF, false); a.f += b.f; // ror:8
    b.i = __builtin_amdgcn_update_dpp(0, a.i, 0x124, 0xF, 0xF, false); a.f += b.f; // ror:4
    b.i = __builtin_amdgcn_update_dpp(0, a.i, 0x122, 0xF, 0xF, false); a.f += b.f; // ror:2
    b.i = __builtin_amdgcn_update_dpp(0, a.i, 0x121, 0xF, 0xF, false); a.f += b.f; // ror:1
    return a.f;
}

#define GLOAD_LDS16(gp, lp) __builtin_amdgcn_global_load_lds( \
    (const __attribute__((address_space(1))) unsigned int*)(gp), \
    (__attribute__((address_space(3))) unsigned int*)(lp), 16, 0, 0)

// ---------------------------------------------------------------------------
// Batched direct bf16 MFMA GEMM: C[z][M,N] = epi(A[z] @ B[z]^T + bias)
// 128x128 tile, BK=32, 4 waves x (4x4) 16x16x32. Conflict-free LDS layout.
// ---------------------------------------------------------------------------
template<int EPI, int OUTBF16>
__global__ __launch_bounds__(256) void gemm_mfma_batch(
    int M, int N, int K,
    const unsigned short* __restrict__ A0, const unsigned short* __restrict__ A1, int lda,
    const unsigned short* __restrict__ B0, const unsigned short* __restrict__ B1, int ldb,
    const float* __restrict__ bias,
    void* __restrict__ C0, void* __restrict__ C1, int ldc)
{
    __shared__ unsigned short As[128 * 32];
    __shared__ unsigned short Bs[128 * 32];
    const int z = blockIdx.z;
    const unsigned short* A = z ? A1 : A0;
    const unsigned short* B = z ? B1 : B0;
    void* Cout = z ? C1 : C0;
    const int tid  = threadIdx.x;
    const int wave = tid >> 6;
    const int lane = tid & 63;
    const int bm = blockIdx.y * 128;
    const int bn = blockIdx.x * 128;

    const int strow = lane & 15;
    const int stkc  = lane >> 4;
    const int wr = wave >> 1, wc = wave & 1;
    const int frow = lane & 15;
    const int fkc  = lane >> 4;

    floatx4 acc[4][4];
    #pragma unroll
    for (int i = 0; i < 4; ++i)
        #pragma unroll
        for (int j = 0; j < 4; ++j)
            acc[i][j] = (floatx4){0.f, 0.f, 0.f, 0.f};

    for (int k0 = 0; k0 < K; k0 += 32) {
        __syncthreads();
        #pragma unroll
        for (int q = 0; q < 2; ++q) {
            int g = wave * 2 + q;
            GLOAD_LDS16(A + (size_t)(bm + g * 16 + strow) * lda + k0 + stkc * 8,
                        As + g * 512);
        }
        #pragma unroll
        for (int q = 0; q < 2; ++q) {
            int g = wave * 2 + q;
            GLOAD_LDS16(B + (size_t)(bn + g * 16 + strow) * ldb + k0 + stkc * 8,
                        Bs + g * 512);
        }
        __syncthreads();

        bf16x8 af[4], bfr[4];
        #pragma unroll
        for (int i = 0; i < 4; ++i)
            af[i] = *(const bf16x8*)(As + (wr * 4 + i) * 512 + fkc * 128 + frow * 8);
        #pragma unroll
        for (int j = 0; j < 4; ++j)
            bfr[j] = *(const bf16x8*)(Bs + (wc * 4 + j) * 512 + fkc * 128 + frow * 8);
        #pragma unroll
        for (int i = 0; i < 4; ++i)
            #pragma unroll
            for (int j = 0; j < 4; ++j)
                acc[i][j] = __builtin_amdgcn_mfma_f32_16x16x32_bf16(
                    af[i], bfr[j], acc[i][j], 0, 0, 0);
    }

    const int orow0 = bm + wr * 64 + (lane >> 4) * 4;
    const int ocol0 = bn + wc * 64 + (lane & 15);
    #pragma unroll
    for (int j = 0; j < 4; ++j) {
        const int col = ocol0 + j * 16;
        const float bv = bias ? bias[col] : 0.f;
        #pragma unroll
        for (int i = 0; i < 4; ++i) {
            #pragma unroll
            for (int r = 0; r < 4; ++r) {
                int row = orow0 + i * 16 + r;
                float t = acc[i][j][r] + bv;
                if (EPI == 1) t = fmaxf(t, 0.f);
                if (OUTBF16)
                    ((unsigned short*)Cout)[(size_t)row * ldc + col] = f2bf(t);
                else
                    ((float*)Cout)[(size_t)row * ldc + col] = t;
            }
        }
    }
}

// ---------------------------------------------------------------------------
// Split-K batched MFMA GEMM -> fp32 partials part[z][M*ldc]. z=dir*NSPLIT+sp.
// ---------------------------------------------------------------------------
template<int NSPLIT>
__global__ __launch_bounds__(256) void gemm_mfma_splitk(
    int M, int N, int K,
    const unsigned short* __restrict__ A0, const unsigned short* __restrict__ A1, int lda,
    const unsigned short* __restrict__ B0, const unsigned short* __restrict__ B1, int ldb,
    float* __restrict__ part, int ldc)
{
    __shared__ unsigned short As[128 * 32];
    __shared__ unsigned short Bs[128 * 32];
    const int z = blockIdx.z;
    const int dir = z / NSPLIT, sp = z % NSPLIT;
    const unsigned short* A = dir ? A1 : A0;
    const unsigned short* B = dir ? B1 : B0;
    float* Cp = part + (size_t)z * M * ldc;
    const int kbeg = sp * (K / NSPLIT);
    const int kend = kbeg + (K / NSPLIT);
    const int tid  = threadIdx.x;
    const int wave = tid >> 6;
    const int lane = tid & 63;
    const int bm = blockIdx.y * 128;
    const int bn = blockIdx.x * 128;

    const int strow = lane & 15;
    const int stkc  = lane >> 4;
    const int wr = wave >> 1, wc = wave & 1;
    const int frow = lane & 15;
    const int fkc  = lane >> 4;

    floatx4 acc[4][4];
    #pragma unroll
    for (int i = 0; i < 4; ++i)
        #pragma unroll
        for (int j = 0; j < 4; ++j)
            acc[i][j] = (floatx4){0.f, 0.f, 0.f, 0.f};

    for (int k0 = kbeg; k0 < kend; k0 += 32) {
        __syncthreads();
        #pragma unroll
        for (int q = 0; q < 2; ++q) {
            int g = wave * 2 + q;
            GLOAD_LDS16(A + (size_t)(bm + g * 16 + strow) * lda + k0 + stkc * 8,
                        As + g * 512);
        }
        #pragma unroll
        for (int q = 0; q < 2; ++q) {
            int g = wave * 2 + q;
            GLOAD_LDS16(B + (size_t)(bn + g * 16 + strow) * ldb + k0 + stkc * 8,
                        Bs + g * 512);
        }
        __syncthreads();

        bf16x8 af[4], bfr[4];
        #pragma unroll
        for (int i = 0; i < 4; ++i)
            af[i] = *(const bf16x8*)(As + (wr * 4 + i) * 512 + fkc * 128 + frow * 8);
        #pragma unroll
        for (int j = 0; j < 4; ++j)
            bfr[j] = *(const bf16x8*)(Bs + (wc * 4 + j) * 512 + fkc * 128 + frow * 8);
        #pragma unroll
        for (int i = 0; i < 4; ++i)
            #pragma unroll
            for (int j = 0; j < 4; ++j)
                acc[i][j] = __builtin_amdgcn_mfma_f32_16x16x32_bf16(
                    af[i], bfr[j], acc[i][j], 0, 0, 0);
    }

    const int orow0 = bm + wr * 64 + (lane >> 4) * 4;
    const int ocol0 = bn + wc * 64 + (lane & 15);
    #pragma unroll
    for (int j = 0; j < 4; ++j) {
        const int col = ocol0 + j * 16;
        #pragma unroll
        for (int i = 0; i < 4; ++i)
            #pragma unroll
            for (int r = 0; r < 4; ++r)
                Cp[(size_t)(orow0 + i * 16 + r) * ldc + col] = acc[i][j][r];
    }
}

// ---------------------------------------------------------------------------
// Split-K reduce (generic): out[i] = sum_s part[s][i] (+ bias[i%ldc]).
// ---------------------------------------------------------------------------
__global__ __launch_bounds__(256) void reduce_splitk_kernel(
    const float* __restrict__ part, int nsplit, int elems, int ldc,
    const float* __restrict__ bias, float* __restrict__ out)
{
    int i = (blockIdx.x * 256 + threadIdx.x) * 4;
    if (i >= elems) return;
    float4 a = *(const float4*)(part + i);
    for (int s = 1; s < nsplit; ++s) {
        float4 t = *(const float4*)(part + (size_t)s * elems + i);
        a.x += t.x; a.y += t.y; a.z += t.z; a.w += t.w;
    }
    if (bias) {
        int c = i % ldc;
        a.x += bias[c]; a.y += bias[c + 1]; a.z += bias[c + 2]; a.w += bias[c + 3];
    }
    *(float4*)(out + i) = a;
}

// Dual split-K2 reduce for out-proj: blockIdx.y = dir.
__global__ __launch_bounds__(256) void reduce_splitk2_dual_kernel(
    const float* __restrict__ part, float* __restrict__ out0, float* __restrict__ out1)
{
    const int dir = blockIdx.y;
    const int i = (blockIdx.x * 256 + threadIdx.x) * 4;
    const float* p = part + (size_t)dir * 2 * (MM * DMODEL);
    float4 a = *(const float4*)(p + i);
    float4 t = *(const float4*)(p + (size_t)(MM * DMODEL) + i);
    a.x += t.x; a.y += t.y; a.z += t.z; a.w += t.w;
    float* out = dir ? out1 : out0;
    *(float4*)(out + i) = a;
}

// ---------------------------------------------------------------------------
// xproj split-K MFMA: tile 128(m) x 64(n), K slice 256. blockIdx.y=dir*4+sp.
// ---------------------------------------------------------------------------
__global__ __launch_bounds__(256) void xproj_splitk_kernel(
    const unsigned short* __restrict__ A_f, const unsigned short* __restrict__ A_b,
    const unsigned short* __restrict__ Wf,  const unsigned short* __restrict__ Wb,
    float* __restrict__ part)
{
    __shared__ unsigned short As[128 * 32];
    __shared__ unsigned short Bs[64 * 32];
    const int tid = threadIdx.x, wave = tid >> 6, lane = tid & 63;
    const int bm = blockIdx.x * 128;
    const int dir = blockIdx.y >> 2, sp = blockIdx.y & 3;
    const unsigned short* A = dir ? A_b : A_f;
    const unsigned short* W = dir ? Wb  : Wf;
    float* Cp = part + (size_t)blockIdx.y * MM * 64;
    const int kbeg = sp * 256, kend = kbeg + 256;

    const int strow = lane & 15;
    const int stkc  = lane >> 4;
    const int frow = lane & 15;
    const int fkc  = lane >> 4;

    floatx4 acc[2][4];
    #pragma unroll
    for (int i = 0; i < 2; ++i)
        #pragma unroll
        for (int j = 0; j < 4; ++j)
            acc[i][j] = (floatx4){0.f, 0.f, 0.f, 0.f};

    for (int k0 = kbeg; k0 < kend; k0 += 32) {
        __syncthreads();
        #pragma unroll
        for (int q = 0; q < 2; ++q) {
            int g = wave * 2 + q;
            GLOAD_LDS16(A + (size_t)(bm + g * 16 + strow) * DINNER + k0 + stkc * 8,
                        As + g * 512);
        }
        GLOAD_LDS16(W + (size_t)(wave * 16 + strow) * DINNER + k0 + stkc * 8,
                    Bs + wave * 512);
        __syncthreads();

        bf16x8 af[2], bfr[4];
        #pragma unroll
        for (int i = 0; i < 2; ++i)
            af[i] = *(const bf16x8*)(As + (wave * 2 + i) * 512 + fkc * 128 + frow * 8);
        #pragma unroll
        for (int j = 0; j < 4; ++j)
            bfr[j] = *(const bf16x8*)(Bs + j * 512 + fkc * 128 + frow * 8);
        #pragma unroll
        for (int i = 0; i < 2; ++i)
            #pragma unroll
            for (int j = 0; j < 4; ++j)
                acc[i][j] = __builtin_amdgcn_mfma_f32_16x16x32_bf16(
                    af[i], bfr[j], acc[i][j], 0, 0, 0);
    }

    const int orow0 = bm + wave * 32 + (lane >> 4) * 4;
    #pragma unroll
    for (int j = 0; j < 4; ++j) {
        const int col = (lane & 15) + j * 16;
        #pragma unroll
        for (int i = 0; i < 2; ++i)
            #pragma unroll
            for (int r = 0; r < 4; ++r)
                Cp[(size_t)(orow0 + i * 16 + r) * 64 + col] = acc[i][j][r];
    }
}

// ---------------------------------------------------------------------------
// xproj reduce: dbc[m][64] = sum of 4 parts; also writes dbcT[64][MM].
// ---------------------------------------------------------------------------
__global__ __launch_bounds__(256) void xproj_reduce_kernel(
    const float* __restrict__ part,
    float* __restrict__ dbc_f, float* __restrict__ dbc_b,
    float* __restrict__ dbcT_f, float* __restrict__ dbcT_b)
{
    const int dir = blockIdx.y;
    const int i = (blockIdx.x * 256 + threadIdx.x) * 4;
    const float* p = part + (size_t)dir * 4 * (MM * 64);
    float4 a = *(const float4*)(p + i);
    #pragma unroll
    for (int s = 1; s < 4; ++s) {
        float4 t = *(const float4*)(p + (size_t)s * (MM * 64) + i);
        a.x += t.x; a.y += t.y; a.z += t.z; a.w += t.w;
    }
    float* dbc  = dir ? dbc_b  : dbc_f;
    float* dbcT = dir ? dbcT_b : dbcT_f;
    *(float4*)(dbc + i) = a;
    const int m = i >> 6, c = i & 63;
    dbcT[(size_t)(c + 0) * MM + m] = a.x;
    dbcT[(size_t)(c + 1) * MM + m] = a.y;
    dbcT[(size_t)(c + 2) * MM + m] = a.z;
    dbcT[(size_t)(c + 3) * MM + m] = a.w;
}

// ---------------------------------------------------------------------------
// Batched fp32 GEMM w/ softplus + row bias (dt-proj): blockIdx.z = dir.
// C[z][M,N] = softplus(A[z][M,K] @ B[z][N,K]^T + biasR[row])
// ---------------------------------------------------------------------------
__global__ __launch_bounds__(256) void dtproj_batch_kernel(
    int M, int N, int K,
    const float* __restrict__ A0, const float* __restrict__ A1, int lda,
    const float* __restrict__ B0, const float* __restrict__ B1, int ldb,
    const float* __restrict__ bias0, const float* __restrict__ bias1,
    float* __restrict__ C0, float* __restrict__ C1, int ldc)
{
    __shared__ float As[16][64];
    __shared__ float Bs[16][64];
    const int z = blockIdx.z;
    const float* A = z ? A1 : A0;
    const float* B = z ? B1 : B0;
    const float* biasR = z ? bias1 : bias0;
    float* C = z ? C1 : C0;
    const int tid = threadIdx.x;
    const int tx = tid & 15, ty = tid >> 4;
    const int bm = blockIdx.y * 64, bn = blockIdx.x * 64;
    const int lm = tid & 63;
    const int lk = (tid >> 6) * 4;
    const float* Arow = A + (size_t)(bm + lm) * lda + lk;
    const float* Brow = B + (size_t)(bn + lm) * ldb + lk;
    float acc[4][4] = {};
    for (int k0 = 0; k0 < K; k0 += 16) {
        float4 av = *(const float4*)(Arow + k0);
        float4 bv = *(const float4*)(Brow + k0);
        __syncthreads();
        As[lk+0][lm] = av.x; As[lk+1][lm] = av.y; As[lk+2][lm] = av.z; As[lk+3][lm] = av.w;
        Bs[lk+0][lm] = bv.x; Bs[lk+1][lm] = bv.y; Bs[lk+2][lm] = bv.z; Bs[lk+3][lm] = bv.w;
        __syncthreads();
        #pragma unroll
        for (int k = 0; k < 16; ++k) {
            float4 a = *(const float4*)(&As[k][ty*4]);
            float4 b = *(const float4*)(&Bs[k][tx*4]);
            float ar[4] = {a.x,a.y,a.z,a.w};
            float br[4] = {b.x,b.y,b.z,b.w};
            #pragma unroll
            for (int i = 0; i < 4; ++i)
                #pragma unroll
                for (int j = 0; j < 4; ++j)
                    acc[i][j] = fmaf(ar[i], br[j], acc[i][j]);
        }
    }
    const int row0 = bm + ty*4, col0 = bn + tx*4;
    #pragma unroll
    for (int i = 0; i < 4; ++i) {
        float br = biasR[row0 + i];
        float4 o;
        float v[4];
        #pragma unroll
        for (int j = 0; j < 4; ++j) {
            float t = acc[i][j] + br;
            v[j] = fmaxf(t, 0.f) + log1pf(__expf(-fabsf(t)));
        }
        o.x = v[0]; o.y = v[1]; o.z = v[2]; o.w = v[3];
        *(float4*)(C + (size_t)(row0 + i) * ldc + col0) = o;
    }
}

// ---------------------------------------------------------------------------
// Segmented casts: 5 pre-GEMM arrays -> one contiguous bf16 block.
// Segments: x(1048576) inW_f(1048576) inW_b(1048576) xpW_f(65536) xpW_b(65536)
// ---------------------------------------------------------------------------
__global__ __launch_bounds__(256) void cast_pre_kernel(
    const float* __restrict__ x, const float* __restrict__ w0,
    const float* __restrict__ w1, const float* __restrict__ xp0,
    const float* __restrict__ xp1, unsigned short* __restrict__ dst)
{
    int i = (blockIdx.x * 256 + threadIdx.x) * 8;
    const float* src; int off;
    if      (i < 1048576) { src = x;   off = 0; }
    else if (i < 2097152) { src = w0;  off = 1048576; }
    else if (i < 3145728) { src = w1;  off = 2097152; }
    else if (i < 3211264) { src = xp0; off = 3145728; }
    else                  { src = xp1; off = 3211264; }
    float4 a = *(const float4*)(src + i - off);
    float4 b = *(const float4*)(src + i - off + 4);
    ushort8v o;
    o[0] = f2bf(a.x); o[1] = f2bf(a.y); o[2] = f2bf(a.z); o[3] = f2bf(a.w);
    o[4] = f2bf(b.x); o[5] = f2bf(b.y); o[6] = f2bf(b.z); o[7] = f2bf(b.w);
    *(ushort8v*)(dst + i) = o;
}

// Segments: outW_f(524288) outW_b(524288) W1(1048576) W2(1048576)
__global__ __launch_bounds__(256) void cast_post_kernel(
    const float* __restrict__ w0, const float* __restrict__ w1,
    const float* __restrict__ w2, const float* __restrict__ w3,
    unsigned short* __restrict__ dst)
{
    int i = (blockIdx.x * 256 + threadIdx.x) * 8;
    const float* src; int off;
    if      (i < 524288)  { src = w0; off = 0; }
    else if (i < 1048576) { src = w1; off = 524288; }
    else if (i < 2097152) { src = w2; off = 1048576; }
    else                  { src = w3; off = 2097152; }
    float4 a = *(const float4*)(src + i - off);
    float4 b = *(const float4*)(src + i - off + 4);
    ushort8v o;
    o[0] = f2bf(a.x); o[1] = f2bf(a.y); o[2] = f2bf(a.z); o[3] = f2bf(a.w);
    o[4] = f2bf(b.x); o[5] = f2bf(b.y); o[6] = f2bf(b.z); o[7] = f2bf(b.w);
    *(ushort8v*)(dst + i) = o;
}

// ---------------------------------------------------------------------------
// Depthwise conv + bias + silu -> bf16 xm[m][d]. blockIdx.y = dir.
// ---------------------------------------------------------------------------
__global__ __launch_bounds__(256) void conv_silu_kernel(
    const float* __restrict__ xz_f, const float* __restrict__ xz_b,
    const float* __restrict__ Wf,   const float* __restrict__ Wb,
    const float* __restrict__ cbf,  const float* __restrict__ cbb,
    unsigned short* __restrict__ of, unsigned short* __restrict__ ob)
{
    const int dir = blockIdx.y;
    const float* xz = dir ? xz_b : xz_f;
    const float* convW = dir ? Wb : Wf;
    const float* convb = dir ? cbb : cbf;
    unsigned short* xm_bf = dir ? ob : of;
    int gid = blockIdx.x * 256 + threadIdx.x;
    int c = gid & (DINNER - 1);
    int m = gid >> 10;
    int b = m >> 10;
    int l = m & (SEQ - 1);
    float4 wv = *(const float4*)(convW + c * 4);
    float w[4] = {wv.x, wv.y, wv.z, wv.w};
    float acc = convb[c];
    #pragma unroll
    for (int j = 0; j < 4; ++j) {
        int p = dir ? (l + 3 - j) : (l - 3 + j);
        if (p >= 0 && p < SEQ)
            acc = fmaf(xz[(size_t)(b * SEQ + p) * 2048 + c], w[j], acc);
    }
    float sig = 1.f / (1.f + __expf(-acc));
    xm_bf[(size_t)m * DINNER + c] = f2bf(acc * sig);
}

// ---------------------------------------------------------------------------
// bf16 transpose (both dirs): in[R][C] -> out[C][R]. blockIdx.z = dir.
// ---------------------------------------------------------------------------
__global__ __launch_bounds__(256) void transpose_bf16_kernel(
    const unsigned short* __restrict__ in0, const unsigned short* __restrict__ in1,
    unsigned short* __restrict__ out0, unsigned short* __restrict__ out1,
    int R, int C)
{
    __shared__ unsigned short t[32][34];
    const unsigned short* in = blockIdx.z ? in1 : in0;
    unsigned short* out = blockIdx.z ? out1 : out0;
    const int c0 = blockIdx.x * 32, r0 = blockIdx.y * 32;
    const int tx = threadIdx.x & 31, ty = threadIdx.x >> 5;
    #pragma unroll
    for (int rr = 0; rr < 32; rr += 8)
        t[ty + rr][tx] = in[(size_t)(r0 + ty + rr) * C + c0 + tx];
    __syncthreads();
    #pragma unroll
    for (int rr = 0; rr < 32; rr += 8)
        out[(size_t)(c0 + ty + rr) * R + r0 + tx] = t[tx][ty + rr];
}

// ---------------------------------------------------------------------------
// Scan phase 1 body (compile-time DIR): P = exp(A*sum dl), H = local scan.
// ---------------------------------------------------------------------------
template<int DIR>
__device__ __forceinline__ void scan1_body(
    const float* __restrict__ deltaT, const unsigned short* __restrict__ xmT,
    const float* __restrict__ dbcT,   const float* __restrict__ Alog,
    float* __restrict__ Pout, float* __restrict__ Hout)
{
    const int tid = threadIdx.x;
    const int s = tid & 15;
    const int dloc = tid >> 4;
    const int d = blockIdx.x * 16 + dloc;
    const int b = blockIdx.y / NCHUNK;
    const int c = blockIdx.y % NCHUNK;

    const float A = -__expf(Alog[d * DSTATE + s]);
    const float* dRow = deltaT + (size_t)d * MM + b * SEQ;
    const unsigned short* xRow = xmT + (size_t)d * MM + b * SEQ;
    const float* bRow = dbcT + (size_t)(DTRANK + s) * MM + b * SEQ;

    float h = 0.f, sdl = 0.f;
    const int segBase = DIR ? (SEQ - CHUNK - c * CHUNK) : (c * CHUNK);
    for (int ii = 0; ii < CHUNK; ii += 8) {
        const int off = DIR ? (segBase + (CHUNK - 8) - ii) : (segBase + ii);
        float4 d0 = *(const float4*)(dRow + off);
        float4 d1 = *(const float4*)(dRow + off + 4);
        float4 b0 = *(const float4*)(bRow + off);
        float4 b1 = *(const float4*)(bRow + off + 4);
        ushort8v x8 = *(const ushort8v*)(xRow + off);
        float dl[8] = {d0.x,d0.y,d0.z,d0.w,d1.x,d1.y,d1.z,d1.w};
        float Bv[8] = {b0.x,b0.y,b0.z,b0.w,b1.x,b1.y,b1.z,b1.w};
        #pragma unroll
        for (int u = 0; u < 8; ++u) {
            const int t = DIR ? (7 - u) : u;
            float dA = __expf(dl[t] * A);
            sdl += dl[t];
            h = fmaf(dA, h, dl[t] * Bv[t] * bf2f(x8[t]));
        }
    }
    const int g = ((DIR * BATCH + b) * DINNER + d) * DSTATE + s;
    Pout[(size_t)c * GTOT + g] = __expf(sdl * A);
    Hout[(size_t)c * GTOT + g] = h;
}

__global__ __launch_bounds__(256) void scan_phase1_kernel(
    const float* __restrict__ dT_f, const float* __restrict__ dT_b,
    const unsigned short* __restrict__ xT_f, const unsigned short* __restrict__ xT_b,
    const float* __restrict__ dbcT_f, const float* __restrict__ dbcT_b,
    const float* __restrict__ Alog_f, const float* __restrict__ Alog_b,
    float* __restrict__ Pout, float* __restrict__ Hout)
{
    if (blockIdx.z == 0) scan1_body<0>(dT_f, xT_f, dbcT_f, Alog_f, Pout, Hout);
    else                 scan1_body<1>(dT_b, xT_b, dbcT_b, Alog_b, Pout, Hout);
}

// ---------------------------------------------------------------------------
// Phase 2: sequential combine over chunks.
// ---------------------------------------------------------------------------
__global__ __launch_bounds__(256) void scan_carry_kernel(
    const float* __restrict__ P, const float* __restrict__ H,
    float* __restrict__ carry)
{
    const int g = blockIdx.x * 256 + threadIdx.x;
    float h = 0.f;
    #pragma unroll
    for (int c = 0; c < NCHUNK; ++c) {
        carry[(size_t)c * GTOT + g] = h;
        h = fmaf(P[(size_t)c * GTOT + g], h, H[(size_t)c * GTOT + g]);
    }
}

// ---------------------------------------------------------------------------
// Phase 3 body: rescan from carry; DPP rowsum for state reduction;
// writes raw y (pre-silu(z)) as fp32 yT[d][m].
// ---------------------------------------------------------------------------
template<int DIR>
__device__ __forceinline__ void scan3_body(
    const float* __restrict__ deltaT, const unsigned short* __restrict__ xmT,
    const float* __restrict__ dbcT,   const float* __restrict__ Alog,
    const float* __restrict__ Dv,     const float* __restrict__ carry,
    float* __restrict__ yT)
{
    const int tid = threadIdx.x;
    const int s = tid & 15;
    const int dloc = tid >> 4;
    const int d = blockIdx.x * 16 + dloc;
    const int b = blockIdx.y / NCHUNK;
    const int c = blockIdx.y % NCHUNK;

    const float A  = -__expf(Alog[d * DSTATE + s]);
    const float Dp = Dv[d];
    const float* dRow = deltaT + (size_t)d * MM + b * SEQ;
    const unsigned short* xRow = xmT + (size_t)d * MM + b * SEQ;
    const float* bRow = dbcT + (size_t)(DTRANK + s) * MM + b * SEQ;
    const float* cRow = dbcT + (size_t)(DTRANK + DSTATE + s) * MM + b * SEQ;
    float* yRow = yT + (size_t)d * MM + b * SEQ;

    const int g = ((DIR * BATCH + b) * DINNER + d) * DSTATE + s;
    float h = carry[(size_t)c * GTOT + g];

    const int segBase = DIR ? (SEQ - CHUNK - c * CHUNK) : (c * CHUNK);
    for (int ii = 0; ii < CHUNK; ii += 8) {
        const int off = DIR ? (segBase + (CHUNK - 8) - ii) : (segBase + ii);
        float4 d0 = *(const float4*)(dRow + off);
        float4 d1 = *(const float4*)(dRow + off + 4);
        float4 b0 = *(const float4*)(bRow + off);
        float4 b1 = *(const float4*)(bRow + off + 4);
        float4 c0 = *(const float4*)(cRow + off);
        float4 c1 = *(const float4*)(cRow + off + 4);
        ushort8v x8 = *(const ushort8v*)(xRow + off);
        float dl[8] = {d0.x,d0.y,d0.z,d0.w,d1.x,d1.y,d1.z,d1.w};
        float Bv[8] = {b0.x,b0.y,b0.z,b0.w,b1.x,b1.y,b1.z,b1.w};
        float Cv[8] = {c0.x,c0.y,c0.z,c0.w,c1.x,c1.y,c1.z,c1.w};
        float yv[8];
        #pragma unroll
        for (int u = 0; u < 8; ++u) {
            const int t = DIR ? (7 - u) : u;
            float xv = bf2f(x8[t]);
            float dA = __expf(dl[t] * A);
            h = fmaf(dA, h, dl[t] * Bv[t] * xv);
            float part = rowsum16(h * Cv[t]);
            yv[t] = fmaf(xv, Dp, part);
        }
        if (s == 0) {
            *(float4*)(yRow + off)     = (float4){yv[0], yv[1], yv[2], yv[3]};
            *(float4*)(yRow + off + 4) = (float4){yv[4], yv[5], yv[6], yv[7]};
        }
    }
}

__global__ __launch_bounds__(256) void scan_phase3_kernel(
    const float* __restrict__ dT_f, const float* __restrict__ dT_b,
    const unsigned short* __restrict__ xT_f, const unsigned short* __restrict__ xT_b,
    const float* __restrict__ dbcT_f, const float* __restrict__ dbcT_b,
    const float* __restrict__ Alog_f, const float* __restrict__ Alog_b,
    const float* __restrict__ D_f, const float* __restrict__ D_b,
    const float* __restrict__ carry,
    float* __restrict__ yT_f, float* __restrict__ yT_b)
{
    if (blockIdx.z == 0) scan3_body<0>(dT_f, xT_f, dbcT_f, Alog_f, D_f, carry, yT_f);
    else                 scan3_body<1>(dT_b, xT_b, dbcT_b, Alog_b, D_b, carry, yT_b);
}

// ---------------------------------------------------------------------------
// y_bf[m][d] = f2bf( yT[d][m] * silu(z[m][d]) ). blockIdx.z = dir.
// ---------------------------------------------------------------------------
__global__ __launch_bounds__(256) void y_silu_transpose_kernel(
    const float* __restrict__ yT_f, const float* __restrict__ yT_b,
    const float* __restrict__ xz_f, const float* __restrict__ xz_b,
    unsigned short* __restrict__ ybf_f, unsigned short* __restrict__ ybf_b)
{
    __shared__ float t[32][33];
    const float* yT = blockIdx.z ? yT_b : yT_f;
    const float* xz = blockIdx.z ? xz_b : xz_f;
    unsigned short* y_bf = blockIdx.z ? ybf_b : ybf_f;
    const int m0 = blockIdx.x * 32, d0 = blockIdx.y * 32;
    const int tx = threadIdx.x & 31, ty = threadIdx.x >> 5;
    #pragma unroll
    for (int rr = 0; rr < 32; rr += 8)
        t[ty + rr][tx] = yT[(size_t)(d0 + ty + rr) * MM + m0 + tx];
    __syncthreads();
    #pragma unroll
    for (int rr = 0; rr < 32; rr += 8) {
        int m = m0 + ty + rr, d = d0 + tx;
        float z = xz[(size_t)m * 2048 + DINNER + d];
        float sig = 1.f / (1.f + __expf(-z));
        y_bf[(size_t)m * DINNER + d] = f2bf(t[tx][ty + rr] * (z * sig));
    }
}

// ---------------------------------------------------------------------------
// out[m,:] = LN(xf+pf; g1,b1) + LN(xf+pb; g2,b2), written as bf16.
// ---------------------------------------------------------------------------
__global__ __launch_bounds__(256) void ln_combine_kernel(
    const float* __restrict__ xf,
    const float* __restrict__ pf, const float* __restrict__ pb,
    const float* __restrict__ g1, const float* __restrict__ b1,
    const float* __restrict__ g2, const float* __restrict__ b2,
    unsigned short* __restrict__ out)
{
    const int m = blockIdx.x;
    const int tid = threadIdx.x;
    const float* xr = xf + (size_t)m * DMODEL;
    const float* p1 = pf + (size_t)m * DMODEL;
    const float* p2 = pb + (size_t)m * DMODEL;
    float v1a = xr[tid] + p1[tid];
    float v1b = xr[tid + 256] + p1[tid + 256];
    float v2a = xr[tid] + p2[tid];
    float v2b = xr[tid + 256] + p2[tid + 256];
    float s1 = v1a + v1b, q1 = v1a*v1a + v1b*v1b;
    float s2 = v2a + v2b, q2 = v2a*v2a + v2b*v2b;
    #pragma unroll
    for (int off = 32; off; off >>= 1) {
        s1 += __shfl_xor(s1, off); q1 += __shfl_xor(q1, off);
        s2 += __shfl_xor(s2, off); q2 += __shfl_xor(q2, off);
    }
    __shared__ float sm[4][4];
    const int w = tid >> 6;
    if ((tid & 63) == 0) { sm[w][0] = s1; sm[w][1] = q1; sm[w][2] = s2; sm[w][3] = q2; }
    __syncthreads();
    s1 = sm[0][0] + sm[1][0] + sm[2][0] + sm[3][0];
    q1 = sm[0][1] + sm[1][1] + sm[2][1] + sm[3][1];
    s2 = sm[0][2] + sm[1][2] + sm[2][2] + sm[3][2];
    q2 = sm[0][3] + sm[1][3] + sm[2][3] + sm[3][3];
    const float inv = 1.f / DMODEL;
    float mu1 = s1 * inv, mu2 = s2 * inv;
    float rs1 = rsqrtf(q1 * inv - mu1 * mu1 + 1e-5f);
    float rs2 = rsqrtf(q2 * inv - mu2 * mu2 + 1e-5f);
    unsigned short* orow = out + (size_t)m * DMODEL;
    orow[tid]       = f2bf((v1a - mu1) * rs1 * g1[tid]       + b1[tid]
                         + (v2a - mu2) * rs2 * g2[tid]       + b2[tid]);
    orow[tid + 256] = f2bf((v1b - mu1) * rs1 * g1[tid + 256] + b1[tid + 256]
                         + (v2b - mu2) * rs2 * g2[tid + 256] + b2[tid + 256]);
}

// ---------------------------------------------------------------------------
// out[m,:] = LN(2*ff[m,:]; g,b)
// ---------------------------------------------------------------------------
__global__ __launch_bounds__(256) void ln_final_kernel(
    const float* __restrict__ ff,
    const float* __restrict__ g, const float* __restrict__ b,
    float* __restrict__ out)
{
    const int m = blockIdx.x;
    const int tid = threadIdx.x;
    const float* fr = ff + (size_t)m * DMODEL;
    float va = 2.f * fr[tid];
    float vb = 2.f * fr[tid + 256];
    float s = va + vb, q = va*va + vb*vb;
    #pragma unroll
    for (int off = 32; off; off >>= 1) {
        s += __shfl_xor(s, off); q += __shfl_xor(q, off);
    }
    __shared__ float sm[4][2];
    const int w = tid >> 6;
    if ((tid & 63) == 0) { sm[w][0] = s; sm[w][1] = q; }
    __syncthreads();
    s = sm[0][0] + sm[1][0] + sm[2][0] + sm[3][0];
    q = sm[0][1] + sm[1][1] + sm[2][1] + sm[3][1];
    const float inv = 1.f / DMODEL;
    float mu = s * inv;
    float rs = rsqrtf(q * inv - mu * mu + 1e-5f);
    float* orow = out + (size_t)m * DMODEL;
    orow[tid]       = (va - mu) * rs * g[tid]       + b[tid];
    orow[tid + 256] = (vb - mu) * rs * g[tid + 256] + b[tid + 256];
}

// ---------------------------------------------------------------------------
extern "C" void kernel_launch(void* const* d_in, const int* in_sizes, int n_in,
                              void* d_out, int out_size, void* d_ws, size_t ws_size,
                              hipStream_t stream)
{
    const float* x         = (const float*)d_in[0];
    const float* fm_in_W   = (const float*)d_in[1];
    const float* fm_conv_W = (const float*)d_in[2];
    const float* fm_conv_b = (const float*)d_in[3];
    const float* fm_xproj_W= (const float*)d_in[4];
    const float* fm_dt_W   = (const float*)d_in[5];
    const float* fm_dt_b   = (const float*)d_in[6];
    const float* fm_A_log  = (const float*)d_in[7];
    const float* fm_D      = (const float*)d_in[8];
    const float* fm_out_W  = (const float*)d_in[9];
    const float* bm_in_W   = (const float*)d_in[10];
    const float* bm_conv_W = (const float*)d_in[11];
    const float* bm_conv_b = (const float*)d_in[12];
    const float* bm_xproj_W= (const float*)d_in[13];
    const float* bm_dt_W   = (const float*)d_in[14];
    const float* bm_dt_b   = (const float*)d_in[15];
    const float* bm_A_log  = (const float*)d_in[16];
    const float* bm_D      = (const float*)d_in[17];
    const float* bm_out_W  = (const float*)d_in[18];
    const float* ln1_g     = (const float*)d_in[19];
    const float* ln1_b     = (const float*)d_in[20];
    const float* ln2_g     = (const float*)d_in[21];
    const float* ln2_b     = (const float*)d_in[22];
    const float* ln3_g     = (const float*)d_in[23];
    const float* ln3_b     = (const float*)d_in[24];
    const float* ff_W1     = (const float*)d_in[25];
    const float* ff_b1     = (const float*)d_in[26];
    const float* ff_W2     = (const float*)d_in[27];
    const float* ff_b2     = (const float*)d_in[28];
    float* out = (float*)d_out;

    // ---- Workspace layout (floats; total 24,641,536 fl = 98.6 MB) ----
    float* ws = (float*)d_ws;
    size_t o = 0;
    float* xz_f = ws + o;  o += (size_t)MM * 2048;                       // 4,194,304
    float* xz_b = ws + o;  o += (size_t)MM * 2048;
    unsigned short* xm_bf_f = (unsigned short*)(ws + o); o += (size_t)MM * DINNER / 2;
    unsigned short* xm_bf_b = (unsigned short*)(ws + o); o += (size_t)MM * DINNER / 2;
    unsigned short* xmT_f   = (unsigned short*)(ws + o); o += (size_t)MM * DINNER / 2;
    unsigned short* xmT_b   = (unsigned short*)(ws + o); o += (size_t)MM * DINNER / 2;
    float* deltaT_f = ws + o; o += (size_t)MM * DINNER;                  // 2,097,152
    float* deltaT_b = ws + o; o += (size_t)MM * DINNER;
    float* dbc_f    = ws + o; o += (size_t)MM * 64;
    float* dbc_b    = ws + o; o += (size_t)MM * 64;
    float* dbcT_f   = ws + o; o += (size_t)MM * 64;
    float* dbcT_b   = ws + o; o += (size_t)MM * 64;
    float* yT_f     = ws + o; o += (size_t)MM * DINNER;
    float* yT_b     = ws + o; o += (size_t)MM * DINNER;
    float* scanP    = ws + o; o += (size_t)NCHUNK * (GTOT / 16) * 16;    // 1,048,576 (FULL)
    float* scanH    = ws + o; o += (size_t)NCHUNK * (GTOT / 16) * 16;
    float* scanCy   = ws + o; o += (size_t)NCHUNK * (GTOT / 16) * 16;

    // ---- Overlays (sequenced reuse of dead regions) ----
    // Pre-GEMM bf16 casts: contiguous block in scanP/scanH (dead until phase1)
    unsigned short* x_bf       = (unsigned short*)scanP;
    unsigned short* fm_inW_bf  = x_bf + 1048576;
    unsigned short* bm_inW_bf  = fm_inW_bf + 1048576;
    unsigned short* fm_xpW_bf  = bm_inW_bf + 1048576;
    unsigned short* bm_xpW_bf  = fm_xpW_bf + 65536;
    // xproj split-K partials in deltaT (dead until dt-proj runs afterward)
    float* gpart = deltaT_f;                       // also out-proj/FF2 partials later
    // After carry: scanP/H dead -> y_bf; after phase3: scanCy dead -> proj_f
    unsigned short* ybf_f = (unsigned short*)scanP;
    unsigned short* ybf_b = (unsigned short*)scanH;
    float* proj_f = scanCy;
    float* proj_b = yT_f;                          // yT dead after y_silu
    float* ff2    = yT_f + 1048576;
    unsigned short* h_bf = (unsigned short*)yT_b;  // 4,194,304 ushorts, exact fit
    // Post-scan weight casts: contiguous block in xz_f (dead after y_silu)
    unsigned short* fm_outW_bf = (unsigned short*)xz_f;
    unsigned short* bm_outW_bf = fm_outW_bf + 524288;
    unsigned short* W1_bf      = bm_outW_bf + 524288;
    unsigned short* W2_bf      = W1_bf + 1048576;
    unsigned short* outsum_bf  = (unsigned short*)xz_b;

    // ---- 0. pre-GEMM casts (1 dispatch) ----
    cast_pre_kernel<<<3276800 / 2048, 256, 0, stream>>>(
        x, fm_in_W, bm_in_W, fm_xproj_W, bm_xproj_W, x_bf);

    // ---- 1. in-proj GEMMs, both dirs (512 blocks) ----
    gemm_mfma_batch<0,0><<<dim3(2048/128, MM/128, 2), 256, 0, stream>>>(
        MM, 2048, DMODEL, x_bf, x_bf, DMODEL, fm_inW_bf, bm_inW_bf, DMODEL,
        nullptr, xz_f, xz_b, 2048);

    // ---- 2. conv + silu (both dirs) -> bf16 xm[m][d]; transpose -> xmT ----
    conv_silu_kernel<<<dim3((MM * DINNER) / 256, 2), 256, 0, stream>>>(
        xz_f, xz_b, fm_conv_W, bm_conv_W, fm_conv_b, bm_conv_b, xm_bf_f, xm_bf_b);
    transpose_bf16_kernel<<<dim3(DINNER/32, MM/32, 2), 256, 0, stream>>>(
        xm_bf_f, xm_bf_b, xmT_f, xmT_b, MM, DINNER);

    // ---- 3. x-proj: split-K x4, both dirs (128 blocks) + reduce ----
    xproj_splitk_kernel<<<dim3(MM/128, 8), 256, 0, stream>>>(
        xm_bf_f, xm_bf_b, fm_xpW_bf, bm_xpW_bf, gpart);
    xproj_reduce_kernel<<<dim3((MM*64)/1024, 2), 256, 0, stream>>>(
        gpart, dbc_f, dbc_b, dbcT_f, dbcT_b);

    // ---- 4. dt-proj, both dirs (writes deltaT[d][m], softplus) ----
    dtproj_batch_kernel<<<dim3(MM/64, DINNER/64, 2), 256, 0, stream>>>(
        DINNER, MM, DTRANK, fm_dt_W, bm_dt_W, DTRANK, dbc_f, dbc_b, 64,
        fm_dt_b, bm_dt_b, deltaT_f, deltaT_b, MM);

    // ---- 5. chunked selective scan (merged dirs) ----
    scan_phase1_kernel<<<dim3(DINNER/16, BATCH*NCHUNK, 2), 256, 0, stream>>>(
        deltaT_f, deltaT_b, xmT_f, xmT_b, dbcT_f, dbcT_b,
        fm_A_log, bm_A_log, scanP, scanH);
    scan_carry_kernel<<<GTOT/256, 256, 0, stream>>>(scanP, scanH, scanCy);
    scan_phase3_kernel<<<dim3(DINNER/16, BATCH*NCHUNK, 2), 256, 0, stream>>>(
        deltaT_f, deltaT_b, xmT_f, xmT_b, dbcT_f, dbcT_b,
        fm_A_log, bm_A_log, fm_D, bm_D, scanCy, yT_f, yT_b);

    // ---- 6. y * silu(z) + transpose (both dirs) -> y_bf[m][d] ----
    y_silu_transpose_kernel<<<dim3(MM/32, DINNER/32, 2), 256, 0, stream>>>(
        yT_f, yT_b, xz_f, xz_b, ybf_f, ybf_b);

    // ---- 6b. post weight casts (1 dispatch; xz dead) ----
    cast_post_kernel<<<3145728 / 2048, 256, 0, stream>>>(
        fm_out_W, bm_out_W, ff_W1, ff_W2, fm_outW_bf);

    // ---- 7. out-proj: dirs x splitK2 (256 blocks) + dual reduce ----
    gemm_mfma_splitk<2><<<dim3(DMODEL/128, MM/128, 4), 256, 0, stream>>>(
        MM, DMODEL, DINNER, ybf_f, ybf_b, DINNER, fm_outW_bf, bm_outW_bf, DINNER,
        gpart, DMODEL);
    reduce_splitk2_dual_kernel<<<dim3((MM*DMODEL)/1024, 2), 256, 0, stream>>>(
        gpart, proj_f, proj_b);

    // ---- 8. out = LN(xf+fwd) + LN(xf+bwd) -> bf16 ----
    ln_combine_kernel<<<MM, 256, 0, stream>>>(
        x, proj_f, proj_b, ln1_g, ln1_b, ln2_g, ln2_b, outsum_bf);

    // ---- 9. FF1 (256 blocks) ----
    gemm_mfma_batch<1,1><<<dim3(DFF/128, MM/128, 1), 256, 0, stream>>>(
        MM, DFF, DMODEL, outsum_bf, outsum_bf, DMODEL, W1_bf, W1_bf, DMODEL,
        ff_b1, h_bf, h_bf, DFF);

    // ---- 10. FF2: splitK4 (256 blocks) + reduce w/ bias ----
    gemm_mfma_splitk<4><<<dim3(DMODEL/128, MM/128, 4), 256, 0, stream>>>(
        MM, DMODEL, DFF, h_bf, h_bf, DFF, W2_bf, W2_bf, DFF, gpart, DMODEL);
    reduce_splitk_kernel<<<(MM*DMODEL)/1024, 256, 0, stream>>>(
        gpart, 4, MM*DMODEL, DMODEL, ff_b2, ff2);

    // ---- 11. final LN(2*ff) ----
    ln_final_kernel<<<MM, 256, 0, stream>>>(ff2, ln3_g, ln3_b, out);
}

// Round 7
// 365.108 us; speedup vs baseline: 3.9672x; 1.1019x over previous
//
#include <hip/hip_runtime.h>
#include <hip/hip_bf16.h>
#include <math.h>

// Problem constants
#define MM 2048        // B*W flattened rows
#define BATCH 2
#define SEQ 1024
#define DMODEL 512
#define DINNER 1024
#define DSTATE 16
#define DTRANK 32
#define DFF 2048

// Chunked-scan constants
#define NCHUNK 16
#define CHUNK 64
#define GTOT 65536          // 2 dirs * BATCH * DINNER * DSTATE

typedef short bf16x8 __attribute__((ext_vector_type(8)));
typedef float floatx4 __attribute__((ext_vector_type(4)));
typedef unsigned short ushort8v __attribute__((ext_vector_type(8)));
typedef unsigned short ushort4v __attribute__((ext_vector_type(4)));

__device__ __forceinline__ unsigned short f2bf(float f) {
    union { float f; unsigned u; } v; v.f = f;
    unsigned r = v.u + 0x7FFF + ((v.u >> 16) & 1);
    return (unsigned short)(r >> 16);
}
__device__ __forceinline__ float bf2f(unsigned short u) {
    union { unsigned u; float f; } v; v.u = ((unsigned)u) << 16; return v.f;
}

// Sum across each 16-lane DPP row via row_ror adds (VALU-only).
__device__ __forceinline__ float rowsum16(float x) {
    union { float f; int i; } a, b;
    a.f = x;
    b.i = __builtin_amdgcn_update_dpp(0, a.i, 0x128, 0xF, 0xF, false); a.f += b.f;
    b.i = __builtin_amdgcn_update_dpp(0, a.i, 0x124, 0xF, 0xF, false); a.f += b.f;
    b.i = __builtin_amdgcn_update_dpp(0, a.i, 0x122, 0xF, 0xF, false); a.f += b.f;
    b.i = __builtin_amdgcn_update_dpp(0, a.i, 0x121, 0xF, 0xF, false); a.f += b.f;
    return a.f;
}

#define GLOAD_LDS16(gp, lp) __builtin_amdgcn_global_load_lds( \
    (const __attribute__((address_space(1))) unsigned int*)(gp), \
    (__attribute__((address_space(3))) unsigned int*)(lp), 16, 0, 0)

// ---------------------------------------------------------------------------
// Batched direct bf16 MFMA GEMM: C[z][M,N] = epi(A[z] @ B[z]^T + bias)
// 128x128 tile, BK=32, 4 waves x (4x4) 16x16x32. Conflict-free LDS layout.
// ---------------------------------------------------------------------------
template<int EPI, int OUTBF16>
__global__ __launch_bounds__(256) void gemm_mfma_batch(
    int M, int N, int K,
    const unsigned short* __restrict__ A0, const unsigned short* __restrict__ A1, int lda,
    const unsigned short* __restrict__ B0, const unsigned short* __restrict__ B1, int ldb,
    const float* __restrict__ bias,
    void* __restrict__ C0, void* __restrict__ C1, int ldc)
{
    __shared__ unsigned short As[128 * 32];
    __shared__ unsigned short Bs[128 * 32];
    const int z = blockIdx.z;
    const unsigned short* A = z ? A1 : A0;
    const unsigned short* B = z ? B1 : B0;
    void* Cout = z ? C1 : C0;
    const int tid  = threadIdx.x;
    const int wave = tid >> 6;
    const int lane = tid & 63;
    const int bm = blockIdx.y * 128;
    const int bn = blockIdx.x * 128;

    const int strow = lane & 15;
    const int stkc  = lane >> 4;
    const int wr = wave >> 1, wc = wave & 1;
    const int frow = lane & 15;
    const int fkc  = lane >> 4;

    floatx4 acc[4][4];
    #pragma unroll
    for (int i = 0; i < 4; ++i)
        #pragma unroll
        for (int j = 0; j < 4; ++j)
            acc[i][j] = (floatx4){0.f, 0.f, 0.f, 0.f};

    for (int k0 = 0; k0 < K; k0 += 32) {
        __syncthreads();
        #pragma unroll
        for (int q = 0; q < 2; ++q) {
            int g = wave * 2 + q;
            GLOAD_LDS16(A + (size_t)(bm + g * 16 + strow) * lda + k0 + stkc * 8,
                        As + g * 512);
        }
        #pragma unroll
        for (int q = 0; q < 2; ++q) {
            int g = wave * 2 + q;
            GLOAD_LDS16(B + (size_t)(bn + g * 16 + strow) * ldb + k0 + stkc * 8,
                        Bs + g * 512);
        }
        __syncthreads();

        bf16x8 af[4], bfr[4];
        #pragma unroll
        for (int i = 0; i < 4; ++i)
            af[i] = *(const bf16x8*)(As + (wr * 4 + i) * 512 + fkc * 128 + frow * 8);
        #pragma unroll
        for (int j = 0; j < 4; ++j)
            bfr[j] = *(const bf16x8*)(Bs + (wc * 4 + j) * 512 + fkc * 128 + frow * 8);
        #pragma unroll
        for (int i = 0; i < 4; ++i)
            #pragma unroll
            for (int j = 0; j < 4; ++j)
                acc[i][j] = __builtin_amdgcn_mfma_f32_16x16x32_bf16(
                    af[i], bfr[j], acc[i][j], 0, 0, 0);
    }

    const int orow0 = bm + wr * 64 + (lane >> 4) * 4;
    const int ocol0 = bn + wc * 64 + (lane & 15);
    #pragma unroll
    for (int j = 0; j < 4; ++j) {
        const int col = ocol0 + j * 16;
        const float bv = bias ? bias[col] : 0.f;
        #pragma unroll
        for (int i = 0; i < 4; ++i) {
            #pragma unroll
            for (int r = 0; r < 4; ++r) {
                int row = orow0 + i * 16 + r;
                float t = acc[i][j][r] + bv;
                if (EPI == 1) t = fmaxf(t, 0.f);
                if (OUTBF16)
                    ((unsigned short*)Cout)[(size_t)row * ldc + col] = f2bf(t);
                else
                    ((float*)Cout)[(size_t)row * ldc + col] = t;
            }
        }
    }
}

// ---------------------------------------------------------------------------
// In-proj GEMM: C split into x-half / z-half buffers (each [M][1024]).
// A shared across dirs; blockIdx.z = dir. M=MM, N=2048, K=512.
// ---------------------------------------------------------------------------
__global__ __launch_bounds__(256) void gemm_inproj_kernel(
    const unsigned short* __restrict__ A,
    const unsigned short* __restrict__ B0, const unsigned short* __restrict__ B1,
    float* __restrict__ Cx0, float* __restrict__ Cz0,
    float* __restrict__ Cx1, float* __restrict__ Cz1)
{
    __shared__ unsigned short As[128 * 32];
    __shared__ unsigned short Bs[128 * 32];
    const int z = blockIdx.z;
    const unsigned short* B = z ? B1 : B0;
    const int tid  = threadIdx.x;
    const int wave = tid >> 6;
    const int lane = tid & 63;
    const int bm = blockIdx.y * 128;
    const int bn = blockIdx.x * 128;

    const int strow = lane & 15;
    const int stkc  = lane >> 4;
    const int wr = wave >> 1, wc = wave & 1;
    const int frow = lane & 15;
    const int fkc  = lane >> 4;

    floatx4 acc[4][4];
    #pragma unroll
    for (int i = 0; i < 4; ++i)
        #pragma unroll
        for (int j = 0; j < 4; ++j)
            acc[i][j] = (floatx4){0.f, 0.f, 0.f, 0.f};

    for (int k0 = 0; k0 < DMODEL; k0 += 32) {
        __syncthreads();
        #pragma unroll
        for (int q = 0; q < 2; ++q) {
            int g = wave * 2 + q;
            GLOAD_LDS16(A + (size_t)(bm + g * 16 + strow) * DMODEL + k0 + stkc * 8,
                        As + g * 512);
        }
        #pragma unroll
        for (int q = 0; q < 2; ++q) {
            int g = wave * 2 + q;
            GLOAD_LDS16(B + (size_t)(bn + g * 16 + strow) * DMODEL + k0 + stkc * 8,
                        Bs + g * 512);
        }
        __syncthreads();

        bf16x8 af[4], bfr[4];
        #pragma unroll
        for (int i = 0; i < 4; ++i)
            af[i] = *(const bf16x8*)(As + (wr * 4 + i) * 512 + fkc * 128 + frow * 8);
        #pragma unroll
        for (int j = 0; j < 4; ++j)
            bfr[j] = *(const bf16x8*)(Bs + (wc * 4 + j) * 512 + fkc * 128 + frow * 8);
        #pragma unroll
        for (int i = 0; i < 4; ++i)
            #pragma unroll
            for (int j = 0; j < 4; ++j)
                acc[i][j] = __builtin_amdgcn_mfma_f32_16x16x32_bf16(
                    af[i], bfr[j], acc[i][j], 0, 0, 0);
    }

    // whole block's 128 cols lie in one half (bn multiple of 128)
    const int zh = bn >= DINNER;
    float* C = z ? (zh ? Cz1 : Cx1) : (zh ? Cz0 : Cx0);
    const int cb = zh ? DINNER : 0;
    const int orow0 = bm + wr * 64 + (lane >> 4) * 4;
    const int ocol0 = bn + wc * 64 + (lane & 15) - cb;
    #pragma unroll
    for (int j = 0; j < 4; ++j) {
        const int col = ocol0 + j * 16;
        #pragma unroll
        for (int i = 0; i < 4; ++i)
            #pragma unroll
            for (int r = 0; r < 4; ++r)
                C[(size_t)(orow0 + i * 16 + r) * DINNER + col] = acc[i][j][r];
    }
}

// ---------------------------------------------------------------------------
// Split-K batched MFMA GEMM -> fp32 partials part[z][M*ldc]. z=dir*NSPLIT+sp.
// ---------------------------------------------------------------------------
template<int NSPLIT>
__global__ __launch_bounds__(256) void gemm_mfma_splitk(
    int M, int N, int K,
    const unsigned short* __restrict__ A0, const unsigned short* __restrict__ A1, int lda,
    const unsigned short* __restrict__ B0, const unsigned short* __restrict__ B1, int ldb,
    float* __restrict__ part, int ldc)
{
    __shared__ unsigned short As[128 * 32];
    __shared__ unsigned short Bs[128 * 32];
    const int z = blockIdx.z;
    const int dir = z / NSPLIT, sp = z % NSPLIT;
    const unsigned short* A = dir ? A1 : A0;
    const unsigned short* B = dir ? B1 : B0;
    float* Cp = part + (size_t)z * M * ldc;
    const int kbeg = sp * (K / NSPLIT);
    const int kend = kbeg + (K / NSPLIT);
    const int tid  = threadIdx.x;
    const int wave = tid >> 6;
    const int lane = tid & 63;
    const int bm = blockIdx.y * 128;
    const int bn = blockIdx.x * 128;

    const int strow = lane & 15;
    const int stkc  = lane >> 4;
    const int wr = wave >> 1, wc = wave & 1;
    const int frow = lane & 15;
    const int fkc  = lane >> 4;

    floatx4 acc[4][4];
    #pragma unroll
    for (int i = 0; i < 4; ++i)
        #pragma unroll
        for (int j = 0; j < 4; ++j)
            acc[i][j] = (floatx4){0.f, 0.f, 0.f, 0.f};

    for (int k0 = kbeg; k0 < kend; k0 += 32) {
        __syncthreads();
        #pragma unroll
        for (int q = 0; q < 2; ++q) {
            int g = wave * 2 + q;
            GLOAD_LDS16(A + (size_t)(bm + g * 16 + strow) * lda + k0 + stkc * 8,
                        As + g * 512);
        }
        #pragma unroll
        for (int q = 0; q < 2; ++q) {
            int g = wave * 2 + q;
            GLOAD_LDS16(B + (size_t)(bn + g * 16 + strow) * ldb + k0 + stkc * 8,
                        Bs + g * 512);
        }
        __syncthreads();

        bf16x8 af[4], bfr[4];
        #pragma unroll
        for (int i = 0; i < 4; ++i)
            af[i] = *(const bf16x8*)(As + (wr * 4 + i) * 512 + fkc * 128 + frow * 8);
        #pragma unroll
        for (int j = 0; j < 4; ++j)
            bfr[j] = *(const bf16x8*)(Bs + (wc * 4 + j) * 512 + fkc * 128 + frow * 8);
        #pragma unroll
        for (int i = 0; i < 4; ++i)
            #pragma unroll
            for (int j = 0; j < 4; ++j)
                acc[i][j] = __builtin_amdgcn_mfma_f32_16x16x32_bf16(
                    af[i], bfr[j], acc[i][j], 0, 0, 0);
    }

    const int orow0 = bm + wr * 64 + (lane >> 4) * 4;
    const int ocol0 = bn + wc * 64 + (lane & 15);
    #pragma unroll
    for (int j = 0; j < 4; ++j) {
        const int col = ocol0 + j * 16;
        #pragma unroll
        for (int i = 0; i < 4; ++i)
            #pragma unroll
            for (int r = 0; r < 4; ++r)
                Cp[(size_t)(orow0 + i * 16 + r) * ldc + col] = acc[i][j][r];
    }
}

// ---------------------------------------------------------------------------
// Split-K reduce (generic): out[i] = sum_s part[s][i] (+ bias[i%ldc]).
// ---------------------------------------------------------------------------
__global__ __launch_bounds__(256) void reduce_splitk_kernel(
    const float* __restrict__ part, int nsplit, int elems, int ldc,
    const float* __restrict__ bias, float* __restrict__ out)
{
    int i = (blockIdx.x * 256 + threadIdx.x) * 4;
    if (i >= elems) return;
    float4 a = *(const float4*)(part + i);
    for (int s = 1; s < nsplit; ++s) {
        float4 t = *(const float4*)(part + (size_t)s * elems + i);
        a.x += t.x; a.y += t.y; a.z += t.z; a.w += t.w;
    }
    if (bias) {
        int c = i % ldc;
        a.x += bias[c]; a.y += bias[c + 1]; a.z += bias[c + 2]; a.w += bias[c + 3];
    }
    *(float4*)(out + i) = a;
}

// Dual split-K2 reduce for out-proj: blockIdx.y = dir.
__global__ __launch_bounds__(256) void reduce_splitk2_dual_kernel(
    const float* __restrict__ part, float* __restrict__ out0, float* __restrict__ out1)
{
    const int dir = blockIdx.y;
    const int i = (blockIdx.x * 256 + threadIdx.x) * 4;
    const float* p = part + (size_t)dir * 2 * (MM * DMODEL);
    float4 a = *(const float4*)(p + i);
    float4 t = *(const float4*)(p + (size_t)(MM * DMODEL) + i);
    a.x += t.x; a.y += t.y; a.z += t.z; a.w += t.w;
    float* out = dir ? out1 : out0;
    *(float4*)(out + i) = a;
}

// ---------------------------------------------------------------------------
// xproj split-K MFMA: tile 128(m) x 64(n), K slice 256. blockIdx.y=dir*4+sp.
// ---------------------------------------------------------------------------
__global__ __launch_bounds__(256) void xproj_splitk_kernel(
    const unsigned short* __restrict__ A_f, const unsigned short* __restrict__ A_b,
    const unsigned short* __restrict__ Wf,  const unsigned short* __restrict__ Wb,
    float* __restrict__ part)
{
    __shared__ unsigned short As[128 * 32];
    __shared__ unsigned short Bs[64 * 32];
    const int tid = threadIdx.x, wave = tid >> 6, lane = tid & 63;
    const int bm = blockIdx.x * 128;
    const int dir = blockIdx.y >> 2, sp = blockIdx.y & 3;
    const unsigned short* A = dir ? A_b : A_f;
    const unsigned short* W = dir ? Wb  : Wf;
    float* Cp = part + (size_t)blockIdx.y * MM * 64;
    const int kbeg = sp * 256, kend = kbeg + 256;

    const int strow = lane & 15;
    const int stkc  = lane >> 4;
    const int frow = lane & 15;
    const int fkc  = lane >> 4;

    floatx4 acc[2][4];
    #pragma unroll
    for (int i = 0; i < 2; ++i)
        #pragma unroll
        for (int j = 0; j < 4; ++j)
            acc[i][j] = (floatx4){0.f, 0.f, 0.f, 0.f};

    for (int k0 = kbeg; k0 < kend; k0 += 32) {
        __syncthreads();
        #pragma unroll
        for (int q = 0; q < 2; ++q) {
            int g = wave * 2 + q;
            GLOAD_LDS16(A + (size_t)(bm + g * 16 + strow) * DINNER + k0 + stkc * 8,
                        As + g * 512);
        }
        GLOAD_LDS16(W + (size_t)(wave * 16 + strow) * DINNER + k0 + stkc * 8,
                    Bs + wave * 512);
        __syncthreads();

        bf16x8 af[2], bfr[4];
        #pragma unroll
        for (int i = 0; i < 2; ++i)
            af[i] = *(const bf16x8*)(As + (wave * 2 + i) * 512 + fkc * 128 + frow * 8);
        #pragma unroll
        for (int j = 0; j < 4; ++j)
            bfr[j] = *(const bf16x8*)(Bs + j * 512 + fkc * 128 + frow * 8);
        #pragma unroll
        for (int i = 0; i < 2; ++i)
            #pragma unroll
            for (int j = 0; j < 4; ++j)
                acc[i][j] = __builtin_amdgcn_mfma_f32_16x16x32_bf16(
                    af[i], bfr[j], acc[i][j], 0, 0, 0);
    }

    const int orow0 = bm + wave * 32 + (lane >> 4) * 4;
    #pragma unroll
    for (int j = 0; j < 4; ++j) {
        const int col = (lane & 15) + j * 16;
        #pragma unroll
        for (int i = 0; i < 2; ++i)
            #pragma unroll
            for (int r = 0; r < 4; ++r)
                Cp[(size_t)(orow0 + i * 16 + r) * 64 + col] = acc[i][j][r];
    }
}

// ---------------------------------------------------------------------------
// xproj reduce: dbc[m][64] = sum of 4 parts; also writes dbcT[64][MM].
// ---------------------------------------------------------------------------
__global__ __launch_bounds__(256) void xproj_reduce_kernel(
    const float* __restrict__ part,
    float* __restrict__ dbc_f, float* __restrict__ dbc_b,
    float* __restrict__ dbcT_f, float* __restrict__ dbcT_b)
{
    const int dir = blockIdx.y;
    const int i = (blockIdx.x * 256 + threadIdx.x) * 4;
    const float* p = part + (size_t)dir * 4 * (MM * 64);
    float4 a = *(const float4*)(p + i);
    #pragma unroll
    for (int s = 1; s < 4; ++s) {
        float4 t = *(const float4*)(p + (size_t)s * (MM * 64) + i);
        a.x += t.x; a.y += t.y; a.z += t.z; a.w += t.w;
    }
    float* dbc  = dir ? dbc_b  : dbc_f;
    float* dbcT = dir ? dbcT_b : dbcT_f;
    *(float4*)(dbc + i) = a;
    const int m = i >> 6, c = i & 63;
    dbcT[(size_t)(c + 0) * MM + m] = a.x;
    dbcT[(size_t)(c + 1) * MM + m] = a.y;
    dbcT[(size_t)(c + 2) * MM + m] = a.z;
    dbcT[(size_t)(c + 3) * MM + m] = a.w;
}

// ---------------------------------------------------------------------------
// Batched fp32 GEMM w/ softplus + row bias (dt-proj), bf16 output.
// C[z][M,N] = softplus(A[z][M,K] @ B[z][N,K]^T + biasR[row]), blockIdx.z=dir.
// ---------------------------------------------------------------------------
__global__ __launch_bounds__(256) void dtproj_batch_kernel(
    int M, int N, int K,
    const float* __restrict__ A0, const float* __restrict__ A1, int lda,
    const float* __restrict__ B0, const float* __restrict__ B1, int ldb,
    const float* __restrict__ bias0, const float* __restrict__ bias1,
    unsigned short* __restrict__ C0, unsigned short* __restrict__ C1, int ldc)
{
    __shared__ float As[16][64];
    __shared__ float Bs[16][64];
    const int z = blockIdx.z;
    const float* A = z ? A1 : A0;
    const float* B = z ? B1 : B0;
    const float* biasR = z ? bias1 : bias0;
    unsigned short* C = z ? C1 : C0;
    const int tid = threadIdx.x;
    const int tx = tid & 15, ty = tid >> 4;
    const int bm = blockIdx.y * 64, bn = blockIdx.x * 64;
    const int lm = tid & 63;
    const int lk = (tid >> 6) * 4;
    const float* Arow = A + (size_t)(bm + lm) * lda + lk;
    const float* Brow = B + (size_t)(bn + lm) * ldb + lk;
    float acc[4][4] = {};
    for (int k0 = 0; k0 < K; k0 += 16) {
        float4 av = *(const float4*)(Arow + k0);
        float4 bv = *(const float4*)(Brow + k0);
        __syncthreads();
        As[lk+0][lm] = av.x; As[lk+1][lm] = av.y; As[lk+2][lm] = av.z; As[lk+3][lm] = av.w;
        Bs[lk+0][lm] = bv.x; Bs[lk+1][lm] = bv.y; Bs[lk+2][lm] = bv.z; Bs[lk+3][lm] = bv.w;
        __syncthreads();
        #pragma unroll
        for (int k = 0; k < 16; ++k) {
            float4 a = *(const float4*)(&As[k][ty*4]);
            float4 b = *(const float4*)(&Bs[k][tx*4]);
            float ar[4] = {a.x,a.y,a.z,a.w};
            float br[4] = {b.x,b.y,b.z,b.w};
            #pragma unroll
            for (int i = 0; i < 4; ++i)
                #pragma unroll
                for (int j = 0; j < 4; ++j)
                    acc[i][j] = fmaf(ar[i], br[j], acc[i][j]);
        }
    }
    const int row0 = bm + ty*4, col0 = bn + tx*4;
    #pragma unroll
    for (int i = 0; i < 4; ++i) {
        float br = biasR[row0 + i];
        ushort4v o;
        #pragma unroll
        for (int j = 0; j < 4; ++j) {
            float t = acc[i][j] + br;
            o[j] = f2bf(fmaxf(t, 0.f) + log1pf(__expf(-fabsf(t))));
        }
        *(ushort4v*)(C + (size_t)(row0 + i) * ldc + col0) = o;
    }
}

// ---------------------------------------------------------------------------
// Segmented casts: 5 pre-GEMM arrays -> one contiguous bf16 block.
// ---------------------------------------------------------------------------
__global__ __launch_bounds__(256) void cast_pre_kernel(
    const float* __restrict__ x, const float* __restrict__ w0,
    const float* __restrict__ w1, const float* __restrict__ xp0,
    const float* __restrict__ xp1, unsigned short* __restrict__ dst)
{
    int i = (blockIdx.x * 256 + threadIdx.x) * 8;
    const float* src; int off;
    if      (i < 1048576) { src = x;   off = 0; }
    else if (i < 2097152) { src = w0;  off = 1048576; }
    else if (i < 3145728) { src = w1;  off = 2097152; }
    else if (i < 3211264) { src = xp0; off = 3145728; }
    else                  { src = xp1; off = 3211264; }
    float4 a = *(const float4*)(src + i - off);
    float4 b = *(const float4*)(src + i - off + 4);
    ushort8v o;
    o[0] = f2bf(a.x); o[1] = f2bf(a.y); o[2] = f2bf(a.z); o[3] = f2bf(a.w);
    o[4] = f2bf(b.x); o[5] = f2bf(b.y); o[6] = f2bf(b.z); o[7] = f2bf(b.w);
    *(ushort8v*)(dst + i) = o;
}

// Segments: outW_f(524288) outW_b(524288) W1(1048576) W2(1048576)
__global__ __launch_bounds__(256) void cast_post_kernel(
    const float* __restrict__ w0, const float* __restrict__ w1,
    const float* __restrict__ w2, const float* __restrict__ w3,
    unsigned short* __restrict__ dst)
{
    int i = (blockIdx.x * 256 + threadIdx.x) * 8;
    const float* src; int off;
    if      (i < 524288)  { src = w0; off = 0; }
    else if (i < 1048576) { src = w1; off = 524288; }
    else if (i < 2097152) { src = w2; off = 1048576; }
    else                  { src = w3; off = 2097152; }
    float4 a = *(const float4*)(src + i - off);
    float4 b = *(const float4*)(src + i - off + 4);
    ushort8v o;
    o[0] = f2bf(a.x); o[1] = f2bf(a.y); o[2] = f2bf(a.z); o[3] = f2bf(a.w);
    o[4] = f2bf(b.x); o[5] = f2bf(b.y); o[6] = f2bf(b.z); o[7] = f2bf(b.w);
    *(ushort8v*)(dst + i) = o;
}

// ---------------------------------------------------------------------------
// Depthwise conv + bias + silu -> bf16 xm[m][d]. Reads xonly[m][1024].
// blockIdx.y = dir.
// ---------------------------------------------------------------------------
__global__ __launch_bounds__(256) void conv_silu_kernel(
    const float* __restrict__ x_f, const float* __restrict__ x_b,
    const float* __restrict__ Wf,  const float* __restrict__ Wb,
    const float* __restrict__ cbf, const float* __restrict__ cbb,
    unsigned short* __restrict__ of, unsigned short* __restrict__ ob)
{
    const int dir = blockIdx.y;
    const float* xo = dir ? x_b : x_f;
    const float* convW = dir ? Wb : Wf;
    const float* convb = dir ? cbb : cbf;
    unsigned short* xm_bf = dir ? ob : of;
    int gid = blockIdx.x * 256 + threadIdx.x;
    int c = gid & (DINNER - 1);
    int m = gid >> 10;
    int b = m >> 10;
    int l = m & (SEQ - 1);
    float4 wv = *(const float4*)(convW + c * 4);
    float w[4] = {wv.x, wv.y, wv.z, wv.w};
    float acc = convb[c];
    #pragma unroll
    for (int j = 0; j < 4; ++j) {
        int p = dir ? (l + 3 - j) : (l - 3 + j);
        if (p >= 0 && p < SEQ)
            acc = fmaf(xo[(size_t)(b * SEQ + p) * DINNER + c], w[j], acc);
    }
    float sig = 1.f / (1.f + __expf(-acc));
    xm_bf[(size_t)m * DINNER + c] = f2bf(acc * sig);
}

// ---------------------------------------------------------------------------
// bf16 transpose (both dirs): in[R][C] -> out[C][R]. blockIdx.z = dir.
// ---------------------------------------------------------------------------
__global__ __launch_bounds__(256) void transpose_bf16_kernel(
    const unsigned short* __restrict__ in0, const unsigned short* __restrict__ in1,
    unsigned short* __restrict__ out0, unsigned short* __restrict__ out1,
    int R, int C)
{
    __shared__ unsigned short t[32][34];
    const unsigned short* in = blockIdx.z ? in1 : in0;
    unsigned short* out = blockIdx.z ? out1 : out0;
    const int c0 = blockIdx.x * 32, r0 = blockIdx.y * 32;
    const int tx = threadIdx.x & 31, ty = threadIdx.x >> 5;
    #pragma unroll
    for (int rr = 0; rr < 32; rr += 8)
        t[ty + rr][tx] = in[(size_t)(r0 + ty + rr) * C + c0 + tx];
    __syncthreads();
    #pragma unroll
    for (int rr = 0; rr < 32; rr += 8)
        out[(size_t)(c0 + ty + rr) * R + r0 + tx] = t[tx][ty + rr];
}

// ---------------------------------------------------------------------------
// Scan pass 1: local scan from zero state. Emits raw y0 (incl. D*x), running
// cumdl per position (s==0 lane), and chunk P = exp(A*sum dl), H = end state.
// ---------------------------------------------------------------------------
template<int DIR>
__device__ __forceinline__ void pass1_body(
    const unsigned short* __restrict__ deltaT, const unsigned short* __restrict__ xmT,
    const float* __restrict__ dbcT, const float* __restrict__ Alog,
    const float* __restrict__ Dv,
    float* __restrict__ y0T, float* __restrict__ cumT,
    float* __restrict__ Pout, float* __restrict__ Hout)
{
    const int tid = threadIdx.x;
    const int s = tid & 15;
    const int dloc = tid >> 4;
    const int d = blockIdx.x * 16 + dloc;
    const int b = blockIdx.y / NCHUNK;
    const int c = blockIdx.y % NCHUNK;

    const float A  = -__expf(Alog[d * DSTATE + s]);
    const float Dp = Dv[d];
    const unsigned short* dRow = deltaT + (size_t)d * MM + b * SEQ;
    const unsigned short* xRow = xmT + (size_t)d * MM + b * SEQ;
    const float* bRow = dbcT + (size_t)(DTRANK + s) * MM + b * SEQ;
    const float* cRow = dbcT + (size_t)(DTRANK + DSTATE + s) * MM + b * SEQ;
    float* yRow = y0T + (size_t)d * MM + b * SEQ;
    float* uRow = cumT + (size_t)d * MM + b * SEQ;

    float h = 0.f, sdl = 0.f;
    const int segBase = DIR ? (SEQ - CHUNK - c * CHUNK) : (c * CHUNK);
    for (int ii = 0; ii < CHUNK; ii += 8) {
        const int off = DIR ? (segBase + (CHUNK - 8) - ii) : (segBase + ii);
        ushort8v dl8 = *(const ushort8v*)(dRow + off);
        ushort8v x8  = *(const ushort8v*)(xRow + off);
        float4 b0 = *(const float4*)(bRow + off);
        float4 b1 = *(const float4*)(bRow + off + 4);
        float4 c0 = *(const float4*)(cRow + off);
        float4 c1 = *(const float4*)(cRow + off + 4);
        float Bv[8] = {b0.x,b0.y,b0.z,b0.w,b1.x,b1.y,b1.z,b1.w};
        float Cv[8] = {c0.x,c0.y,c0.z,c0.w,c1.x,c1.y,c1.z,c1.w};
        float yv[8], cu[8];
        #pragma unroll
        for (int u = 0; u < 8; ++u) {
            const int t = DIR ? (7 - u) : u;
            float dlv = bf2f(dl8[t]);
            float xv  = bf2f(x8[t]);
            float dA = __expf(dlv * A);
            sdl += dlv;
            h = fmaf(dA, h, dlv * Bv[t] * xv);
            float part = rowsum16(h * Cv[t]);
            yv[t] = fmaf(xv, Dp, part);
            cu[t] = sdl;
        }
        if (s == 0) {
            *(float4*)(yRow + off)     = (float4){yv[0], yv[1], yv[2], yv[3]};
            *(float4*)(yRow + off + 4) = (float4){yv[4], yv[5], yv[6], yv[7]};
            *(float4*)(uRow + off)     = (float4){cu[0], cu[1], cu[2], cu[3]};
            *(float4*)(uRow + off + 4) = (float4){cu[4], cu[5], cu[6], cu[7]};
        }
    }
    const int g = ((DIR * BATCH + b) * DINNER + d) * DSTATE + s;
    Pout[(size_t)c * GTOT + g] = __expf(sdl * A);
    Hout[(size_t)c * GTOT + g] = h;
}

__global__ __launch_bounds__(256) void scan_pass1_kernel(
    const unsigned short* __restrict__ dT_f, const unsigned short* __restrict__ dT_b,
    const unsigned short* __restrict__ xT_f, const unsigned short* __restrict__ xT_b,
    const float* __restrict__ dbcT_f, const float* __restrict__ dbcT_b,
    const float* __restrict__ Alog_f, const float* __restrict__ Alog_b,
    const float* __restrict__ D_f, const float* __restrict__ D_b,
    float* __restrict__ y0T_f, float* __restrict__ y0T_b,
    float* __restrict__ cumT_f, float* __restrict__ cumT_b,
    float* __restrict__ Pout, float* __restrict__ Hout)
{
    if (blockIdx.z == 0)
        pass1_body<0>(dT_f, xT_f, dbcT_f, Alog_f, D_f, y0T_f, cumT_f, Pout, Hout);
    else
        pass1_body<1>(dT_b, xT_b, dbcT_b, Alog_b, D_b, y0T_b, cumT_b, Pout, Hout);
}

// ---------------------------------------------------------------------------
// Phase 2: sequential combine over chunks.
// ---------------------------------------------------------------------------
__global__ __launch_bounds__(256) void scan_carry_kernel(
    const float* __restrict__ P, const float* __restrict__ H,
    float* __restrict__ carry)
{
    const int g = blockIdx.x * 256 + threadIdx.x;
    float h = 0.f;
    #pragma unroll
    for (int c = 0; c < NCHUNK; ++c) {
        carry[(size_t)c * GTOT + g] = h;
        h = fmaf(P[(size_t)c * GTOT + g], h, H[(size_t)c * GTOT + g]);
    }
}

// ---------------------------------------------------------------------------
// Correction pass (fully parallel, no serial chain):
//   y[m,d] = y0[m,d] + sum_s C[m,s]*carry[d,s]*exp(A[d,s]*cumdl[m,d])
// then *= silu(z), transpose -> ybf[m][d]. blockIdx.z = dir.
// ---------------------------------------------------------------------------
__global__ __launch_bounds__(256) void scan_correct_kernel(
    const float* __restrict__ y0T_f, const float* __restrict__ y0T_b,
    const float* __restrict__ cumT_f, const float* __restrict__ cumT_b,
    const float* __restrict__ dbcT_f, const float* __restrict__ dbcT_b,
    const float* __restrict__ Alog_f, const float* __restrict__ Alog_b,
    const float* __restrict__ carry,
    const float* __restrict__ z_f, const float* __restrict__ z_b,
    unsigned short* __restrict__ ybf_f, unsigned short* __restrict__ ybf_b)
{
    __shared__ float Cs[16][33];   // C[s][m-local]
    __shared__ float Asm[32][16];  // A per (d-local, s)
    __shared__ float Cy[32][16];   // carry per (d-local, s)
    __shared__ float t[32][33];    // transpose buffer

    const int dir = blockIdx.z;
    const float* y0T  = dir ? y0T_b  : y0T_f;
    const float* cumT = dir ? cumT_b : cumT_f;
    const float* dbcT = dir ? dbcT_b : dbcT_f;
    const float* Alog = dir ? Alog_b : Alog_f;
    const float* zon  = dir ? z_b    : z_f;
    unsigned short* ybf = dir ? ybf_b : ybf_f;

    const int m0 = blockIdx.x * 32, d0 = blockIdx.y * 32;
    const int b = m0 >> 10;
    const int l0 = m0 & (SEQ - 1);
    const int c = dir ? ((SEQ - 1 - l0) >> 6) : (l0 >> 6);

    // stage C, A, carry tiles
    for (int idx = threadIdx.x; idx < 512; idx += 256) {
        int s = idx >> 5, ml = idx & 31;
        Cs[s][ml] = dbcT[(size_t)(DTRANK + DSTATE + s) * MM + m0 + ml];
        int dl2 = idx >> 4, s2 = idx & 15;
        Asm[dl2][s2] = -__expf(Alog[(d0 + dl2) * DSTATE + s2]);
        Cy[dl2][s2] = carry[(size_t)c * GTOT
            + ((size_t)(dir * BATCH + b) * DINNER + d0 + dl2) * DSTATE + s2];
    }
    __syncthreads();

    const int tx = threadIdx.x & 31, ty = threadIdx.x >> 5;
    #pragma unroll
    for (int rr = 0; rr < 32; rr += 8) {
        const int dloc = ty + rr;
        const size_t base = (size_t)(d0 + dloc) * MM + m0 + tx;
        float u  = cumT[base];
        float y0 = y0T[base];
        float corr = 0.f;
        #pragma unroll
        for (int s = 0; s < DSTATE; ++s)
            corr = fmaf(Cs[s][tx] * Cy[dloc][s], __expf(Asm[dloc][s] * u), corr);
        t[dloc][tx] = y0 + corr;
    }
    __syncthreads();
    #pragma unroll
    for (int rr = 0; rr < 32; rr += 8) {
        int m = m0 + ty + rr, d = d0 + tx;
        float z = zon[(size_t)m * DINNER + d];
        float sig = 1.f / (1.f + __expf(-z));
        ybf[(size_t)m * DINNER + d] = f2bf(t[tx][ty + rr] * (z * sig));
    }
}

// ---------------------------------------------------------------------------
// out[m,:] = LN(xf+pf; g1,b1) + LN(xf+pb; g2,b2), written as bf16.
// ---------------------------------------------------------------------------
__global__ __launch_bounds__(256) void ln_combine_kernel(
    const float* __restrict__ xf,
    const float* __restrict__ pf, const float* __restrict__ pb,
    const float* __restrict__ g1, const float* __restrict__ b1,
    const float* __restrict__ g2, const float* __restrict__ b2,
    unsigned short* __restrict__ out)
{
    const int m = blockIdx.x;
    const int tid = threadIdx.x;
    const float* xr = xf + (size_t)m * DMODEL;
    const float* p1 = pf + (size_t)m * DMODEL;
    const float* p2 = pb + (size_t)m * DMODEL;
    float v1a = xr[tid] + p1[tid];
    float v1b = xr[tid + 256] + p1[tid + 256];
    float v2a = xr[tid] + p2[tid];
    float v2b = xr[tid + 256] + p2[tid + 256];
    float s1 = v1a + v1b, q1 = v1a*v1a + v1b*v1b;
    float s2 = v2a + v2b, q2 = v2a*v2a + v2b*v2b;
    #pragma unroll
    for (int off = 32; off; off >>= 1) {
        s1 += __shfl_xor(s1, off); q1 += __shfl_xor(q1, off);
        s2 += __shfl_xor(s2, off); q2 += __shfl_xor(q2, off);
    }
    __shared__ float sm[4][4];
    const int w = tid >> 6;
    if ((tid & 63) == 0) { sm[w][0] = s1; sm[w][1] = q1; sm[w][2] = s2; sm[w][3] = q2; }
    __syncthreads();
    s1 = sm[0][0] + sm[1][0] + sm[2][0] + sm[3][0];
    q1 = sm[0][1] + sm[1][1] + sm[2][1] + sm[3][1];
    s2 = sm[0][2] + sm[1][2] + sm[2][2] + sm[3][2];
    q2 = sm[0][3] + sm[1][3] + sm[2][3] + sm[3][3];
    const float inv = 1.f / DMODEL;
    float mu1 = s1 * inv, mu2 = s2 * inv;
    float rs1 = rsqrtf(q1 * inv - mu1 * mu1 + 1e-5f);
    float rs2 = rsqrtf(q2 * inv - mu2 * mu2 + 1e-5f);
    unsigned short* orow = out + (size_t)m * DMODEL;
    orow[tid]       = f2bf((v1a - mu1) * rs1 * g1[tid]       + b1[tid]
                         + (v2a - mu2) * rs2 * g2[tid]       + b2[tid]);
    orow[tid + 256] = f2bf((v1b - mu1) * rs1 * g1[tid + 256] + b1[tid + 256]
                         + (v2b - mu2) * rs2 * g2[tid + 256] + b2[tid + 256]);
}

// ---------------------------------------------------------------------------
// out[m,:] = LN(2*ff[m,:]; g,b)
// ---------------------------------------------------------------------------
__global__ __launch_bounds__(256) void ln_final_kernel(
    const float* __restrict__ ff,
    const float* __restrict__ g, const float* __restrict__ b,
    float* __restrict__ out)
{
    const int m = blockIdx.x;
    const int tid = threadIdx.x;
    const float* fr = ff + (size_t)m * DMODEL;
    float va = 2.f * fr[tid];
    float vb = 2.f * fr[tid + 256];
    float s = va + vb, q = va*va + vb*vb;
    #pragma unroll
    for (int off = 32; off; off >>= 1) {
        s += __shfl_xor(s, off); q += __shfl_xor(q, off);
    }
    __shared__ float sm[4][2];
    const int w = tid >> 6;
    if ((tid & 63) == 0) { sm[w][0] = s; sm[w][1] = q; }
    __syncthreads();
    s = sm[0][0] + sm[1][0] + sm[2][0] + sm[3][0];
    q = sm[0][1] + sm[1][1] + sm[2][1] + sm[3][1];
    const float inv = 1.f / DMODEL;
    float mu = s * inv;
    float rs = rsqrtf(q * inv - mu * mu + 1e-5f);
    float* orow = out + (size_t)m * DMODEL;
    orow[tid]       = (va - mu) * rs * g[tid]       + b[tid];
    orow[tid + 256] = (vb - mu) * rs * g[tid + 256] + b[tid + 256];
}

// ---------------------------------------------------------------------------
extern "C" void kernel_launch(void* const* d_in, const int* in_sizes, int n_in,
                              void* d_out, int out_size, void* d_ws, size_t ws_size,
                              hipStream_t stream)
{
    const float* x         = (const float*)d_in[0];
    const float* fm_in_W   = (const float*)d_in[1];
    const float* fm_conv_W = (const float*)d_in[2];
    const float* fm_conv_b = (const float*)d_in[3];
    const float* fm_xproj_W= (const float*)d_in[4];
    const float* fm_dt_W   = (const float*)d_in[5];
    const float* fm_dt_b   = (const float*)d_in[6];
    const float* fm_A_log  = (const float*)d_in[7];
    const float* fm_D      = (const float*)d_in[8];
    const float* fm_out_W  = (const float*)d_in[9];
    const float* bm_in_W   = (const float*)d_in[10];
    const float* bm_conv_W = (const float*)d_in[11];
    const float* bm_conv_b = (const float*)d_in[12];
    const float* bm_xproj_W= (const float*)d_in[13];
    const float* bm_dt_W   = (const float*)d_in[14];
    const float* bm_dt_b   = (const float*)d_in[15];
    const float* bm_A_log  = (const float*)d_in[16];
    const float* bm_D      = (const float*)d_in[17];
    const float* bm_out_W  = (const float*)d_in[18];
    const float* ln1_g     = (const float*)d_in[19];
    const float* ln1_b     = (const float*)d_in[20];
    const float* ln2_g     = (const float*)d_in[21];
    const float* ln2_b     = (const float*)d_in[22];
    const float* ln3_g     = (const float*)d_in[23];
    const float* ln3_b     = (const float*)d_in[24];
    const float* ff_W1     = (const float*)d_in[25];
    const float* ff_b1     = (const float*)d_in[26];
    const float* ff_W2     = (const float*)d_in[27];
    const float* ff_b2     = (const float*)d_in[28];
    float* out = (float*)d_out;

    // ---- Workspace layout (floats; total 22,544,384 fl = 90.2 MB) ----
    float* ws = (float*)d_ws;
    size_t o = 0;
    float* xonly_f = ws + o; o += (size_t)MM * DINNER;     // 2,097,152
    float* xonly_b = ws + o; o += (size_t)MM * DINNER;
    float* zonly_f = ws + o; o += (size_t)MM * DINNER;
    float* zonly_b = ws + o; o += (size_t)MM * DINNER;
    unsigned short* xm_bf_f = (unsigned short*)(ws + o); o += (size_t)MM * DINNER / 2;
    unsigned short* xm_bf_b = (unsigned short*)(ws + o); o += (size_t)MM * DINNER / 2;
    unsigned short* xmT_f   = (unsigned short*)(ws + o); o += (size_t)MM * DINNER / 2;
    unsigned short* xmT_b   = (unsigned short*)(ws + o); o += (size_t)MM * DINNER / 2;
    unsigned short* deltaT_f= (unsigned short*)(ws + o); o += (size_t)MM * DINNER / 2;  // bf16
    unsigned short* deltaT_b= (unsigned short*)(ws + o); o += (size_t)MM * DINNER / 2;
    float* dbc_f    = ws + o; o += (size_t)MM * 64;
    float* dbc_b    = ws + o; o += (size_t)MM * 64;
    float* dbcT_f   = ws + o; o += (size_t)MM * 64;
    float* dbcT_b   = ws + o; o += (size_t)MM * 64;
    float* y0T_f    = ws + o; o += (size_t)MM * DINNER;    // 2,097,152
    float* y0T_b    = ws + o; o += (size_t)MM * DINNER;
    float* scanP    = ws + o; o += (size_t)NCHUNK * (GTOT / 16) * 16;  // 1,048,576
    float* scanH    = ws + o; o += (size_t)NCHUNK * (GTOT / 16) * 16;
    float* scanCy   = ws + o; o += (size_t)NCHUNK * (GTOT / 16) * 16;

    // ---- Overlays (sequenced reuse of dead regions) ----
    float* cumT_f = xonly_f;   // xonly dead after conv
    float* cumT_b = xonly_b;
    // pre-GEMM bf16 casts in scanP+scanH (dead until pass1)
    unsigned short* x_bf       = (unsigned short*)scanP;
    unsigned short* fm_inW_bf  = x_bf + 1048576;
    unsigned short* bm_inW_bf  = fm_inW_bf + 1048576;
    unsigned short* fm_xpW_bf  = bm_inW_bf + 1048576;
    unsigned short* bm_xpW_bf  = fm_xpW_bf + 65536;
    float* gpartX = y0T_f;     // xproj partials (1,048,576 fl), dead before pass1
    unsigned short* ybf_f = (unsigned short*)scanP;  // P/H dead after carry
    unsigned short* ybf_b = (unsigned short*)scanH;
    // post-scan weight casts in zonly_f (dead after correct)
    unsigned short* fm_outW_bf = (unsigned short*)zonly_f;
    unsigned short* bm_outW_bf = fm_outW_bf + 524288;
    unsigned short* W1_bf      = bm_outW_bf + 524288;
    unsigned short* W2_bf      = W1_bf + 1048576;
    float* gpartO = y0T_f;     // out-proj / FF2 partials (4,194,304 fl, spans y0T_f+b)
    float* proj_f = scanCy;    // carry dead after correct
    float* proj_b = xonly_f;   // cumT dead after correct
    unsigned short* outsum_bf  = (unsigned short*)xonly_b;
    unsigned short* h_bf = (unsigned short*)deltaT_f;  // spans deltaT_f+deltaT_b
    float* ff2 = scanP;        // ybf dead after out-proj

    // ---- 0. pre-GEMM casts ----
    cast_pre_kernel<<<3276800 / 2048, 256, 0, stream>>>(
        x, fm_in_W, bm_in_W, fm_xproj_W, bm_xproj_W, x_bf);

    // ---- 1. in-proj GEMMs, split x/z outputs, both dirs (512 blocks) ----
    gemm_inproj_kernel<<<dim3(2048/128, MM/128, 2), 256, 0, stream>>>(
        x_bf, fm_inW_bf, bm_inW_bf, xonly_f, zonly_f, xonly_b, zonly_b);

    // ---- 2. conv + silu (both dirs) -> bf16 xm[m][d]; transpose -> xmT ----
    conv_silu_kernel<<<dim3((MM * DINNER) / 256, 2), 256, 0, stream>>>(
        xonly_f, xonly_b, fm_conv_W, bm_conv_W, fm_conv_b, bm_conv_b, xm_bf_f, xm_bf_b);
    transpose_bf16_kernel<<<dim3(DINNER/32, MM/32, 2), 256, 0, stream>>>(
        xm_bf_f, xm_bf_b, xmT_f, xmT_b, MM, DINNER);

    // ---- 3. x-proj: split-K x4, both dirs + reduce ----
    xproj_splitk_kernel<<<dim3(MM/128, 8), 256, 0, stream>>>(
        xm_bf_f, xm_bf_b, fm_xpW_bf, bm_xpW_bf, gpartX);
    xproj_reduce_kernel<<<dim3((MM*64)/1024, 2), 256, 0, stream>>>(
        gpartX, dbc_f, dbc_b, dbcT_f, dbcT_b);

    // ---- 4. dt-proj, both dirs -> deltaT bf16 [d][m], softplus ----
    dtproj_batch_kernel<<<dim3(MM/64, DINNER/64, 2), 256, 0, stream>>>(
        DINNER, MM, DTRANK, fm_dt_W, bm_dt_W, DTRANK, dbc_f, dbc_b, 64,
        fm_dt_b, bm_dt_b, deltaT_f, deltaT_b, MM);

    // ---- 5. scan: pass1 (local, zero-state) + carry + parallel correction ----
    scan_pass1_kernel<<<dim3(DINNER/16, BATCH*NCHUNK, 2), 256, 0, stream>>>(
        deltaT_f, deltaT_b, xmT_f, xmT_b, dbcT_f, dbcT_b,
        fm_A_log, bm_A_log, fm_D, bm_D,
        y0T_f, y0T_b, cumT_f, cumT_b, scanP, scanH);
    scan_carry_kernel<<<GTOT/256, 256, 0, stream>>>(scanP, scanH, scanCy);
    scan_correct_kernel<<<dim3(MM/32, DINNER/32, 2), 256, 0, stream>>>(
        y0T_f, y0T_b, cumT_f, cumT_b, dbcT_f, dbcT_b, fm_A_log, bm_A_log,
        scanCy, zonly_f, zonly_b, ybf_f, ybf_b);

    // ---- 6. post weight casts (zonly dead) ----
    cast_post_kernel<<<3145728 / 2048, 256, 0, stream>>>(
        fm_out_W, bm_out_W, ff_W1, ff_W2, fm_outW_bf);

    // ---- 7. out-proj: dirs x splitK2 (256 blocks) + dual reduce ----
    gemm_mfma_splitk<2><<<dim3(DMODEL/128, MM/128, 4), 256, 0, stream>>>(
        MM, DMODEL, DINNER, ybf_f, ybf_b, DINNER, fm_outW_bf, bm_outW_bf, DINNER,
        gpartO, DMODEL);
    reduce_splitk2_dual_kernel<<<dim3((MM*DMODEL)/1024, 2), 256, 0, stream>>>(
        gpartO, proj_f, proj_b);

    // ---- 8. out = LN(xf+fwd) + LN(xf+bwd) -> bf16 ----
    ln_combine_kernel<<<MM, 256, 0, stream>>>(
        x, proj_f, proj_b, ln1_g, ln1_b, ln2_g, ln2_b, outsum_bf);

    // ---- 9. FF1 (256 blocks) ----
    gemm_mfma_batch<1,1><<<dim3(DFF/128, MM/128, 1), 256, 0, stream>>>(
        MM, DFF, DMODEL, outsum_bf, outsum_bf, DMODEL, W1_bf, W1_bf, DMODEL,
        ff_b1, h_bf, h_bf, DFF);

    // ---- 10. FF2: splitK4 (256 blocks) + reduce w/ bias ----
    gemm_mfma_splitk<4><<<dim3(DMODEL/128, MM/128, 4), 256, 0, stream>>>(
        MM, DMODEL, DFF, h_bf, h_bf, DFF, W2_bf, W2_bf, DFF, gpartO, DMODEL);
    reduce_splitk_kernel<<<(MM*DMODEL)/1024, 256, 0, stream>>>(
        gpartO, 4, MM*DMODEL, DMODEL, ff_b2, ff2);

    // ---- 11. final LN(2*ff) ----
    ln_final_kernel<<<MM, 256, 0, stream>>>(ff2, ln3_g, ln3_b, out);
}

// Round 8
// 335.634 us; speedup vs baseline: 4.3156x; 1.0878x over previous
//
#include <hip/hip_runtime.h>
#include <hip/hip_bf16.h>
#include <math.h>

// Problem constants
#define MM 2048        // B*W flattened rows
#define BATCH 2
#define SEQ 1024
#define DMODEL 512
#define DINNER 1024
#define DSTATE 16
#define DTRANK 32
#define DFF 2048

// Chunked-scan constants
#define NCHUNK 16
#define CHUNK 64
#define GTOT 65536          // 2 dirs * BATCH * DINNER * DSTATE

typedef short bf16x8 __attribute__((ext_vector_type(8)));
typedef float floatx4 __attribute__((ext_vector_type(4)));
typedef unsigned short ushort8v __attribute__((ext_vector_type(8)));
typedef unsigned short ushort4v __attribute__((ext_vector_type(4)));

__device__ __forceinline__ unsigned short f2bf(float f) {
    union { float f; unsigned u; } v; v.f = f;
    unsigned r = v.u + 0x7FFF + ((v.u >> 16) & 1);
    return (unsigned short)(r >> 16);
}
__device__ __forceinline__ float bf2f(unsigned short u) {
    union { unsigned u; float f; } v; v.u = ((unsigned)u) << 16; return v.f;
}

// Sum across each 16-lane DPP row via row_ror adds (VALU-only).
__device__ __forceinline__ float rowsum16(float x) {
    union { float f; int i; } a, b;
    a.f = x;
    b.i = __builtin_amdgcn_update_dpp(0, a.i, 0x128, 0xF, 0xF, false); a.f += b.f;
    b.i = __builtin_amdgcn_update_dpp(0, a.i, 0x124, 0xF, 0xF, false); a.f += b.f;
    b.i = __builtin_amdgcn_update_dpp(0, a.i, 0x122, 0xF, 0xF, false); a.f += b.f;
    b.i = __builtin_amdgcn_update_dpp(0, a.i, 0x121, 0xF, 0xF, false); a.f += b.f;
    return a.f;
}

#define GLOAD_LDS16(gp, lp) __builtin_amdgcn_global_load_lds( \
    (const __attribute__((address_space(1))) unsigned int*)(gp), \
    (__attribute__((address_space(3))) unsigned int*)(lp), 16, 0, 0)

// ---------------------------------------------------------------------------
// Batched direct bf16 MFMA GEMM: C[z][M,N] = epi(A[z] @ B[z]^T + bias)
// 128x128 tile, BK=32, 4 waves x (4x4) 16x16x32. Conflict-free LDS layout.
// ---------------------------------------------------------------------------
template<int EPI, int OUTBF16>
__global__ __launch_bounds__(256) void gemm_mfma_batch(
    int M, int N, int K,
    const unsigned short* __restrict__ A0, const unsigned short* __restrict__ A1, int lda,
    const unsigned short* __restrict__ B0, const unsigned short* __restrict__ B1, int ldb,
    const float* __restrict__ bias,
    void* __restrict__ C0, void* __restrict__ C1, int ldc)
{
    __shared__ unsigned short As[128 * 32];
    __shared__ unsigned short Bs[128 * 32];
    const int z = blockIdx.z;
    const unsigned short* A = z ? A1 : A0;
    const unsigned short* B = z ? B1 : B0;
    void* Cout = z ? C1 : C0;
    const int tid  = threadIdx.x;
    const int wave = tid >> 6;
    const int lane = tid & 63;
    const int bm = blockIdx.y * 128;
    const int bn = blockIdx.x * 128;

    const int strow = lane & 15;
    const int stkc  = lane >> 4;
    const int wr = wave >> 1, wc = wave & 1;
    const int frow = lane & 15;
    const int fkc  = lane >> 4;

    floatx4 acc[4][4];
    #pragma unroll
    for (int i = 0; i < 4; ++i)
        #pragma unroll
        for (int j = 0; j < 4; ++j)
            acc[i][j] = (floatx4){0.f, 0.f, 0.f, 0.f};

    for (int k0 = 0; k0 < K; k0 += 32) {
        __syncthreads();
        #pragma unroll
        for (int q = 0; q < 2; ++q) {
            int g = wave * 2 + q;
            GLOAD_LDS16(A + (size_t)(bm + g * 16 + strow) * lda + k0 + stkc * 8,
                        As + g * 512);
        }
        #pragma unroll
        for (int q = 0; q < 2; ++q) {
            int g = wave * 2 + q;
            GLOAD_LDS16(B + (size_t)(bn + g * 16 + strow) * ldb + k0 + stkc * 8,
                        Bs + g * 512);
        }
        __syncthreads();

        bf16x8 af[4], bfr[4];
        #pragma unroll
        for (int i = 0; i < 4; ++i)
            af[i] = *(const bf16x8*)(As + (wr * 4 + i) * 512 + fkc * 128 + frow * 8);
        #pragma unroll
        for (int j = 0; j < 4; ++j)
            bfr[j] = *(const bf16x8*)(Bs + (wc * 4 + j) * 512 + fkc * 128 + frow * 8);
        #pragma unroll
        for (int i = 0; i < 4; ++i)
            #pragma unroll
            for (int j = 0; j < 4; ++j)
                acc[i][j] = __builtin_amdgcn_mfma_f32_16x16x32_bf16(
                    af[i], bfr[j], acc[i][j], 0, 0, 0);
    }

    const int orow0 = bm + wr * 64 + (lane >> 4) * 4;
    const int ocol0 = bn + wc * 64 + (lane & 15);
    #pragma unroll
    for (int j = 0; j < 4; ++j) {
        const int col = ocol0 + j * 16;
        const float bv = bias ? bias[col] : 0.f;
        #pragma unroll
        for (int i = 0; i < 4; ++i) {
            #pragma unroll
            for (int r = 0; r < 4; ++r) {
                int row = orow0 + i * 16 + r;
                float t = acc[i][j][r] + bv;
                if (EPI == 1) t = fmaxf(t, 0.f);
                if (OUTBF16)
                    ((unsigned short*)Cout)[(size_t)row * ldc + col] = f2bf(t);
                else
                    ((float*)Cout)[(size_t)row * ldc + col] = t;
            }
        }
    }
}

// ---------------------------------------------------------------------------
// In-proj GEMM: C split into x-half / z-half buffers (each [M][1024]).
// A shared across dirs; blockIdx.z = dir. M=MM, N=2048, K=512.
// ---------------------------------------------------------------------------
__global__ __launch_bounds__(256) void gemm_inproj_kernel(
    const unsigned short* __restrict__ A,
    const unsigned short* __restrict__ B0, const unsigned short* __restrict__ B1,
    float* __restrict__ Cx0, float* __restrict__ Cz0,
    float* __restrict__ Cx1, float* __restrict__ Cz1)
{
    __shared__ unsigned short As[128 * 32];
    __shared__ unsigned short Bs[128 * 32];
    const int z = blockIdx.z;
    const unsigned short* B = z ? B1 : B0;
    const int tid  = threadIdx.x;
    const int wave = tid >> 6;
    const int lane = tid & 63;
    const int bm = blockIdx.y * 128;
    const int bn = blockIdx.x * 128;

    const int strow = lane & 15;
    const int stkc  = lane >> 4;
    const int wr = wave >> 1, wc = wave & 1;
    const int frow = lane & 15;
    const int fkc  = lane >> 4;

    floatx4 acc[4][4];
    #pragma unroll
    for (int i = 0; i < 4; ++i)
        #pragma unroll
        for (int j = 0; j < 4; ++j)
            acc[i][j] = (floatx4){0.f, 0.f, 0.f, 0.f};

    for (int k0 = 0; k0 < DMODEL; k0 += 32) {
        __syncthreads();
        #pragma unroll
        for (int q = 0; q < 2; ++q) {
            int g = wave * 2 + q;
            GLOAD_LDS16(A + (size_t)(bm + g * 16 + strow) * DMODEL + k0 + stkc * 8,
                        As + g * 512);
        }
        #pragma unroll
        for (int q = 0; q < 2; ++q) {
            int g = wave * 2 + q;
            GLOAD_LDS16(B + (size_t)(bn + g * 16 + strow) * DMODEL + k0 + stkc * 8,
                        Bs + g * 512);
        }
        __syncthreads();

        bf16x8 af[4], bfr[4];
        #pragma unroll
        for (int i = 0; i < 4; ++i)
            af[i] = *(const bf16x8*)(As + (wr * 4 + i) * 512 + fkc * 128 + frow * 8);
        #pragma unroll
        for (int j = 0; j < 4; ++j)
            bfr[j] = *(const bf16x8*)(Bs + (wc * 4 + j) * 512 + fkc * 128 + frow * 8);
        #pragma unroll
        for (int i = 0; i < 4; ++i)
            #pragma unroll
            for (int j = 0; j < 4; ++j)
                acc[i][j] = __builtin_amdgcn_mfma_f32_16x16x32_bf16(
                    af[i], bfr[j], acc[i][j], 0, 0, 0);
    }

    const int zh = bn >= DINNER;
    float* C = z ? (zh ? Cz1 : Cx1) : (zh ? Cz0 : Cx0);
    const int cb = zh ? DINNER : 0;
    const int orow0 = bm + wr * 64 + (lane >> 4) * 4;
    const int ocol0 = bn + wc * 64 + (lane & 15) - cb;
    #pragma unroll
    for (int j = 0; j < 4; ++j) {
        const int col = ocol0 + j * 16;
        #pragma unroll
        for (int i = 0; i < 4; ++i)
            #pragma unroll
            for (int r = 0; r < 4; ++r)
                C[(size_t)(orow0 + i * 16 + r) * DINNER + col] = acc[i][j][r];
    }
}

// ---------------------------------------------------------------------------
// Split-K batched MFMA GEMM -> fp32 partials part[z][M*ldc]. z=dir*NSPLIT+sp.
// ---------------------------------------------------------------------------
template<int NSPLIT>
__global__ __launch_bounds__(256) void gemm_mfma_splitk(
    int M, int N, int K,
    const unsigned short* __restrict__ A0, const unsigned short* __restrict__ A1, int lda,
    const unsigned short* __restrict__ B0, const unsigned short* __restrict__ B1, int ldb,
    float* __restrict__ part, int ldc)
{
    __shared__ unsigned short As[128 * 32];
    __shared__ unsigned short Bs[128 * 32];
    const int z = blockIdx.z;
    const int dir = z / NSPLIT, sp = z % NSPLIT;
    const unsigned short* A = dir ? A1 : A0;
    const unsigned short* B = dir ? B1 : B0;
    float* Cp = part + (size_t)z * M * ldc;
    const int kbeg = sp * (K / NSPLIT);
    const int kend = kbeg + (K / NSPLIT);
    const int tid  = threadIdx.x;
    const int wave = tid >> 6;
    const int lane = tid & 63;
    const int bm = blockIdx.y * 128;
    const int bn = blockIdx.x * 128;

    const int strow = lane & 15;
    const int stkc  = lane >> 4;
    const int wr = wave >> 1, wc = wave & 1;
    const int frow = lane & 15;
    const int fkc  = lane >> 4;

    floatx4 acc[4][4];
    #pragma unroll
    for (int i = 0; i < 4; ++i)
        #pragma unroll
        for (int j = 0; j < 4; ++j)
            acc[i][j] = (floatx4){0.f, 0.f, 0.f, 0.f};

    for (int k0 = kbeg; k0 < kend; k0 += 32) {
        __syncthreads();
        #pragma unroll
        for (int q = 0; q < 2; ++q) {
            int g = wave * 2 + q;
            GLOAD_LDS16(A + (size_t)(bm + g * 16 + strow) * lda + k0 + stkc * 8,
                        As + g * 512);
        }
        #pragma unroll
        for (int q = 0; q < 2; ++q) {
            int g = wave * 2 + q;
            GLOAD_LDS16(B + (size_t)(bn + g * 16 + strow) * ldb + k0 + stkc * 8,
                        Bs + g * 512);
        }
        __syncthreads();

        bf16x8 af[4], bfr[4];
        #pragma unroll
        for (int i = 0; i < 4; ++i)
            af[i] = *(const bf16x8*)(As + (wr * 4 + i) * 512 + fkc * 128 + frow * 8);
        #pragma unroll
        for (int j = 0; j < 4; ++j)
            bfr[j] = *(const bf16x8*)(Bs + (wc * 4 + j) * 512 + fkc * 128 + frow * 8);
        #pragma unroll
        for (int i = 0; i < 4; ++i)
            #pragma unroll
            for (int j = 0; j < 4; ++j)
                acc[i][j] = __builtin_amdgcn_mfma_f32_16x16x32_bf16(
                    af[i], bfr[j], acc[i][j], 0, 0, 0);
    }

    const int orow0 = bm + wr * 64 + (lane >> 4) * 4;
    const int ocol0 = bn + wc * 64 + (lane & 15);
    #pragma unroll
    for (int j = 0; j < 4; ++j) {
        const int col = ocol0 + j * 16;
        #pragma unroll
        for (int i = 0; i < 4; ++i)
            #pragma unroll
            for (int r = 0; r < 4; ++r)
                Cp[(size_t)(orow0 + i * 16 + r) * ldc + col] = acc[i][j][r];
    }
}

// ---------------------------------------------------------------------------
// xproj split-K MFMA: tile 128(m) x 64(n), K slice 256. blockIdx.y=dir*4+sp.
// ---------------------------------------------------------------------------
__global__ __launch_bounds__(256) void xproj_splitk_kernel(
    const unsigned short* __restrict__ A_f, const unsigned short* __restrict__ A_b,
    const unsigned short* __restrict__ Wf,  const unsigned short* __restrict__ Wb,
    float* __restrict__ part)
{
    __shared__ unsigned short As[128 * 32];
    __shared__ unsigned short Bs[64 * 32];
    const int tid = threadIdx.x, wave = tid >> 6, lane = tid & 63;
    const int bm = blockIdx.x * 128;
    const int dir = blockIdx.y >> 2, sp = blockIdx.y & 3;
    const unsigned short* A = dir ? A_b : A_f;
    const unsigned short* W = dir ? Wb  : Wf;
    float* Cp = part + (size_t)blockIdx.y * MM * 64;
    const int kbeg = sp * 256, kend = kbeg + 256;

    const int strow = lane & 15;
    const int stkc  = lane >> 4;
    const int frow = lane & 15;
    const int fkc  = lane >> 4;

    floatx4 acc[2][4];
    #pragma unroll
    for (int i = 0; i < 2; ++i)
        #pragma unroll
        for (int j = 0; j < 4; ++j)
            acc[i][j] = (floatx4){0.f, 0.f, 0.f, 0.f};

    for (int k0 = kbeg; k0 < kend; k0 += 32) {
        __syncthreads();
        #pragma unroll
        for (int q = 0; q < 2; ++q) {
            int g = wave * 2 + q;
            GLOAD_LDS16(A + (size_t)(bm + g * 16 + strow) * DINNER + k0 + stkc * 8,
                        As + g * 512);
        }
        GLOAD_LDS16(W + (size_t)(wave * 16 + strow) * DINNER + k0 + stkc * 8,
                    Bs + wave * 512);
        __syncthreads();

        bf16x8 af[2], bfr[4];
        #pragma unroll
        for (int i = 0; i < 2; ++i)
            af[i] = *(const bf16x8*)(As + (wave * 2 + i) * 512 + fkc * 128 + frow * 8);
        #pragma unroll
        for (int j = 0; j < 4; ++j)
            bfr[j] = *(const bf16x8*)(Bs + j * 512 + fkc * 128 + frow * 8);
        #pragma unroll
        for (int i = 0; i < 2; ++i)
            #pragma unroll
            for (int j = 0; j < 4; ++j)
                acc[i][j] = __builtin_amdgcn_mfma_f32_16x16x32_bf16(
                    af[i], bfr[j], acc[i][j], 0, 0, 0);
    }

    const int orow0 = bm + wave * 32 + (lane >> 4) * 4;
    #pragma unroll
    for (int j = 0; j < 4; ++j) {
        const int col = (lane & 15) + j * 16;
        #pragma unroll
        for (int i = 0; i < 2; ++i)
            #pragma unroll
            for (int r = 0; r < 4; ++r)
                Cp[(size_t)(orow0 + i * 16 + r) * 64 + col] = acc[i][j][r];
    }
}

// ---------------------------------------------------------------------------
// xproj reduce: cols 0..31 -> dbc[m][32] (dt rows); cols 32..63 -> bct[m][32]
// (B then C, m-major: the scan's coalesced layout). grid ((MM*64)/1024, 2).
// ---------------------------------------------------------------------------
__global__ __launch_bounds__(256) void xproj_reduce_kernel(
    const float* __restrict__ part,
    float* __restrict__ dbc_f, float* __restrict__ dbc_b,
    float* __restrict__ bct_f, float* __restrict__ bct_b)
{
    const int dir = blockIdx.y;
    const int i = (blockIdx.x * 256 + threadIdx.x) * 4;
    const float* p = part + (size_t)dir * 4 * (MM * 64);
    float4 a = *(const float4*)(p + i);
    #pragma unroll
    for (int s = 1; s < 4; ++s) {
        float4 t = *(const float4*)(p + (size_t)s * (MM * 64) + i);
        a.x += t.x; a.y += t.y; a.z += t.z; a.w += t.w;
    }
    const int m = i >> 6, c = i & 63;
    if (c < 32) {
        float* dbc = dir ? dbc_b : dbc_f;
        *(float4*)(dbc + (size_t)m * 32 + c) = a;
    } else {
        float* bct = dir ? bct_b : bct_f;
        *(float4*)(bct + (size_t)m * 32 + (c - 32)) = a;
    }
}

// ---------------------------------------------------------------------------
// Batched fp32 GEMM w/ softplus + row bias (dt-proj), bf16 output.
// C[z][M,N] = softplus(A[z][M,K] @ B[z][N,K]^T + biasR[row]), blockIdx.z=dir.
// ---------------------------------------------------------------------------
__global__ __launch_bounds__(256) void dtproj_batch_kernel(
    int M, int N, int K,
    const float* __restrict__ A0, const float* __restrict__ A1, int lda,
    const float* __restrict__ B0, const float* __restrict__ B1, int ldb,
    const float* __restrict__ bias0, const float* __restrict__ bias1,
    unsigned short* __restrict__ C0, unsigned short* __restrict__ C1, int ldc)
{
    __shared__ float As[16][64];
    __shared__ float Bs[16][64];
    const int z = blockIdx.z;
    const float* A = z ? A1 : A0;
    const float* B = z ? B1 : B0;
    const float* biasR = z ? bias1 : bias0;
    unsigned short* C = z ? C1 : C0;
    const int tid = threadIdx.x;
    const int tx = tid & 15, ty = tid >> 4;
    const int bm = blockIdx.y * 64, bn = blockIdx.x * 64;
    const int lm = tid & 63;
    const int lk = (tid >> 6) * 4;
    const float* Arow = A + (size_t)(bm + lm) * lda + lk;
    const float* Brow = B + (size_t)(bn + lm) * ldb + lk;
    float acc[4][4] = {};
    for (int k0 = 0; k0 < K; k0 += 16) {
        float4 av = *(const float4*)(Arow + k0);
        float4 bv = *(const float4*)(Brow + k0);
        __syncthreads();
        As[lk+0][lm] = av.x; As[lk+1][lm] = av.y; As[lk+2][lm] = av.z; As[lk+3][lm] = av.w;
        Bs[lk+0][lm] = bv.x; Bs[lk+1][lm] = bv.y; Bs[lk+2][lm] = bv.z; Bs[lk+3][lm] = bv.w;
        __syncthreads();
        #pragma unroll
        for (int k = 0; k < 16; ++k) {
            float4 a = *(const float4*)(&As[k][ty*4]);
            float4 b = *(const float4*)(&Bs[k][tx*4]);
            float ar[4] = {a.x,a.y,a.z,a.w};
            float br[4] = {b.x,b.y,b.z,b.w};
            #pragma unroll
            for (int i = 0; i < 4; ++i)
                #pragma unroll
                for (int j = 0; j < 4; ++j)
                    acc[i][j] = fmaf(ar[i], br[j], acc[i][j]);
        }
    }
    const int row0 = bm + ty*4, col0 = bn + tx*4;
    #pragma unroll
    for (int i = 0; i < 4; ++i) {
        float br = biasR[row0 + i];
        ushort4v o;
        #pragma unroll
        for (int j = 0; j < 4; ++j) {
            float t = acc[i][j] + br;
            o[j] = f2bf(fmaxf(t, 0.f) + log1pf(__expf(-fabsf(t))));
        }
        *(ushort4v*)(C + (size_t)(row0 + i) * ldc + col0) = o;
    }
}

// ---------------------------------------------------------------------------
// Segmented casts: 5 pre-GEMM arrays -> one contiguous bf16 block.
// ---------------------------------------------------------------------------
__global__ __launch_bounds__(256) void cast_pre_kernel(
    const float* __restrict__ x, const float* __restrict__ w0,
    const float* __restrict__ w1, const float* __restrict__ xp0,
    const float* __restrict__ xp1, unsigned short* __restrict__ dst)
{
    int i = (blockIdx.x * 256 + threadIdx.x) * 8;
    const float* src; int off;
    if      (i < 1048576) { src = x;   off = 0; }
    else if (i < 2097152) { src = w0;  off = 1048576; }
    else if (i < 3145728) { src = w1;  off = 2097152; }
    else if (i < 3211264) { src = xp0; off = 3145728; }
    else                  { src = xp1; off = 3211264; }
    float4 a = *(const float4*)(src + i - off);
    float4 b = *(const float4*)(src + i - off + 4);
    ushort8v o;
    o[0] = f2bf(a.x); o[1] = f2bf(a.y); o[2] = f2bf(a.z); o[3] = f2bf(a.w);
    o[4] = f2bf(b.x); o[5] = f2bf(b.y); o[6] = f2bf(b.z); o[7] = f2bf(b.w);
    *(ushort8v*)(dst + i) = o;
}

// Segments: outW_f(524288) outW_b(524288) W1(1048576) W2(1048576)
__global__ __launch_bounds__(256) void cast_post_kernel(
    const float* __restrict__ w0, const float* __restrict__ w1,
    const float* __restrict__ w2, const float* __restrict__ w3,
    unsigned short* __restrict__ dst)
{
    int i = (blockIdx.x * 256 + threadIdx.x) * 8;
    const float* src; int off;
    if      (i < 524288)  { src = w0; off = 0; }
    else if (i < 1048576) { src = w1; off = 524288; }
    else if (i < 2097152) { src = w2; off = 1048576; }
    else                  { src = w3; off = 2097152; }
    float4 a = *(const float4*)(src + i - off);
    float4 b = *(const float4*)(src + i - off + 4);
    ushort8v o;
    o[0] = f2bf(a.x); o[1] = f2bf(a.y); o[2] = f2bf(a.z); o[3] = f2bf(a.w);
    o[4] = f2bf(b.x); o[5] = f2bf(b.y); o[6] = f2bf(b.z); o[7] = f2bf(b.w);
    *(ushort8v*)(dst + i) = o;
}

// ---------------------------------------------------------------------------
// Depthwise conv + bias + silu -> bf16 xm[m][d]. blockIdx.y = dir.
// ---------------------------------------------------------------------------
__global__ __launch_bounds__(256) void conv_silu_kernel(
    const float* __restrict__ x_f, const float* __restrict__ x_b,
    const float* __restrict__ Wf,  const float* __restrict__ Wb,
    const float* __restrict__ cbf, const float* __restrict__ cbb,
    unsigned short* __restrict__ of, unsigned short* __restrict__ ob)
{
    const int dir = blockIdx.y;
    const float* xo = dir ? x_b : x_f;
    const float* convW = dir ? Wb : Wf;
    const float* convb = dir ? cbb : cbf;
    unsigned short* xm_bf = dir ? ob : of;
    int gid = blockIdx.x * 256 + threadIdx.x;
    int c = gid & (DINNER - 1);
    int m = gid >> 10;
    int b = m >> 10;
    int l = m & (SEQ - 1);
    float4 wv = *(const float4*)(convW + c * 4);
    float w[4] = {wv.x, wv.y, wv.z, wv.w};
    float acc = convb[c];
    #pragma unroll
    for (int j = 0; j < 4; ++j) {
        int p = dir ? (l + 3 - j) : (l - 3 + j);
        if (p >= 0 && p < SEQ)
            acc = fmaf(xo[(size_t)(b * SEQ + p) * DINNER + c], w[j], acc);
    }
    float sig = 1.f / (1.f + __expf(-acc));
    xm_bf[(size_t)m * DINNER + c] = f2bf(acc * sig);
}

// ---------------------------------------------------------------------------
// bf16 transpose (both dirs): in[R][C] -> out[C][R]. blockIdx.z = dir.
// ---------------------------------------------------------------------------
__global__ __launch_bounds__(256) void transpose_bf16_kernel(
    const unsigned short* __restrict__ in0, const unsigned short* __restrict__ in1,
    unsigned short* __restrict__ out0, unsigned short* __restrict__ out1,
    int R, int C)
{
    __shared__ unsigned short t[32][34];
    const unsigned short* in = blockIdx.z ? in1 : in0;
    unsigned short* out = blockIdx.z ? out1 : out0;
    const int c0 = blockIdx.x * 32, r0 = blockIdx.y * 32;
    const int tx = threadIdx.x & 31, ty = threadIdx.x >> 5;
    #pragma unroll
    for (int rr = 0; rr < 32; rr += 8)
        t[ty + rr][tx] = in[(size_t)(r0 + ty + rr) * C + c0 + tx];
    __syncthreads();
    #pragma unroll
    for (int rr = 0; rr < 32; rr += 8)
        out[(size_t)(c0 + ty + rr) * R + r0 + tx] = t[tx][ty + rr];
}

// ---------------------------------------------------------------------------
// Scan pass 1: local scan from zero state. Emits y0 (bf16, incl. D*x),
// running cumdl (fp32, s==0 lane), chunk P = exp(A*sum dl), H = end state.
// B/C loads use bct[m][32] (coalesced across the 16-lane state row).
// ---------------------------------------------------------------------------
template<int DIR>
__device__ __forceinline__ void pass1_body(
    const unsigned short* __restrict__ deltaT, const unsigned short* __restrict__ xmT,
    const float* __restrict__ bct, const float* __restrict__ Alog,
    const float* __restrict__ Dv,
    unsigned short* __restrict__ y0T, float* __restrict__ cumT,
    float* __restrict__ Pout, float* __restrict__ Hout)
{
    const int tid = threadIdx.x;
    const int s = tid & 15;
    const int dloc = tid >> 4;
    const int d = blockIdx.x * 16 + dloc;
    const int b = blockIdx.y / NCHUNK;
    const int c = blockIdx.y % NCHUNK;

    const float A  = -__expf(Alog[d * DSTATE + s]);
    const float Dp = Dv[d];
    const unsigned short* dRow = deltaT + (size_t)d * MM + b * SEQ;
    const unsigned short* xRow = xmT + (size_t)d * MM + b * SEQ;
    const float* bcRow = bct + (size_t)(b * SEQ) * 32 + s;
    unsigned short* yRow = y0T + (size_t)d * MM + b * SEQ;
    float* uRow = cumT + (size_t)d * MM + b * SEQ;

    float h = 0.f, sdl = 0.f;
    const int segBase = DIR ? (SEQ - CHUNK - c * CHUNK) : (c * CHUNK);
    for (int ii = 0; ii < CHUNK; ii += 8) {
        const int off = DIR ? (segBase + (CHUNK - 8) - ii) : (segBase + ii);
        ushort8v dl8 = *(const ushort8v*)(dRow + off);
        ushort8v x8  = *(const ushort8v*)(xRow + off);
        const float* bp = bcRow + (size_t)off * 32;
        float Bv[8], Cv[8];
        #pragma unroll
        for (int u = 0; u < 8; ++u) {
            Bv[u] = bp[u * 32];
            Cv[u] = bp[u * 32 + 16];
        }
        float yv[8], cu[8];
        #pragma unroll
        for (int u = 0; u < 8; ++u) {
            const int t = DIR ? (7 - u) : u;
            float dlv = bf2f(dl8[t]);
            float xv  = bf2f(x8[t]);
            float dA = __expf(dlv * A);
            sdl += dlv;
            h = fmaf(dA, h, dlv * Bv[t] * xv);
            float part = rowsum16(h * Cv[t]);
            yv[t] = fmaf(xv, Dp, part);
            cu[t] = sdl;
        }
        if (s == 0) {
            ushort8v y8;
            #pragma unroll
            for (int u = 0; u < 8; ++u) y8[u] = f2bf(yv[u]);
            *(ushort8v*)(yRow + off) = y8;
            *(float4*)(uRow + off)     = (float4){cu[0], cu[1], cu[2], cu[3]};
            *(float4*)(uRow + off + 4) = (float4){cu[4], cu[5], cu[6], cu[7]};
        }
    }
    const int g = ((DIR * BATCH + b) * DINNER + d) * DSTATE + s;
    Pout[(size_t)c * GTOT + g] = __expf(sdl * A);
    Hout[(size_t)c * GTOT + g] = h;
}

__global__ __launch_bounds__(256) void scan_pass1_kernel(
    const unsigned short* __restrict__ dT_f, const unsigned short* __restrict__ dT_b,
    const unsigned short* __restrict__ xT_f, const unsigned short* __restrict__ xT_b,
    const float* __restrict__ bct_f, const float* __restrict__ bct_b,
    const float* __restrict__ Alog_f, const float* __restrict__ Alog_b,
    const float* __restrict__ D_f, const float* __restrict__ D_b,
    unsigned short* __restrict__ y0T_f, unsigned short* __restrict__ y0T_b,
    float* __restrict__ cumT_f, float* __restrict__ cumT_b,
    float* __restrict__ Pout, float* __restrict__ Hout)
{
    if (blockIdx.z == 0)
        pass1_body<0>(dT_f, xT_f, bct_f, Alog_f, D_f, y0T_f, cumT_f, Pout, Hout);
    else
        pass1_body<1>(dT_b, xT_b, bct_b, Alog_b, D_b, y0T_b, cumT_b, Pout, Hout);
}

// ---------------------------------------------------------------------------
// Phase 2: sequential combine over chunks.
// ---------------------------------------------------------------------------
__global__ __launch_bounds__(256) void scan_carry_kernel(
    const float* __restrict__ P, const float* __restrict__ H,
    float* __restrict__ carry)
{
    const int g = blockIdx.x * 256 + threadIdx.x;
    float h = 0.f;
    #pragma unroll
    for (int c = 0; c < NCHUNK; ++c) {
        carry[(size_t)c * GTOT + g] = h;
        h = fmaf(P[(size_t)c * GTOT + g], h, H[(size_t)c * GTOT + g]);
    }
}

// ---------------------------------------------------------------------------
// Correction pass (fully parallel):
//   y[m,d] = y0[m,d] + sum_s C[m,s]*carry[d,s]*exp(A[d,s]*cumdl[m,d])
// then *= silu(z), transpose -> ybf[m][d]. blockIdx.z = dir.
// ---------------------------------------------------------------------------
__global__ __launch_bounds__(256) void scan_correct_kernel(
    const unsigned short* __restrict__ y0T_f, const unsigned short* __restrict__ y0T_b,
    const float* __restrict__ cumT_f, const float* __restrict__ cumT_b,
    const float* __restrict__ bct_f, const float* __restrict__ bct_b,
    const float* __restrict__ Alog_f, const float* __restrict__ Alog_b,
    const float* __restrict__ carry,
    const float* __restrict__ z_f, const float* __restrict__ z_b,
    unsigned short* __restrict__ ybf_f, unsigned short* __restrict__ ybf_b)
{
    __shared__ float Cs[16][33];   // C[s][m-local]
    __shared__ float Asm[32][16];  // A per (d-local, s)
    __shared__ float Cy[32][16];   // carry per (d-local, s)
    __shared__ float t[32][33];    // transpose buffer

    const int dir = blockIdx.z;
    const unsigned short* y0T = dir ? y0T_b : y0T_f;
    const float* cumT = dir ? cumT_b : cumT_f;
    const float* bct  = dir ? bct_b  : bct_f;
    const float* Alog = dir ? Alog_b : Alog_f;
    const float* zon  = dir ? z_b    : z_f;
    unsigned short* ybf = dir ? ybf_b : ybf_f;

    const int m0 = blockIdx.x * 32, d0 = blockIdx.y * 32;
    const int b = m0 >> 10;
    const int l0 = m0 & (SEQ - 1);
    const int c = dir ? ((SEQ - 1 - l0) >> 6) : (l0 >> 6);

    for (int idx = threadIdx.x; idx < 512; idx += 256) {
        int s1 = idx & 15, ml = idx >> 4;
        Cs[s1][ml] = bct[(size_t)(m0 + ml) * 32 + 16 + s1];
        int dl2 = idx >> 4, s2 = idx & 15;
        Asm[dl2][s2] = -__expf(Alog[(d0 + dl2) * DSTATE + s2]);
        Cy[dl2][s2] = carry[(size_t)c * GTOT
            + ((size_t)(dir * BATCH + b) * DINNER + d0 + dl2) * DSTATE + s2];
    }
    __syncthreads();

    const int tx = threadIdx.x & 31, ty = threadIdx.x >> 5;
    #pragma unroll
    for (int rr = 0; rr < 32; rr += 8) {
        const int dloc = ty + rr;
        const size_t base = (size_t)(d0 + dloc) * MM + m0 + tx;
        float u  = cumT[base];
        float y0 = bf2f(y0T[base]);
        float corr = 0.f;
        #pragma unroll
        for (int s = 0; s < DSTATE; ++s)
            corr = fmaf(Cs[s][tx] * Cy[dloc][s], __expf(Asm[dloc][s] * u), corr);
        t[dloc][tx] = y0 + corr;
    }
    __syncthreads();
    #pragma unroll
    for (int rr = 0; rr < 32; rr += 8) {
        int m = m0 + ty + rr, d = d0 + tx;
        float z = zon[(size_t)m * DINNER + d];
        float sig = 1.f / (1.f + __expf(-z));
        ybf[(size_t)m * DINNER + d] = f2bf(t[tx][ty + rr] * (z * sig));
    }
}

// ---------------------------------------------------------------------------
// Fused split-K reduce + dual LN:
// out[m,:] = LN(x + p0+p1; g1,b1) + LN(x + p2+p3; g2,b2) -> bf16.
// part = out-proj partials [4][MM*DMODEL] (dir0: 0,1; dir1: 2,3).
// ---------------------------------------------------------------------------
__global__ __launch_bounds__(256) void ln_combine_fused_kernel(
    const float* __restrict__ xf, const float* __restrict__ part,
    const float* __restrict__ g1, const float* __restrict__ b1,
    const float* __restrict__ g2, const float* __restrict__ b2,
    unsigned short* __restrict__ out)
{
    const int m = blockIdx.x;
    const int tid = threadIdx.x;
    const float* xr = xf + (size_t)m * DMODEL;
    const float* p0 = part + (size_t)m * DMODEL;
    const float* p1 = p0 + (size_t)MM * DMODEL;
    const float* p2 = p1 + (size_t)MM * DMODEL;
    const float* p3 = p2 + (size_t)MM * DMODEL;
    float v1a = xr[tid]       + p0[tid]       + p1[tid];
    float v1b = xr[tid + 256] + p0[tid + 256] + p1[tid + 256];
    float v2a = xr[tid]       + p2[tid]       + p3[tid];
    float v2b = xr[tid + 256] + p2[tid + 256] + p3[tid + 256];
    float s1 = v1a + v1b, q1 = v1a*v1a + v1b*v1b;
    float s2 = v2a + v2b, q2 = v2a*v2a + v2b*v2b;
    #pragma unroll
    for (int off = 32; off; off >>= 1) {
        s1 += __shfl_xor(s1, off); q1 += __shfl_xor(q1, off);
        s2 += __shfl_xor(s2, off); q2 += __shfl_xor(q2, off);
    }
    __shared__ float sm[4][4];
    const int w = tid >> 6;
    if ((tid & 63) == 0) { sm[w][0] = s1; sm[w][1] = q1; sm[w][2] = s2; sm[w][3] = q2; }
    __syncthreads();
    s1 = sm[0][0] + sm[1][0] + sm[2][0] + sm[3][0];
    q1 = sm[0][1] + sm[1][1] + sm[2][1] + sm[3][1];
    s2 = sm[0][2] + sm[1][2] + sm[2][2] + sm[3][2];
    q2 = sm[0][3] + sm[1][3] + sm[2][3] + sm[3][3];
    const float inv = 1.f / DMODEL;
    float mu1 = s1 * inv, mu2 = s2 * inv;
    float rs1 = rsqrtf(q1 * inv - mu1 * mu1 + 1e-5f);
    float rs2 = rsqrtf(q2 * inv - mu2 * mu2 + 1e-5f);
    unsigned short* orow = out + (size_t)m * DMODEL;
    orow[tid]       = f2bf((v1a - mu1) * rs1 * g1[tid]       + b1[tid]
                         + (v2a - mu2) * rs2 * g2[tid]       + b2[tid]);
    orow[tid + 256] = f2bf((v1b - mu1) * rs1 * g1[tid + 256] + b1[tid + 256]
                         + (v2b - mu2) * rs2 * g2[tid + 256] + b2[tid + 256]);
}

// ---------------------------------------------------------------------------
// Fused FF2 split-K4 reduce + bias + LN(2*ff): part [4][MM*DMODEL].
// ---------------------------------------------------------------------------
__global__ __launch_bounds__(256) void ln_final_fused_kernel(
    const float* __restrict__ part, const float* __restrict__ bias,
    const float* __restrict__ g, const float* __restrict__ b,
    float* __restrict__ out)
{
    const int m = blockIdx.x;
    const int tid = threadIdx.x;
    const size_t stride = (size_t)MM * DMODEL;
    const float* p = part + (size_t)m * DMODEL;
    float fa = bias[tid]       + p[tid]       + p[stride + tid]
             + p[2*stride + tid]       + p[3*stride + tid];
    float fb = bias[tid + 256] + p[tid + 256] + p[stride + tid + 256]
             + p[2*stride + tid + 256] + p[3*stride + tid + 256];
    float va = 2.f * fa, vb = 2.f * fb;
    float s = va + vb, q = va*va + vb*vb;
    #pragma unroll
    for (int off = 32; off; off >>= 1) {
        s += __shfl_xor(s, off); q += __shfl_xor(q, off);
    }
    __shared__ float sm[4][2];
    const int w = tid >> 6;
    if ((tid & 63) == 0) { sm[w][0] = s; sm[w][1] = q; }
    __syncthreads();
    s = sm[0][0] + sm[1][0] + sm[2][0] + sm[3][0];
    q = sm[0][1] + sm[1][1] + sm[2][1] + sm[3][1];
    const float inv = 1.f / DMODEL;
    float mu = s * inv;
    float rs = rsqrtf(q * inv - mu * mu + 1e-5f);
    float* orow = out + (size_t)m * DMODEL;
    orow[tid]       = (va - mu) * rs * g[tid]       + b[tid];
    orow[tid + 256] = (vb - mu) * rs * g[tid + 256] + b[tid + 256];
}

// ---------------------------------------------------------------------------
extern "C" void kernel_launch(void* const* d_in, const int* in_sizes, int n_in,
                              void* d_out, int out_size, void* d_ws, size_t ws_size,
                              hipStream_t stream)
{
    const float* x         = (const float*)d_in[0];
    const float* fm_in_W   = (const float*)d_in[1];
    const float* fm_conv_W = (const float*)d_in[2];
    const float* fm_conv_b = (const float*)d_in[3];
    const float* fm_xproj_W= (const float*)d_in[4];
    const float* fm_dt_W   = (const float*)d_in[5];
    const float* fm_dt_b   = (const float*)d_in[6];
    const float* fm_A_log  = (const float*)d_in[7];
    const float* fm_D      = (const float*)d_in[8];
    const float* fm_out_W  = (const float*)d_in[9];
    const float* bm_in_W   = (const float*)d_in[10];
    const float* bm_conv_W = (const float*)d_in[11];
    const float* bm_conv_b = (const float*)d_in[12];
    const float* bm_xproj_W= (const float*)d_in[13];
    const float* bm_dt_W   = (const float*)d_in[14];
    const float* bm_dt_b   = (const float*)d_in[15];
    const float* bm_A_log  = (const float*)d_in[16];
    const float* bm_D      = (const float*)d_in[17];
    const float* bm_out_W  = (const float*)d_in[18];
    const float* ln1_g     = (const float*)d_in[19];
    const float* ln1_b     = (const float*)d_in[20];
    const float* ln2_g     = (const float*)d_in[21];
    const float* ln2_b     = (const float*)d_in[22];
    const float* ln3_g     = (const float*)d_in[23];
    const float* ln3_b     = (const float*)d_in[24];
    const float* ff_W1     = (const float*)d_in[25];
    const float* ff_b1     = (const float*)d_in[26];
    const float* ff_W2     = (const float*)d_in[27];
    const float* ff_b2     = (const float*)d_in[28];
    float* out = (float*)d_out;

    // ---- Workspace layout (floats; total 23,330,816 fl = 93.3 MB) ----
    float* ws = (float*)d_ws;
    size_t o = 0;
    float* xonly_f = ws + o; o += (size_t)MM * DINNER;     // 2,097,152
    float* xonly_b = ws + o; o += (size_t)MM * DINNER;
    float* zonly_f = ws + o; o += (size_t)MM * DINNER;
    float* zonly_b = ws + o; o += (size_t)MM * DINNER;
    unsigned short* xm_bf_f = (unsigned short*)(ws + o); o += (size_t)MM * DINNER / 2;
    unsigned short* xm_bf_b = (unsigned short*)(ws + o); o += (size_t)MM * DINNER / 2;
    unsigned short* xmT_f   = (unsigned short*)(ws + o); o += (size_t)MM * DINNER / 2;
    unsigned short* xmT_b   = (unsigned short*)(ws + o); o += (size_t)MM * DINNER / 2;
    unsigned short* deltaT_f= (unsigned short*)(ws + o); o += (size_t)MM * DINNER / 2;
    unsigned short* deltaT_b= (unsigned short*)(ws + o); o += (size_t)MM * DINNER / 2;
    float* dbc_f    = ws + o; o += (size_t)MM * 32;        // 65,536
    float* dbc_b    = ws + o; o += (size_t)MM * 32;
    float* bct_f    = ws + o; o += (size_t)MM * 32;
    float* bct_b    = ws + o; o += (size_t)MM * 32;
    unsigned short* y0T_f = (unsigned short*)(ws + o); o += (size_t)MM * DINNER / 2;
    unsigned short* y0T_b = (unsigned short*)(ws + o); o += (size_t)MM * DINNER / 2;
    float* scanP    = ws + o; o += (size_t)NCHUNK * (GTOT / 16) * 16;  // 1,048,576
    float* scanH    = ws + o; o += (size_t)NCHUNK * (GTOT / 16) * 16;
    float* scanCy   = ws + o; o += (size_t)NCHUNK * (GTOT / 16) * 16;
    float* gpart    = ws + o; o += (size_t)4 * MM * DMODEL;            // 4,194,304

    // ---- Overlays ----
    float* cumT_f = xonly_f;   // xonly dead after conv
    float* cumT_b = xonly_b;
    unsigned short* x_bf       = (unsigned short*)scanP;   // dead until pass1
    unsigned short* fm_inW_bf  = x_bf + 1048576;
    unsigned short* bm_inW_bf  = fm_inW_bf + 1048576;
    unsigned short* fm_xpW_bf  = bm_inW_bf + 1048576;
    unsigned short* bm_xpW_bf  = fm_xpW_bf + 65536;
    unsigned short* ybf_f = (unsigned short*)scanP;        // P/H dead after carry
    unsigned short* ybf_b = (unsigned short*)scanH;
    unsigned short* fm_outW_bf = (unsigned short*)zonly_f; // zonly dead after correct
    unsigned short* bm_outW_bf = fm_outW_bf + 524288;
    unsigned short* W1_bf      = bm_outW_bf + 524288;
    unsigned short* W2_bf      = W1_bf + 1048576;
    unsigned short* outsum_bf  = (unsigned short*)xonly_b; // cumT_b dead after correct
    unsigned short* h_bf = (unsigned short*)deltaT_f;      // deltaT dead after pass1

    // ---- 0. pre-GEMM casts ----
    cast_pre_kernel<<<3276800 / 2048, 256, 0, stream>>>(
        x, fm_in_W, bm_in_W, fm_xproj_W, bm_xproj_W, x_bf);

    // ---- 1. in-proj GEMMs, split x/z outputs, both dirs (512 blocks) ----
    gemm_inproj_kernel<<<dim3(2048/128, MM/128, 2), 256, 0, stream>>>(
        x_bf, fm_inW_bf, bm_inW_bf, xonly_f, zonly_f, xonly_b, zonly_b);

    // ---- 2. conv + silu (both dirs) -> bf16 xm[m][d]; transpose -> xmT ----
    conv_silu_kernel<<<dim3((MM * DINNER) / 256, 2), 256, 0, stream>>>(
        xonly_f, xonly_b, fm_conv_W, bm_conv_W, fm_conv_b, bm_conv_b, xm_bf_f, xm_bf_b);
    transpose_bf16_kernel<<<dim3(DINNER/32, MM/32, 2), 256, 0, stream>>>(
        xm_bf_f, xm_bf_b, xmT_f, xmT_b, MM, DINNER);

    // ---- 3. x-proj: split-K x4, both dirs + reduce -> dbc[m][32], bct[m][32] ----
    xproj_splitk_kernel<<<dim3(MM/128, 8), 256, 0, stream>>>(
        xm_bf_f, xm_bf_b, fm_xpW_bf, bm_xpW_bf, gpart);
    xproj_reduce_kernel<<<dim3((MM*64)/1024, 2), 256, 0, stream>>>(
        gpart, dbc_f, dbc_b, bct_f, bct_b);

    // ---- 4. dt-proj, both dirs -> deltaT bf16 [d][m], softplus ----
    dtproj_batch_kernel<<<dim3(MM/64, DINNER/64, 2), 256, 0, stream>>>(
        DINNER, MM, DTRANK, fm_dt_W, bm_dt_W, DTRANK, dbc_f, dbc_b, 32,
        fm_dt_b, bm_dt_b, deltaT_f, deltaT_b, MM);

    // ---- 5. scan: pass1 + carry + parallel correction ----
    scan_pass1_kernel<<<dim3(DINNER/16, BATCH*NCHUNK, 2), 256, 0, stream>>>(
        deltaT_f, deltaT_b, xmT_f, xmT_b, bct_f, bct_b,
        fm_A_log, bm_A_log, fm_D, bm_D,
        y0T_f, y0T_b, cumT_f, cumT_b, scanP, scanH);
    scan_carry_kernel<<<GTOT/256, 256, 0, stream>>>(scanP, scanH, scanCy);
    scan_correct_kernel<<<dim3(MM/32, DINNER/32, 2), 256, 0, stream>>>(
        y0T_f, y0T_b, cumT_f, cumT_b, bct_f, bct_b, fm_A_log, bm_A_log,
        scanCy, zonly_f, zonly_b, ybf_f, ybf_b);

    // ---- 6. post weight casts (zonly dead) ----
    cast_post_kernel<<<3145728 / 2048, 256, 0, stream>>>(
        fm_out_W, bm_out_W, ff_W1, ff_W2, fm_outW_bf);

    // ---- 7. out-proj: dirs x splitK2 (256 blocks) -> gpart ----
    gemm_mfma_splitk<2><<<dim3(DMODEL/128, MM/128, 4), 256, 0, stream>>>(
        MM, DMODEL, DINNER, ybf_f, ybf_b, DINNER, fm_outW_bf, bm_outW_bf, DINNER,
        gpart, DMODEL);

    // ---- 8. fused reduce + dual LN -> bf16 outsum ----
    ln_combine_fused_kernel<<<MM, 256, 0, stream>>>(
        x, gpart, ln1_g, ln1_b, ln2_g, ln2_b, outsum_bf);

    // ---- 9. FF1 (256 blocks) ----
    gemm_mfma_batch<1,1><<<dim3(DFF/128, MM/128, 1), 256, 0, stream>>>(
        MM, DFF, DMODEL, outsum_bf, outsum_bf, DMODEL, W1_bf, W1_bf, DMODEL,
        ff_b1, h_bf, h_bf, DFF);

    // ---- 10. FF2: splitK4 (256 blocks) -> gpart ----
    gemm_mfma_splitk<4><<<dim3(DMODEL/128, MM/128, 4), 256, 0, stream>>>(
        MM, DMODEL, DFF, h_bf, h_bf, DFF, W2_bf, W2_bf, DFF, gpart, DMODEL);

    // ---- 11. fused reduce + bias + final LN(2*ff) ----
    ln_final_fused_kernel<<<MM, 256, 0, stream>>>(
        gpart, ff_b2, ln3_g, ln3_b, out);
}

// Round 10
// 330.870 us; speedup vs baseline: 4.3777x; 1.0144x over previous
//
#include <hip/hip_runtime.h>
#include <hip/hip_bf16.h>
#include <math.h>

// Problem constants
#define MM 2048        // B*W flattened rows
#define BATCH 2
#define SEQ 1024
#define DMODEL 512
#define DINNER 1024
#define DSTATE 16
#define DTRANK 32
#define DFF 2048

// Chunked-scan constants
#define NCHUNK 16
#define CHUNK 64
#define GTOT 65536          // 2 dirs * BATCH * DINNER * DSTATE

typedef short bf16x8 __attribute__((ext_vector_type(8)));
typedef float floatx4 __attribute__((ext_vector_type(4)));
typedef unsigned short ushort8v __attribute__((ext_vector_type(8)));
typedef unsigned short ushort4v __attribute__((ext_vector_type(4)));

__device__ __forceinline__ unsigned short f2bf(float f) {
    union { float f; unsigned u; } v; v.f = f;
    unsigned r = v.u + 0x7FFF + ((v.u >> 16) & 1);
    return (unsigned short)(r >> 16);
}
__device__ __forceinline__ float bf2f(unsigned short u) {
    union { unsigned u; float f; } v; v.u = ((unsigned)u) << 16; return v.f;
}

// Sum across each 16-lane DPP row via row_ror adds (VALU-only).
__device__ __forceinline__ float rowsum16(float x) {
    union { float f; int i; } a, b;
    a.f = x;
    b.i = __builtin_amdgcn_update_dpp(0, a.i, 0x128, 0xF, 0xF, false); a.f += b.f;
    b.i = __builtin_amdgcn_update_dpp(0, a.i, 0x124, 0xF, 0xF, false); a.f += b.f;
    b.i = __builtin_amdgcn_update_dpp(0, a.i, 0x122, 0xF, 0xF, false); a.f += b.f;
    b.i = __builtin_amdgcn_update_dpp(0, a.i, 0x121, 0xF, 0xF, false); a.f += b.f;
    return a.f;
}

#define GLOAD_LDS16(gp, lp) __builtin_amdgcn_global_load_lds( \
    (const __attribute__((address_space(1))) unsigned int*)(gp), \
    (__attribute__((address_space(3))) unsigned int*)(lp), 16, 0, 0)

// NOTE: single-buffered barrier-stage-barrier K-loops only. The LDS
// double-buffer variant (stage next tile after the barrier) RACES on this
// compiler: the waitcnt pass ties the LDS-DMA drain to aliasing ds_reads,
// which never alias the freshest DMA in a dbuf loop -> missing vmcnt wait
// across the loop backedge (round-9 post-timing divergence).

// ---------------------------------------------------------------------------
// Batched direct bf16 MFMA GEMM: C[z][M,N] = epi(A[z] @ B[z]^T + bias)
// 128x128 tile, BK=32, 4 waves x (4x4) 16x16x32. Conflict-free LDS layout.
// ---------------------------------------------------------------------------
template<int EPI, int OUTBF16>
__global__ __launch_bounds__(256) void gemm_mfma_batch(
    int M, int N, int K,
    const unsigned short* __restrict__ A0, const unsigned short* __restrict__ A1, int lda,
    const unsigned short* __restrict__ B0, const unsigned short* __restrict__ B1, int ldb,
    const float* __restrict__ bias,
    void* __restrict__ C0, void* __restrict__ C1, int ldc)
{
    __shared__ unsigned short As[128 * 32];
    __shared__ unsigned short Bs[128 * 32];
    const int z = blockIdx.z;
    const unsigned short* A = z ? A1 : A0;
    const unsigned short* B = z ? B1 : B0;
    void* Cout = z ? C1 : C0;
    const int tid  = threadIdx.x;
    const int wave = tid >> 6;
    const int lane = tid & 63;
    const int bm = blockIdx.y * 128;
    const int bn = blockIdx.x * 128;

    const int strow = lane & 15;
    const int stkc  = lane >> 4;
    const int wr = wave >> 1, wc = wave & 1;
    const int frow = lane & 15;
    const int fkc  = lane >> 4;

    floatx4 acc[4][4];
    #pragma unroll
    for (int i = 0; i < 4; ++i)
        #pragma unroll
        for (int j = 0; j < 4; ++j)
            acc[i][j] = (floatx4){0.f, 0.f, 0.f, 0.f};

    for (int k0 = 0; k0 < K; k0 += 32) {
        __syncthreads();
        #pragma unroll
        for (int q = 0; q < 2; ++q) {
            int g = wave * 2 + q;
            GLOAD_LDS16(A + (size_t)(bm + g * 16 + strow) * lda + k0 + stkc * 8,
                        As + g * 512);
        }
        #pragma unroll
        for (int q = 0; q < 2; ++q) {
            int g = wave * 2 + q;
            GLOAD_LDS16(B + (size_t)(bn + g * 16 + strow) * ldb + k0 + stkc * 8,
                        Bs + g * 512);
        }
        __syncthreads();

        bf16x8 af[4], bfr[4];
        #pragma unroll
        for (int i = 0; i < 4; ++i)
            af[i] = *(const bf16x8*)(As + (wr * 4 + i) * 512 + fkc * 128 + frow * 8);
        #pragma unroll
        for (int j = 0; j < 4; ++j)
            bfr[j] = *(const bf16x8*)(Bs + (wc * 4 + j) * 512 + fkc * 128 + frow * 8);
        #pragma unroll
        for (int i = 0; i < 4; ++i)
            #pragma unroll
            for (int j = 0; j < 4; ++j)
                acc[i][j] = __builtin_amdgcn_mfma_f32_16x16x32_bf16(
                    af[i], bfr[j], acc[i][j], 0, 0, 0);
    }

    const int orow0 = bm + wr * 64 + (lane >> 4) * 4;
    const int ocol0 = bn + wc * 64 + (lane & 15);
    #pragma unroll
    for (int j = 0; j < 4; ++j) {
        const int col = ocol0 + j * 16;
        const float bv = bias ? bias[col] : 0.f;
        #pragma unroll
        for (int i = 0; i < 4; ++i) {
            #pragma unroll
            for (int r = 0; r < 4; ++r) {
                int row = orow0 + i * 16 + r;
                float t = acc[i][j][r] + bv;
                if (EPI == 1) t = fmaxf(t, 0.f);
                if (OUTBF16)
                    ((unsigned short*)Cout)[(size_t)row * ldc + col] = f2bf(t);
                else
                    ((float*)Cout)[(size_t)row * ldc + col] = t;
            }
        }
    }
}

// ---------------------------------------------------------------------------
// In-proj GEMM: C split into x-half / z-half buffers (each [M][1024]).
// A shared across dirs; blockIdx.z = dir. M=MM, N=2048, K=512.
// ---------------------------------------------------------------------------
__global__ __launch_bounds__(256) void gemm_inproj_kernel(
    const unsigned short* __restrict__ A,
    const unsigned short* __restrict__ B0, const unsigned short* __restrict__ B1,
    float* __restrict__ Cx0, float* __restrict__ Cz0,
    float* __restrict__ Cx1, float* __restrict__ Cz1)
{
    __shared__ unsigned short As[128 * 32];
    __shared__ unsigned short Bs[128 * 32];
    const int z = blockIdx.z;
    const unsigned short* B = z ? B1 : B0;
    const int tid  = threadIdx.x;
    const int wave = tid >> 6;
    const int lane = tid & 63;
    const int bm = blockIdx.y * 128;
    const int bn = blockIdx.x * 128;

    const int strow = lane & 15;
    const int stkc  = lane >> 4;
    const int wr = wave >> 1, wc = wave & 1;
    const int frow = lane & 15;
    const int fkc  = lane >> 4;

    floatx4 acc[4][4];
    #pragma unroll
    for (int i = 0; i < 4; ++i)
        #pragma unroll
        for (int j = 0; j < 4; ++j)
            acc[i][j] = (floatx4){0.f, 0.f, 0.f, 0.f};

    for (int k0 = 0; k0 < DMODEL; k0 += 32) {
        __syncthreads();
        #pragma unroll
        for (int q = 0; q < 2; ++q) {
            int g = wave * 2 + q;
            GLOAD_LDS16(A + (size_t)(bm + g * 16 + strow) * DMODEL + k0 + stkc * 8,
                        As + g * 512);
        }
        #pragma unroll
        for (int q = 0; q < 2; ++q) {
            int g = wave * 2 + q;
            GLOAD_LDS16(B + (size_t)(bn + g * 16 + strow) * DMODEL + k0 + stkc * 8,
                        Bs + g * 512);
        }
        __syncthreads();

        bf16x8 af[4], bfr[4];
        #pragma unroll
        for (int i = 0; i < 4; ++i)
            af[i] = *(const bf16x8*)(As + (wr * 4 + i) * 512 + fkc * 128 + frow * 8);
        #pragma unroll
        for (int j = 0; j < 4; ++j)
            bfr[j] = *(const bf16x8*)(Bs + (wc * 4 + j) * 512 + fkc * 128 + frow * 8);
        #pragma unroll
        for (int i = 0; i < 4; ++i)
            #pragma unroll
            for (int j = 0; j < 4; ++j)
                acc[i][j] = __builtin_amdgcn_mfma_f32_16x16x32_bf16(
                    af[i], bfr[j], acc[i][j], 0, 0, 0);
    }

    const int zh = bn >= DINNER;
    float* C = z ? (zh ? Cz1 : Cx1) : (zh ? Cz0 : Cx0);
    const int cb = zh ? DINNER : 0;
    const int orow0 = bm + wr * 64 + (lane >> 4) * 4;
    const int ocol0 = bn + wc * 64 + (lane & 15) - cb;
    #pragma unroll
    for (int j = 0; j < 4; ++j) {
        const int col = ocol0 + j * 16;
        #pragma unroll
        for (int i = 0; i < 4; ++i)
            #pragma unroll
            for (int r = 0; r < 4; ++r)
                C[(size_t)(orow0 + i * 16 + r) * DINNER + col] = acc[i][j][r];
    }
}

// ---------------------------------------------------------------------------
// Split-K batched MFMA GEMM -> fp32 partials part[z][M*ldc]. z=dir*NSPLIT+sp.
// ---------------------------------------------------------------------------
template<int NSPLIT>
__global__ __launch_bounds__(256) void gemm_mfma_splitk(
    int M, int N, int K,
    const unsigned short* __restrict__ A0, const unsigned short* __restrict__ A1, int lda,
    const unsigned short* __restrict__ B0, const unsigned short* __restrict__ B1, int ldb,
    float* __restrict__ part, int ldc)
{
    __shared__ unsigned short As[128 * 32];
    __shared__ unsigned short Bs[128 * 32];
    const int z = blockIdx.z;
    const int dir = z / NSPLIT, sp = z % NSPLIT;
    const unsigned short* A = dir ? A1 : A0;
    const unsigned short* B = dir ? B1 : B0;
    float* Cp = part + (size_t)z * M * ldc;
    const int kbeg = sp * (K / NSPLIT);
    const int kend = kbeg + (K / NSPLIT);
    const int tid  = threadIdx.x;
    const int wave = tid >> 6;
    const int lane = tid & 63;
    const int bm = blockIdx.y * 128;
    const int bn = blockIdx.x * 128;

    const int strow = lane & 15;
    const int stkc  = lane >> 4;
    const int wr = wave >> 1, wc = wave & 1;
    const int frow = lane & 15;
    const int fkc  = lane >> 4;

    floatx4 acc[4][4];
    #pragma unroll
    for (int i = 0; i < 4; ++i)
        #pragma unroll
        for (int j = 0; j < 4; ++j)
            acc[i][j] = (floatx4){0.f, 0.f, 0.f, 0.f};

    for (int k0 = kbeg; k0 < kend; k0 += 32) {
        __syncthreads();
        #pragma unroll
        for (int q = 0; q < 2; ++q) {
            int g = wave * 2 + q;
            GLOAD_LDS16(A + (size_t)(bm + g * 16 + strow) * lda + k0 + stkc * 8,
                        As + g * 512);
        }
        #pragma unroll
        for (int q = 0; q < 2; ++q) {
            int g = wave * 2 + q;
            GLOAD_LDS16(B + (size_t)(bn + g * 16 + strow) * ldb + k0 + stkc * 8,
                        Bs + g * 512);
        }
        __syncthreads();

        bf16x8 af[4], bfr[4];
        #pragma unroll
        for (int i = 0; i < 4; ++i)
            af[i] = *(const bf16x8*)(As + (wr * 4 + i) * 512 + fkc * 128 + frow * 8);
        #pragma unroll
        for (int j = 0; j < 4; ++j)
            bfr[j] = *(const bf16x8*)(Bs + (wc * 4 + j) * 512 + fkc * 128 + frow * 8);
        #pragma unroll
        for (int i = 0; i < 4; ++i)
            #pragma unroll
            for (int j = 0; j < 4; ++j)
                acc[i][j] = __builtin_amdgcn_mfma_f32_16x16x32_bf16(
                    af[i], bfr[j], acc[i][j], 0, 0, 0);
    }

    const int orow0 = bm + wr * 64 + (lane >> 4) * 4;
    const int ocol0 = bn + wc * 64 + (lane & 15);
    #pragma unroll
    for (int j = 0; j < 4; ++j) {
        const int col = ocol0 + j * 16;
        #pragma unroll
        for (int i = 0; i < 4; ++i)
            #pragma unroll
            for (int r = 0; r < 4; ++r)
                Cp[(size_t)(orow0 + i * 16 + r) * ldc + col] = acc[i][j][r];
    }
}

// ---------------------------------------------------------------------------
// xproj split-K MFMA: tile 128(m) x 64(n), K slice 256. blockIdx.y=dir*4+sp.
// ---------------------------------------------------------------------------
__global__ __launch_bounds__(256) void xproj_splitk_kernel(
    const unsigned short* __restrict__ A_f, const unsigned short* __restrict__ A_b,
    const unsigned short* __restrict__ Wf,  const unsigned short* __restrict__ Wb,
    float* __restrict__ part)
{
    __shared__ unsigned short As[128 * 32];
    __shared__ unsigned short Bs[64 * 32];
    const int tid = threadIdx.x, wave = tid >> 6, lane = tid & 63;
    const int bm = blockIdx.x * 128;
    const int dir = blockIdx.y >> 2, sp = blockIdx.y & 3;
    const unsigned short* A = dir ? A_b : A_f;
    const unsigned short* W = dir ? Wb  : Wf;
    float* Cp = part + (size_t)blockIdx.y * MM * 64;
    const int kbeg = sp * 256, kend = kbeg + 256;

    const int strow = lane & 15;
    const int stkc  = lane >> 4;
    const int frow = lane & 15;
    const int fkc  = lane >> 4;

    floatx4 acc[2][4];
    #pragma unroll
    for (int i = 0; i < 2; ++i)
        #pragma unroll
        for (int j = 0; j < 4; ++j)
            acc[i][j] = (floatx4){0.f, 0.f, 0.f, 0.f};

    for (int k0 = kbeg; k0 < kend; k0 += 32) {
        __syncthreads();
        #pragma unroll
        for (int q = 0; q < 2; ++q) {
            int g = wave * 2 + q;
            GLOAD_LDS16(A + (size_t)(bm + g * 16 + strow) * DINNER + k0 + stkc * 8,
                        As + g * 512);
        }
        GLOAD_LDS16(W + (size_t)(wave * 16 + strow) * DINNER + k0 + stkc * 8,
                    Bs + wave * 512);
        __syncthreads();

        bf16x8 af[2], bfr[4];
        #pragma unroll
        for (int i = 0; i < 2; ++i)
            af[i] = *(const bf16x8*)(As + (wave * 2 + i) * 512 + fkc * 128 + frow * 8);
        #pragma unroll
        for (int j = 0; j < 4; ++j)
            bfr[j] = *(const bf16x8*)(Bs + j * 512 + fkc * 128 + frow * 8);
        #pragma unroll
        for (int i = 0; i < 2; ++i)
            #pragma unroll
            for (int j = 0; j < 4; ++j)
                acc[i][j] = __builtin_amdgcn_mfma_f32_16x16x32_bf16(
                    af[i], bfr[j], acc[i][j], 0, 0, 0);
    }

    const int orow0 = bm + wave * 32 + (lane >> 4) * 4;
    #pragma unroll
    for (int j = 0; j < 4; ++j) {
        const int col = (lane & 15) + j * 16;
        #pragma unroll
        for (int i = 0; i < 2; ++i)
            #pragma unroll
            for (int r = 0; r < 4; ++r)
                Cp[(size_t)(orow0 + i * 16 + r) * 64 + col] = acc[i][j][r];
    }
}

// ---------------------------------------------------------------------------
// xproj reduce: cols 0..31 -> dbc[m][32] (dt rows); cols 32..63 -> bct[m][32].
// ---------------------------------------------------------------------------
__global__ __launch_bounds__(256) void xproj_reduce_kernel(
    const float* __restrict__ part,
    float* __restrict__ dbc_f, float* __restrict__ dbc_b,
    float* __restrict__ bct_f, float* __restrict__ bct_b)
{
    const int dir = blockIdx.y;
    const int i = (blockIdx.x * 256 + threadIdx.x) * 4;
    const float* p = part + (size_t)dir * 4 * (MM * 64);
    float4 a = *(const float4*)(p + i);
    #pragma unroll
    for (int s = 1; s < 4; ++s) {
        float4 t = *(const float4*)(p + (size_t)s * (MM * 64) + i);
        a.x += t.x; a.y += t.y; a.z += t.z; a.w += t.w;
    }
    const int m = i >> 6, c = i & 63;
    if (c < 32) {
        float* dbc = dir ? dbc_b : dbc_f;
        *(float4*)(dbc + (size_t)m * 32 + c) = a;
    } else {
        float* bct = dir ? bct_b : bct_f;
        *(float4*)(bct + (size_t)m * 32 + (c - 32)) = a;
    }
}

// ---------------------------------------------------------------------------
// Batched fp32 GEMM w/ softplus + row bias (dt-proj), bf16 output.
// ---------------------------------------------------------------------------
__global__ __launch_bounds__(256) void dtproj_batch_kernel(
    int M, int N, int K,
    const float* __restrict__ A0, const float* __restrict__ A1, int lda,
    const float* __restrict__ B0, const float* __restrict__ B1, int ldb,
    const float* __restrict__ bias0, const float* __restrict__ bias1,
    unsigned short* __restrict__ C0, unsigned short* __restrict__ C1, int ldc)
{
    __shared__ float As[16][64];
    __shared__ float Bs[16][64];
    const int z = blockIdx.z;
    const float* A = z ? A1 : A0;
    const float* B = z ? B1 : B0;
    const float* biasR = z ? bias1 : bias0;
    unsigned short* C = z ? C1 : C0;
    const int tid = threadIdx.x;
    const int tx = tid & 15, ty = tid >> 4;
    const int bm = blockIdx.y * 64, bn = blockIdx.x * 64;
    const int lm = tid & 63;
    const int lk = (tid >> 6) * 4;
    const float* Arow = A + (size_t)(bm + lm) * lda + lk;
    const float* Brow = B + (size_t)(bn + lm) * ldb + lk;
    float acc[4][4] = {};
    for (int k0 = 0; k0 < K; k0 += 16) {
        float4 av = *(const float4*)(Arow + k0);
        float4 bv = *(const float4*)(Brow + k0);
        __syncthreads();
        As[lk+0][lm] = av.x; As[lk+1][lm] = av.y; As[lk+2][lm] = av.z; As[lk+3][lm] = av.w;
        Bs[lk+0][lm] = bv.x; Bs[lk+1][lm] = bv.y; Bs[lk+2][lm] = bv.z; Bs[lk+3][lm] = bv.w;
        __syncthreads();
        #pragma unroll
        for (int k = 0; k < 16; ++k) {
            float4 a = *(const float4*)(&As[k][ty*4]);
            float4 b = *(const float4*)(&Bs[k][tx*4]);
            float ar[4] = {a.x,a.y,a.z,a.w};
            float br[4] = {b.x,b.y,b.z,b.w};
            #pragma unroll
            for (int i = 0; i < 4; ++i)
                #pragma unroll
                for (int j = 0; j < 4; ++j)
                    acc[i][j] = fmaf(ar[i], br[j], acc[i][j]);
        }
    }
    const int row0 = bm + ty*4, col0 = bn + tx*4;
    #pragma unroll
    for (int i = 0; i < 4; ++i) {
        float br = biasR[row0 + i];
        ushort4v o;
        #pragma unroll
        for (int j = 0; j < 4; ++j) {
            float t = acc[i][j] + br;
            o[j] = f2bf(fmaxf(t, 0.f) + log1pf(__expf(-fabsf(t))));
        }
        *(ushort4v*)(C + (size_t)(row0 + i) * ldc + col0) = o;
    }
}

// ---------------------------------------------------------------------------
// Segmented casts: 5 pre-GEMM arrays -> one contiguous bf16 block.
// ---------------------------------------------------------------------------
__global__ __launch_bounds__(256) void cast_pre_kernel(
    const float* __restrict__ x, const float* __restrict__ w0,
    const float* __restrict__ w1, const float* __restrict__ xp0,
    const float* __restrict__ xp1, unsigned short* __restrict__ dst)
{
    int i = (blockIdx.x * 256 + threadIdx.x) * 8;
    const float* src; int off;
    if      (i < 1048576) { src = x;   off = 0; }
    else if (i < 2097152) { src = w0;  off = 1048576; }
    else if (i < 3145728) { src = w1;  off = 2097152; }
    else if (i < 3211264) { src = xp0; off = 3145728; }
    else                  { src = xp1; off = 3211264; }
    float4 a = *(const float4*)(src + i - off);
    float4 b = *(const float4*)(src + i - off + 4);
    ushort8v o;
    o[0] = f2bf(a.x); o[1] = f2bf(a.y); o[2] = f2bf(a.z); o[3] = f2bf(a.w);
    o[4] = f2bf(b.x); o[5] = f2bf(b.y); o[6] = f2bf(b.z); o[7] = f2bf(b.w);
    *(ushort8v*)(dst + i) = o;
}

// Segments: outW_f(524288) outW_b(524288) W1(1048576) W2(1048576)
__global__ __launch_bounds__(256) void cast_post_kernel(
    const float* __restrict__ w0, const float* __restrict__ w1,
    const float* __restrict__ w2, const float* __restrict__ w3,
    unsigned short* __restrict__ dst)
{
    int i = (blockIdx.x * 256 + threadIdx.x) * 8;
    const float* src; int off;
    if      (i < 524288)  { src = w0; off = 0; }
    else if (i < 1048576) { src = w1; off = 524288; }
    else if (i < 2097152) { src = w2; off = 1048576; }
    else                  { src = w3; off = 2097152; }
    float4 a = *(const float4*)(src + i - off);
    float4 b = *(const float4*)(src + i - off + 4);
    ushort8v o;
    o[0] = f2bf(a.x); o[1] = f2bf(a.y); o[2] = f2bf(a.z); o[3] = f2bf(a.w);
    o[4] = f2bf(b.x); o[5] = f2bf(b.y); o[6] = f2bf(b.z); o[7] = f2bf(b.w);
    *(ushort8v*)(dst + i) = o;
}

// ---------------------------------------------------------------------------
// Fused depthwise conv + bias + silu + transpose: writes xm[m][d] (bf16) and
// xmT[d][m] (bf16) in one pass. 32x32 tile, blockIdx.z = dir.
// ---------------------------------------------------------------------------
__global__ __launch_bounds__(256) void conv_silu_tr_kernel(
    const float* __restrict__ x_f, const float* __restrict__ x_b,
    const float* __restrict__ Wf,  const float* __restrict__ Wb,
    const float* __restrict__ cbf, const float* __restrict__ cbb,
    unsigned short* __restrict__ of,  unsigned short* __restrict__ ob,
    unsigned short* __restrict__ otf, unsigned short* __restrict__ otb)
{
    __shared__ unsigned short t[32][34];
    const int dir = blockIdx.z;
    const float* xo = dir ? x_b : x_f;
    const float* convW = dir ? Wb : Wf;
    const float* convb = dir ? cbb : cbf;
    unsigned short* xm  = dir ? ob : of;
    unsigned short* xmT = dir ? otb : otf;
    const int m0 = blockIdx.x * 32, d0 = blockIdx.y * 32;
    const int tx = threadIdx.x & 31, ty = threadIdx.x >> 5;
    const int d = d0 + tx;
    float4 wv = *(const float4*)(convW + d * 4);
    float w[4] = {wv.x, wv.y, wv.z, wv.w};
    const float cb = convb[d];
    #pragma unroll
    for (int rr = 0; rr < 32; rr += 8) {
        int m = m0 + ty + rr;
        int b = m >> 10, l = m & (SEQ - 1);
        float acc = cb;
        #pragma unroll
        for (int j = 0; j < 4; ++j) {
            int p = dir ? (l + 3 - j) : (l - 3 + j);
            if (p >= 0 && p < SEQ)
                acc = fmaf(xo[(size_t)(b * SEQ + p) * DINNER + d], w[j], acc);
        }
        float sig = 1.f / (1.f + __expf(-acc));
        unsigned short v = f2bf(acc * sig);
        xm[(size_t)m * DINNER + d] = v;
        t[ty + rr][tx] = v;
    }
    __syncthreads();
    #pragma unroll
    for (int rr = 0; rr < 32; rr += 8)
        xmT[(size_t)(d0 + ty + rr) * MM + m0 + tx] = t[tx][ty + rr];
}

// ---------------------------------------------------------------------------
// Scan pass 1: local scan from zero state. Emits y0 (bf16, incl. D*x),
// running cumdl (fp32, s==0 lane), chunk P = exp(A*sum dl), H = end state.
// ---------------------------------------------------------------------------
template<int DIR>
__device__ __forceinline__ void pass1_body(
    const unsigned short* __restrict__ deltaT, const unsigned short* __restrict__ xmT,
    const float* __restrict__ bct, const float* __restrict__ Alog,
    const float* __restrict__ Dv,
    unsigned short* __restrict__ y0T, float* __restrict__ cumT,
    float* __restrict__ Pout, float* __restrict__ Hout)
{
    const int tid = threadIdx.x;
    const int s = tid & 15;
    const int dloc = tid >> 4;
    const int d = blockIdx.x * 16 + dloc;
    const int b = blockIdx.y / NCHUNK;
    const int c = blockIdx.y % NCHUNK;

    const float A  = -__expf(Alog[d * DSTATE + s]);
    const float Dp = Dv[d];
    const unsigned short* dRow = deltaT + (size_t)d * MM + b * SEQ;
    const unsigned short* xRow = xmT + (size_t)d * MM + b * SEQ;
    const float* bcRow = bct + (size_t)(b * SEQ) * 32 + s;
    unsigned short* yRow = y0T + (size_t)d * MM + b * SEQ;
    float* uRow = cumT + (size_t)d * MM + b * SEQ;

    float h = 0.f, sdl = 0.f;
    const int segBase = DIR ? (SEQ - CHUNK - c * CHUNK) : (c * CHUNK);
    for (int ii = 0; ii < CHUNK; ii += 8) {
        const int off = DIR ? (segBase + (CHUNK - 8) - ii) : (segBase + ii);
        ushort8v dl8 = *(const ushort8v*)(dRow + off);
        ushort8v x8  = *(const ushort8v*)(xRow + off);
        const float* bp = bcRow + (size_t)off * 32;
        float Bv[8], Cv[8];
        #pragma unroll
        for (int u = 0; u < 8; ++u) {
            Bv[u] = bp[u * 32];
            Cv[u] = bp[u * 32 + 16];
        }
        float yv[8], cu[8];
        #pragma unroll
        for (int u = 0; u < 8; ++u) {
            const int t = DIR ? (7 - u) : u;
            float dlv = bf2f(dl8[t]);
            float xv  = bf2f(x8[t]);
            float dA = __expf(dlv * A);
            sdl += dlv;
            h = fmaf(dA, h, dlv * Bv[t] * xv);
            float part = rowsum16(h * Cv[t]);
            yv[t] = fmaf(xv, Dp, part);
            cu[t] = sdl;
        }
        if (s == 0) {
            ushort8v y8;
            #pragma unroll
            for (int u = 0; u < 8; ++u) y8[u] = f2bf(yv[u]);
            *(ushort8v*)(yRow + off) = y8;
            *(float4*)(uRow + off)     = (float4){cu[0], cu[1], cu[2], cu[3]};
            *(float4*)(uRow + off + 4) = (float4){cu[4], cu[5], cu[6], cu[7]};
        }
    }
    const int g = ((DIR * BATCH + b) * DINNER + d) * DSTATE + s;
    Pout[(size_t)c * GTOT + g] = __expf(sdl * A);
    Hout[(size_t)c * GTOT + g] = h;
}

__global__ __launch_bounds__(256) void scan_pass1_kernel(
    const unsigned short* __restrict__ dT_f, const unsigned short* __restrict__ dT_b,
    const unsigned short* __restrict__ xT_f, const unsigned short* __restrict__ xT_b,
    const float* __restrict__ bct_f, const float* __restrict__ bct_b,
    const float* __restrict__ Alog_f, const float* __restrict__ Alog_b,
    const float* __restrict__ D_f, const float* __restrict__ D_b,
    unsigned short* __restrict__ y0T_f, unsigned short* __restrict__ y0T_b,
    float* __restrict__ cumT_f, float* __restrict__ cumT_b,
    float* __restrict__ Pout, float* __restrict__ Hout)
{
    if (blockIdx.z == 0)
        pass1_body<0>(dT_f, xT_f, bct_f, Alog_f, D_f, y0T_f, cumT_f, Pout, Hout);
    else
        pass1_body<1>(dT_b, xT_b, bct_b, Alog_b, D_b, y0T_b, cumT_b, Pout, Hout);
}

// ---------------------------------------------------------------------------
// Phase 2: sequential combine over chunks.
// ---------------------------------------------------------------------------
__global__ __launch_bounds__(256) void scan_carry_kernel(
    const float* __restrict__ P, const float* __restrict__ H,
    float* __restrict__ carry)
{
    const int g = blockIdx.x * 256 + threadIdx.x;
    float h = 0.f;
    #pragma unroll
    for (int c = 0; c < NCHUNK; ++c) {
        carry[(size_t)c * GTOT + g] = h;
        h = fmaf(P[(size_t)c * GTOT + g], h, H[(size_t)c * GTOT + g]);
    }
}

// ---------------------------------------------------------------------------
// Correction pass (fully parallel):
//   y[m,d] = y0[m,d] + sum_s C[m,s]*carry[d,s]*exp(A[d,s]*cumdl[m,d])
// then *= silu(z), transpose -> ybf[m][d]. blockIdx.z = dir.
// ---------------------------------------------------------------------------
__global__ __launch_bounds__(256) void scan_correct_kernel(
    const unsigned short* __restrict__ y0T_f, const unsigned short* __restrict__ y0T_b,
    const float* __restrict__ cumT_f, const float* __restrict__ cumT_b,
    const float* __restrict__ bct_f, const float* __restrict__ bct_b,
    const float* __restrict__ Alog_f, const float* __restrict__ Alog_b,
    const float* __restrict__ carry,
    const float* __restrict__ z_f, const float* __restrict__ z_b,
    unsigned short* __restrict__ ybf_f, unsigned short* __restrict__ ybf_b)
{
    __shared__ float Cs[16][33];   // C[s][m-local]
    __shared__ float Asm[32][16];  // A per (d-local, s)
    __shared__ float Cy[32][16];   // carry per (d-local, s)
    __shared__ float t[32][33];    // transpose buffer

    const int dir = blockIdx.z;
    const unsigned short* y0T = dir ? y0T_b : y0T_f;
    const float* cumT = dir ? cumT_b : cumT_f;
    const float* bct  = dir ? bct_b  : bct_f;
    const float* Alog = dir ? Alog_b : Alog_f;
    const float* zon  = dir ? z_b    : z_f;
    unsigned short* ybf = dir ? ybf_b : ybf_f;

    const int m0 = blockIdx.x * 32, d0 = blockIdx.y * 32;
    const int b = m0 >> 10;
    const int l0 = m0 & (SEQ - 1);
    const int c = dir ? ((SEQ - 1 - l0) >> 6) : (l0 >> 6);

    for (int idx = threadIdx.x; idx < 512; idx += 256) {
        int s1 = idx & 15, ml = idx >> 4;
        Cs[s1][ml] = bct[(size_t)(m0 + ml) * 32 + 16 + s1];
        int dl2 = idx >> 4, s2 = idx & 15;
        Asm[dl2][s2] = -__expf(Alog[(d0 + dl2) * DSTATE + s2]);
        Cy[dl2][s2] = carry[(size_t)c * GTOT
            + ((size_t)(dir * BATCH + b) * DINNER + d0 + dl2) * DSTATE + s2];
    }
    __syncthreads();

    const int tx = threadIdx.x & 31, ty = threadIdx.x >> 5;
    #pragma unroll
    for (int rr = 0; rr < 32; rr += 8) {
        const int dloc = ty + rr;
        const size_t base = (size_t)(d0 + dloc) * MM + m0 + tx;
        float u  = cumT[base];
        float y0 = bf2f(y0T[base]);
        float corr = 0.f;
        #pragma unroll
        for (int s = 0; s < DSTATE; ++s)
            corr = fmaf(Cs[s][tx] * Cy[dloc][s], __expf(Asm[dloc][s] * u), corr);
        t[dloc][tx] = y0 + corr;
    }
    __syncthreads();
    #pragma unroll
    for (int rr = 0; rr < 32; rr += 8) {
        int m = m0 + ty + rr, d = d0 + tx;
        float z = zon[(size_t)m * DINNER + d];
        float sig = 1.f / (1.f + __expf(-z));
        ybf[(size_t)m * DINNER + d] = f2bf(t[tx][ty + rr] * (z * sig));
    }
}

// ---------------------------------------------------------------------------
// Fused split-K reduce + dual LN -> bf16.
// ---------------------------------------------------------------------------
__global__ __launch_bounds__(256) void ln_combine_fused_kernel(
    const float* __restrict__ xf, const float* __restrict__ part,
    const float* __restrict__ g1, const float* __restrict__ b1,
    const float* __restrict__ g2, const float* __restrict__ b2,
    unsigned short* __restrict__ out)
{
    const int m = blockIdx.x;
    const int tid = threadIdx.x;
    const float* xr = xf + (size_t)m * DMODEL;
    const float* p0 = part + (size_t)m * DMODEL;
    const float* p1 = p0 + (size_t)MM * DMODEL;
    const float* p2 = p1 + (size_t)MM * DMODEL;
    const float* p3 = p2 + (size_t)MM * DMODEL;
    float v1a = xr[tid]       + p0[tid]       + p1[tid];
    float v1b = xr[tid + 256] + p0[tid + 256] + p1[tid + 256];
    float v2a = xr[tid]       + p2[tid]       + p3[tid];
    float v2b = xr[tid + 256] + p2[tid + 256] + p3[tid + 256];
    float s1 = v1a + v1b, q1 = v1a*v1a + v1b*v1b;
    float s2 = v2a + v2b, q2 = v2a*v2a + v2b*v2b;
    #pragma unroll
    for (int off = 32; off; off >>= 1) {
        s1 += __shfl_xor(s1, off); q1 += __shfl_xor(q1, off);
        s2 += __shfl_xor(s2, off); q2 += __shfl_xor(q2, off);
    }
    __shared__ float sm[4][4];
    const int w = tid >> 6;
    if ((tid & 63) == 0) { sm[w][0] = s1; sm[w][1] = q1; sm[w][2] = s2; sm[w][3] = q2; }
    __syncthreads();
    s1 = sm[0][0] + sm[1][0] + sm[2][0] + sm[3][0];
    q1 = sm[0][1] + sm[1][1] + sm[2][1] + sm[3][1];
    s2 = sm[0][2] + sm[1][2] + sm[2][2] + sm[3][2];
    q2 = sm[0][3] + sm[1][3] + sm[2][3] + sm[3][3];
    const float inv = 1.f / DMODEL;
    float mu1 = s1 * inv, mu2 = s2 * inv;
    float rs1 = rsqrtf(q1 * inv - mu1 * mu1 + 1e-5f);
    float rs2 = rsqrtf(q2 * inv - mu2 * mu2 + 1e-5f);
    unsigned short* orow = out + (size_t)m * DMODEL;
    orow[tid]       = f2bf((v1a - mu1) * rs1 * g1[tid]       + b1[tid]
                         + (v2a - mu2) * rs2 * g2[tid]       + b2[tid]);
    orow[tid + 256] = f2bf((v1b - mu1) * rs1 * g1[tid + 256] + b1[tid + 256]
                         + (v2b - mu2) * rs2 * g2[tid + 256] + b2[tid + 256]);
}

// ---------------------------------------------------------------------------
// Fused FF2 split-K4 reduce + bias + LN(2*ff).
// ---------------------------------------------------------------------------
__global__ __launch_bounds__(256) void ln_final_fused_kernel(
    const float* __restrict__ part, const float* __restrict__ bias,
    const float* __restrict__ g, const float* __restrict__ b,
    float* __restrict__ out)
{
    const int m = blockIdx.x;
    const int tid = threadIdx.x;
    const size_t stride = (size_t)MM * DMODEL;
    const float* p = part + (size_t)m * DMODEL;
    float fa = bias[tid]       + p[tid]       + p[stride + tid]
             + p[2*stride + tid]       + p[3*stride + tid];
    float fb = bias[tid + 256] + p[tid + 256] + p[stride + tid + 256]
             + p[2*stride + tid + 256] + p[3*stride + tid + 256];
    float va = 2.f * fa, vb = 2.f * fb;
    float s = va + vb, q = va*va + vb*vb;
    #pragma unroll
    for (int off = 32; off; off >>= 1) {
        s += __shfl_xor(s, off); q += __shfl_xor(q, off);
    }
    __shared__ float sm[4][2];
    const int w = tid >> 6;
    if ((tid & 63) == 0) { sm[w][0] = s; sm[w][1] = q; }
    __syncthreads();
    s = sm[0][0] + sm[1][0] + sm[2][0] + sm[3][0];
    q = sm[0][1] + sm[1][1] + sm[2][1] + sm[3][1];
    const float inv = 1.f / DMODEL;
    float mu = s * inv;
    float rs = rsqrtf(q * inv - mu * mu + 1e-5f);
    float* orow = out + (size_t)m * DMODEL;
    orow[tid]       = (va - mu) * rs * g[tid]       + b[tid];
    orow[tid + 256] = (vb - mu) * rs * g[tid + 256] + b[tid + 256];
}

// ---------------------------------------------------------------------------
extern "C" void kernel_launch(void* const* d_in, const int* in_sizes, int n_in,
                              void* d_out, int out_size, void* d_ws, size_t ws_size,
                              hipStream_t stream)
{
    const float* x         = (const float*)d_in[0];
    const float* fm_in_W   = (const float*)d_in[1];
    const float* fm_conv_W = (const float*)d_in[2];
    const float* fm_conv_b = (const float*)d_in[3];
    const float* fm_xproj_W= (const float*)d_in[4];
    const float* fm_dt_W   = (const float*)d_in[5];
    const float* fm_dt_b   = (const float*)d_in[6];
    const float* fm_A_log  = (const float*)d_in[7];
    const float* fm_D      = (const float*)d_in[8];
    const float* fm_out_W  = (const float*)d_in[9];
    const float* bm_in_W   = (const float*)d_in[10];
    const float* bm_conv_W = (const float*)d_in[11];
    const float* bm_conv_b = (const float*)d_in[12];
    const float* bm_xproj_W= (const float*)d_in[13];
    const float* bm_dt_W   = (const float*)d_in[14];
    const float* bm_dt_b   = (const float*)d_in[15];
    const float* bm_A_log  = (const float*)d_in[16];
    const float* bm_D      = (const float*)d_in[17];
    const float* bm_out_W  = (const float*)d_in[18];
    const float* ln1_g     = (const float*)d_in[19];
    const float* ln1_b     = (const float*)d_in[20];
    const float* ln2_g     = (const float*)d_in[21];
    const float* ln2_b     = (const float*)d_in[22];
    const float* ln3_g     = (const float*)d_in[23];
    const float* ln3_b     = (const float*)d_in[24];
    const float* ff_W1     = (const float*)d_in[25];
    const float* ff_b1     = (const float*)d_in[26];
    const float* ff_W2     = (const float*)d_in[27];
    const float* ff_b2     = (const float*)d_in[28];
    float* out = (float*)d_out;

    // ---- Workspace layout (floats; total 23,330,816 fl = 93.3 MB) ----
    float* ws = (float*)d_ws;
    size_t o = 0;
    float* xonly_f = ws + o; o += (size_t)MM * DINNER;     // 2,097,152
    float* xonly_b = ws + o; o += (size_t)MM * DINNER;
    float* zonly_f = ws + o; o += (size_t)MM * DINNER;
    float* zonly_b = ws + o; o += (size_t)MM * DINNER;
    unsigned short* xm_bf_f = (unsigned short*)(ws + o); o += (size_t)MM * DINNER / 2;
    unsigned short* xm_bf_b = (unsigned short*)(ws + o); o += (size_t)MM * DINNER / 2;
    unsigned short* xmT_f   = (unsigned short*)(ws + o); o += (size_t)MM * DINNER / 2;
    unsigned short* xmT_b   = (unsigned short*)(ws + o); o += (size_t)MM * DINNER / 2;
    unsigned short* deltaT_f= (unsigned short*)(ws + o); o += (size_t)MM * DINNER / 2;
    unsigned short* deltaT_b= (unsigned short*)(ws + o); o += (size_t)MM * DINNER / 2;
    float* dbc_f    = ws + o; o += (size_t)MM * 32;        // 65,536
    float* dbc_b    = ws + o; o += (size_t)MM * 32;
    float* bct_f    = ws + o; o += (size_t)MM * 32;
    float* bct_b    = ws + o; o += (size_t)MM * 32;
    unsigned short* y0T_f = (unsigned short*)(ws + o); o += (size_t)MM * DINNER / 2;
    unsigned short* y0T_b = (unsigned short*)(ws + o); o += (size_t)MM * DINNER / 2;
    float* scanP    = ws + o; o += (size_t)NCHUNK * (GTOT / 16) * 16;  // 1,048,576
    float* scanH    = ws + o; o += (size_t)NCHUNK * (GTOT / 16) * 16;
    float* scanCy   = ws + o; o += (size_t)NCHUNK * (GTOT / 16) * 16;
    float* gpart    = ws + o; o += (size_t)4 * MM * DMODEL;            // 4,194,304

    // ---- Overlays ----
    float* cumT_f = xonly_f;   // xonly dead after conv
    float* cumT_b = xonly_b;
    unsigned short* x_bf       = (unsigned short*)scanP;   // dead until pass1
    unsigned short* fm_inW_bf  = x_bf + 1048576;
    unsigned short* bm_inW_bf  = fm_inW_bf + 1048576;
    unsigned short* fm_xpW_bf  = bm_inW_bf + 1048576;
    unsigned short* bm_xpW_bf  = fm_xpW_bf + 65536;
    unsigned short* ybf_f = (unsigned short*)scanP;        // P/H dead after carry
    unsigned short* ybf_b = (unsigned short*)scanH;
    unsigned short* fm_outW_bf = (unsigned short*)zonly_f; // zonly dead after correct
    unsigned short* bm_outW_bf = fm_outW_bf + 524288;
    unsigned short* W1_bf      = bm_outW_bf + 524288;
    unsigned short* W2_bf      = W1_bf + 1048576;
    unsigned short* outsum_bf  = (unsigned short*)xonly_b; // cumT_b dead after correct
    unsigned short* h_bf = (unsigned short*)deltaT_f;      // deltaT dead after pass1

    // ---- 0. pre-GEMM casts ----
    cast_pre_kernel<<<3276800 / 2048, 256, 0, stream>>>(
        x, fm_in_W, bm_in_W, fm_xproj_W, bm_xproj_W, x_bf);

    // ---- 1. in-proj GEMMs, split x/z outputs, both dirs (512 blocks) ----
    gemm_inproj_kernel<<<dim3(2048/128, MM/128, 2), 256, 0, stream>>>(
        x_bf, fm_inW_bf, bm_inW_bf, xonly_f, zonly_f, xonly_b, zonly_b);

    // ---- 2. fused conv + silu + transpose -> xm[m][d], xmT[d][m] ----
    conv_silu_tr_kernel<<<dim3(MM/32, DINNER/32, 2), 256, 0, stream>>>(
        xonly_f, xonly_b, fm_conv_W, bm_conv_W, fm_conv_b, bm_conv_b,
        xm_bf_f, xm_bf_b, xmT_f, xmT_b);

    // ---- 3. x-proj: split-K x4, both dirs + reduce -> dbc[m][32], bct[m][32] ----
    xproj_splitk_kernel<<<dim3(MM/128, 8), 256, 0, stream>>>(
        xm_bf_f, xm_bf_b, fm_xpW_bf, bm_xpW_bf, gpart);
    xproj_reduce_kernel<<<dim3((MM*64)/1024, 2), 256, 0, stream>>>(
        gpart, dbc_f, dbc_b, bct_f, bct_b);

    // ---- 4. dt-proj, both dirs -> deltaT bf16 [d][m], softplus ----
    dtproj_batch_kernel<<<dim3(MM/64, DINNER/64, 2), 256, 0, stream>>>(
        DINNER, MM, DTRANK, fm_dt_W, bm_dt_W, DTRANK, dbc_f, dbc_b, 32,
        fm_dt_b, bm_dt_b, deltaT_f, deltaT_b, MM);

    // ---- 5. scan: pass1 + carry + parallel correction ----
    scan_pass1_kernel<<<dim3(DINNER/16, BATCH*NCHUNK, 2), 256, 0, stream>>>(
        deltaT_f, deltaT_b, xmT_f, xmT_b, bct_f, bct_b,
        fm_A_log, bm_A_log, fm_D, bm_D,
        y0T_f, y0T_b, cumT_f, cumT_b, scanP, scanH);
    scan_carry_kernel<<<GTOT/256, 256, 0, stream>>>(scanP, scanH, scanCy);
    scan_correct_kernel<<<dim3(MM/32, DINNER/32, 2), 256, 0, stream>>>(
        y0T_f, y0T_b, cumT_f, cumT_b, bct_f, bct_b, fm_A_log, bm_A_log,
        scanCy, zonly_f, zonly_b, ybf_f, ybf_b);

    // ---- 6. post weight casts (zonly dead) ----
    cast_post_kernel<<<3145728 / 2048, 256, 0, stream>>>(
        fm_out_W, bm_out_W, ff_W1, ff_W2, fm_outW_bf);

    // ---- 7. out-proj: dirs x splitK2 (256 blocks) -> gpart ----
    gemm_mfma_splitk<2><<<dim3(DMODEL/128, MM/128, 4), 256, 0, stream>>>(
        MM, DMODEL, DINNER, ybf_f, ybf_b, DINNER, fm_outW_bf, bm_outW_bf, DINNER,
        gpart, DMODEL);

    // ---- 8. fused reduce + dual LN -> bf16 outsum ----
    ln_combine_fused_kernel<<<MM, 256, 0, stream>>>(
        x, gpart, ln1_g, ln1_b, ln2_g, ln2_b, outsum_bf);

    // ---- 9. FF1 (256 blocks) ----
    gemm_mfma_batch<1,1><<<dim3(DFF/128, MM/128, 1), 256, 0, stream>>>(
        MM, DFF, DMODEL, outsum_bf, outsum_bf, DMODEL, W1_bf, W1_bf, DMODEL,
        ff_b1, h_bf, h_bf, DFF);

    // ---- 10. FF2: splitK4 (256 blocks) -> gpart ----
    gemm_mfma_splitk<4><<<dim3(DMODEL/128, MM/128, 4), 256, 0, stream>>>(
        MM, DMODEL, DFF, h_bf, h_bf, DFF, W2_bf, W2_bf, DFF, gpart, DMODEL);

    // ---- 11. fused reduce + bias + final LN(2*ff) ----
    ln_final_fused_kernel<<<MM, 256, 0, stream>>>(
        gpart, ff_b2, ln3_g, ln3_b, out);
}

// Round 11
// 305.543 us; speedup vs baseline: 4.7406x; 1.0829x over previous
//
#include <hip/hip_runtime.h>
#include <hip/hip_bf16.h>
#include <math.h>

// Problem constants
#define MM 2048        // B*W flattened rows
#define BATCH 2
#define SEQ 1024
#define DMODEL 512
#define DINNER 1024
#define DSTATE 16
#define DTRANK 32
#define DFF 2048

// Chunked-scan constants
#define NCHUNK 16
#define CHUNK 64
#define GTOT 65536          // 2 dirs * BATCH * DINNER * DSTATE

typedef short bf16x8 __attribute__((ext_vector_type(8)));
typedef float floatx4 __attribute__((ext_vector_type(4)));
typedef unsigned short ushort8v __attribute__((ext_vector_type(8)));
typedef unsigned short ushort4v __attribute__((ext_vector_type(4)));

__device__ __forceinline__ unsigned short f2bf(float f) {
    union { float f; unsigned u; } v; v.f = f;
    unsigned r = v.u + 0x7FFF + ((v.u >> 16) & 1);
    return (unsigned short)(r >> 16);
}
__device__ __forceinline__ float bf2f(unsigned short u) {
    union { unsigned u; float f; } v; v.u = ((unsigned)u) << 16; return v.f;
}

// Sum across each 4-lane quad via DPP quad_perm adds (VALU-only).
// After both steps every lane in the quad holds the quad total.
__device__ __forceinline__ float quadsum4(float x) {
    union { float f; int i; } a, b;
    a.f = x;
    b.i = __builtin_amdgcn_update_dpp(0, a.i, 0xB1, 0xF, 0xF, false); a.f += b.f; // [1,0,3,2]
    b.i = __builtin_amdgcn_update_dpp(0, a.i, 0x4E, 0xF, 0xF, false); a.f += b.f; // [2,3,0,1]
    return a.f;
}

#define GLOAD_LDS16(gp, lp) __builtin_amdgcn_global_load_lds( \
    (const __attribute__((address_space(1))) unsigned int*)(gp), \
    (__attribute__((address_space(3))) unsigned int*)(lp), 16, 0, 0)

// NOTE: single-buffered barrier-stage-barrier K-loops only. The LDS
// double-buffer variant (stage next tile after the barrier) RACES on this
// compiler (round-9 post-timing divergence): the waitcnt pass ties the
// LDS-DMA drain to aliasing ds_reads, which never alias the freshest DMA in
// a dbuf loop -> missing vmcnt wait across the loop backedge.
// BK=64 here stages BOTH 32-k halves before ONE barrier (disjoint LDS
// regions, all staged pre-barrier, all read post-barrier) — same safety as
// BK=32 single-buffer, half the barrier drains.

// ---------------------------------------------------------------------------
// Batched direct bf16 MFMA GEMM: C[z][M,N] = epi(A[z] @ B[z]^T + bias)
// 128x128 tile, BK=64 (2 staged halves per barrier). Conflict-free LDS.
// K % 64 == 0 required.
// ---------------------------------------------------------------------------
template<int EPI, int OUTBF16>
__global__ __launch_bounds__(256) void gemm_mfma_batch(
    int M, int N, int K,
    const unsigned short* __restrict__ A0, const unsigned short* __restrict__ A1, int lda,
    const unsigned short* __restrict__ B0, const unsigned short* __restrict__ B1, int ldb,
    const float* __restrict__ bias,
    void* __restrict__ C0, void* __restrict__ C1, int ldc)
{
    __shared__ unsigned short As[2][128 * 32];
    __shared__ unsigned short Bs[2][128 * 32];
    const int z = blockIdx.z;
    const unsigned short* A = z ? A1 : A0;
    const unsigned short* B = z ? B1 : B0;
    void* Cout = z ? C1 : C0;
    const int tid  = threadIdx.x;
    const int wave = tid >> 6;
    const int lane = tid & 63;
    const int bm = blockIdx.y * 128;
    const int bn = blockIdx.x * 128;

    const int strow = lane & 15;
    const int stkc  = lane >> 4;
    const int wr = wave >> 1, wc = wave & 1;
    const int frow = lane & 15;
    const int fkc  = lane >> 4;

    floatx4 acc[4][4];
    #pragma unroll
    for (int i = 0; i < 4; ++i)
        #pragma unroll
        for (int j = 0; j < 4; ++j)
            acc[i][j] = (floatx4){0.f, 0.f, 0.f, 0.f};

    for (int k0 = 0; k0 < K; k0 += 64) {
        __syncthreads();
        #pragma unroll
        for (int hh = 0; hh < 2; ++hh) {
            #pragma unroll
            for (int q = 0; q < 2; ++q) {
                int g = wave * 2 + q;
                GLOAD_LDS16(A + (size_t)(bm + g * 16 + strow) * lda + k0 + hh * 32 + stkc * 8,
                            As[hh] + g * 512);
            }
            #pragma unroll
            for (int q = 0; q < 2; ++q) {
                int g = wave * 2 + q;
                GLOAD_LDS16(B + (size_t)(bn + g * 16 + strow) * ldb + k0 + hh * 32 + stkc * 8,
                            Bs[hh] + g * 512);
            }
        }
        __syncthreads();

        #pragma unroll
        for (int hh = 0; hh < 2; ++hh) {
            bf16x8 af[4], bfr[4];
            #pragma unroll
            for (int i = 0; i < 4; ++i)
                af[i] = *(const bf16x8*)(As[hh] + (wr * 4 + i) * 512 + fkc * 128 + frow * 8);
            #pragma unroll
            for (int j = 0; j < 4; ++j)
                bfr[j] = *(const bf16x8*)(Bs[hh] + (wc * 4 + j) * 512 + fkc * 128 + frow * 8);
            #pragma unroll
            for (int i = 0; i < 4; ++i)
                #pragma unroll
                for (int j = 0; j < 4; ++j)
                    acc[i][j] = __builtin_amdgcn_mfma_f32_16x16x32_bf16(
                        af[i], bfr[j], acc[i][j], 0, 0, 0);
        }
    }

    const int orow0 = bm + wr * 64 + (lane >> 4) * 4;
    const int ocol0 = bn + wc * 64 + (lane & 15);
    #pragma unroll
    for (int j = 0; j < 4; ++j) {
        const int col = ocol0 + j * 16;
        const float bv = bias ? bias[col] : 0.f;
        #pragma unroll
        for (int i = 0; i < 4; ++i) {
            #pragma unroll
            for (int r = 0; r < 4; ++r) {
                int row = orow0 + i * 16 + r;
                float t = acc[i][j][r] + bv;
                if (EPI == 1) t = fmaxf(t, 0.f);
                if (OUTBF16)
                    ((unsigned short*)Cout)[(size_t)row * ldc + col] = f2bf(t);
                else
                    ((float*)Cout)[(size_t)row * ldc + col] = t;
            }
        }
    }
}

// ---------------------------------------------------------------------------
// In-proj GEMM (BK=64): C split into x-half / z-half buffers.
// A shared across dirs; blockIdx.z = dir. M=MM, N=2048, K=512.
// ---------------------------------------------------------------------------
__global__ __launch_bounds__(256) void gemm_inproj_kernel(
    const unsigned short* __restrict__ A,
    const unsigned short* __restrict__ B0, const unsigned short* __restrict__ B1,
    float* __restrict__ Cx0, float* __restrict__ Cz0,
    float* __restrict__ Cx1, float* __restrict__ Cz1)
{
    __shared__ unsigned short As[2][128 * 32];
    __shared__ unsigned short Bs[2][128 * 32];
    const int z = blockIdx.z;
    const unsigned short* B = z ? B1 : B0;
    const int tid  = threadIdx.x;
    const int wave = tid >> 6;
    const int lane = tid & 63;
    const int bm = blockIdx.y * 128;
    const int bn = blockIdx.x * 128;

    const int strow = lane & 15;
    const int stkc  = lane >> 4;
    const int wr = wave >> 1, wc = wave & 1;
    const int frow = lane & 15;
    const int fkc  = lane >> 4;

    floatx4 acc[4][4];
    #pragma unroll
    for (int i = 0; i < 4; ++i)
        #pragma unroll
        for (int j = 0; j < 4; ++j)
            acc[i][j] = (floatx4){0.f, 0.f, 0.f, 0.f};

    for (int k0 = 0; k0 < DMODEL; k0 += 64) {
        __syncthreads();
        #pragma unroll
        for (int hh = 0; hh < 2; ++hh) {
            #pragma unroll
            for (int q = 0; q < 2; ++q) {
                int g = wave * 2 + q;
                GLOAD_LDS16(A + (size_t)(bm + g * 16 + strow) * DMODEL + k0 + hh * 32 + stkc * 8,
                            As[hh] + g * 512);
            }
            #pragma unroll
            for (int q = 0; q < 2; ++q) {
                int g = wave * 2 + q;
                GLOAD_LDS16(B + (size_t)(bn + g * 16 + strow) * DMODEL + k0 + hh * 32 + stkc * 8,
                            Bs[hh] + g * 512);
            }
        }
        __syncthreads();

        #pragma unroll
        for (int hh = 0; hh < 2; ++hh) {
            bf16x8 af[4], bfr[4];
            #pragma unroll
            for (int i = 0; i < 4; ++i)
                af[i] = *(const bf16x8*)(As[hh] + (wr * 4 + i) * 512 + fkc * 128 + frow * 8);
            #pragma unroll
            for (int j = 0; j < 4; ++j)
                bfr[j] = *(const bf16x8*)(Bs[hh] + (wc * 4 + j) * 512 + fkc * 128 + frow * 8);
            #pragma unroll
            for (int i = 0; i < 4; ++i)
                #pragma unroll
                for (int j = 0; j < 4; ++j)
                    acc[i][j] = __builtin_amdgcn_mfma_f32_16x16x32_bf16(
                        af[i], bfr[j], acc[i][j], 0, 0, 0);
        }
    }

    const int zh = bn >= DINNER;
    float* C = z ? (zh ? Cz1 : Cx1) : (zh ? Cz0 : Cx0);
    const int cb = zh ? DINNER : 0;
    const int orow0 = bm + wr * 64 + (lane >> 4) * 4;
    const int ocol0 = bn + wc * 64 + (lane & 15) - cb;
    #pragma unroll
    for (int j = 0; j < 4; ++j) {
        const int col = ocol0 + j * 16;
        #pragma unroll
        for (int i = 0; i < 4; ++i)
            #pragma unroll
            for (int r = 0; r < 4; ++r)
                C[(size_t)(orow0 + i * 16 + r) * DINNER + col] = acc[i][j][r];
    }
}

// ---------------------------------------------------------------------------
// Split-K batched MFMA GEMM (BK=64) -> fp32 partials part[z][M*ldc].
// z = dir*NSPLIT + sp. (K/NSPLIT) % 64 == 0 required.
// ---------------------------------------------------------------------------
template<int NSPLIT>
__global__ __launch_bounds__(256) void gemm_mfma_splitk(
    int M, int N, int K,
    const unsigned short* __restrict__ A0, const unsigned short* __restrict__ A1, int lda,
    const unsigned short* __restrict__ B0, const unsigned short* __restrict__ B1, int ldb,
    float* __restrict__ part, int ldc)
{
    __shared__ unsigned short As[2][128 * 32];
    __shared__ unsigned short Bs[2][128 * 32];
    const int z = blockIdx.z;
    const int dir = z / NSPLIT, sp = z % NSPLIT;
    const unsigned short* A = dir ? A1 : A0;
    const unsigned short* B = dir ? B1 : B0;
    float* Cp = part + (size_t)z * M * ldc;
    const int kbeg = sp * (K / NSPLIT);
    const int kend = kbeg + (K / NSPLIT);
    const int tid  = threadIdx.x;
    const int wave = tid >> 6;
    const int lane = tid & 63;
    const int bm = blockIdx.y * 128;
    const int bn = blockIdx.x * 128;

    const int strow = lane & 15;
    const int stkc  = lane >> 4;
    const int wr = wave >> 1, wc = wave & 1;
    const int frow = lane & 15;
    const int fkc  = lane >> 4;

    floatx4 acc[4][4];
    #pragma unroll
    for (int i = 0; i < 4; ++i)
        #pragma unroll
        for (int j = 0; j < 4; ++j)
            acc[i][j] = (floatx4){0.f, 0.f, 0.f, 0.f};

    for (int k0 = kbeg; k0 < kend; k0 += 64) {
        __syncthreads();
        #pragma unroll
        for (int hh = 0; hh < 2; ++hh) {
            #pragma unroll
            for (int q = 0; q < 2; ++q) {
                int g = wave * 2 + q;
                GLOAD_LDS16(A + (size_t)(bm + g * 16 + strow) * lda + k0 + hh * 32 + stkc * 8,
                            As[hh] + g * 512);
            }
            #pragma unroll
            for (int q = 0; q < 2; ++q) {
                int g = wave * 2 + q;
                GLOAD_LDS16(B + (size_t)(bn + g * 16 + strow) * ldb + k0 + hh * 32 + stkc * 8,
                            Bs[hh] + g * 512);
            }
        }
        __syncthreads();

        #pragma unroll
        for (int hh = 0; hh < 2; ++hh) {
            bf16x8 af[4], bfr[4];
            #pragma unroll
            for (int i = 0; i < 4; ++i)
                af[i] = *(const bf16x8*)(As[hh] + (wr * 4 + i) * 512 + fkc * 128 + frow * 8);
            #pragma unroll
            for (int j = 0; j < 4; ++j)
                bfr[j] = *(const bf16x8*)(Bs[hh] + (wc * 4 + j) * 512 + fkc * 128 + frow * 8);
            #pragma unroll
            for (int i = 0; i < 4; ++i)
                #pragma unroll
                for (int j = 0; j < 4; ++j)
                    acc[i][j] = __builtin_amdgcn_mfma_f32_16x16x32_bf16(
                        af[i], bfr[j], acc[i][j], 0, 0, 0);
        }
    }

    const int orow0 = bm + wr * 64 + (lane >> 4) * 4;
    const int ocol0 = bn + wc * 64 + (lane & 15);
    #pragma unroll
    for (int j = 0; j < 4; ++j) {
        const int col = ocol0 + j * 16;
        #pragma unroll
        for (int i = 0; i < 4; ++i)
            #pragma unroll
            for (int r = 0; r < 4; ++r)
                Cp[(size_t)(orow0 + i * 16 + r) * ldc + col] = acc[i][j][r];
    }
}

// ---------------------------------------------------------------------------
// xproj split-K MFMA (BK=64): tile 128(m) x 64(n), K slice 256.
// blockIdx.y = dir*4 + sp.
// ---------------------------------------------------------------------------
__global__ __launch_bounds__(256) void xproj_splitk_kernel(
    const unsigned short* __restrict__ A_f, const unsigned short* __restrict__ A_b,
    const unsigned short* __restrict__ Wf,  const unsigned short* __restrict__ Wb,
    float* __restrict__ part)
{
    __shared__ unsigned short As[2][128 * 32];
    __shared__ unsigned short Bs[2][64 * 32];
    const int tid = threadIdx.x, wave = tid >> 6, lane = tid & 63;
    const int bm = blockIdx.x * 128;
    const int dir = blockIdx.y >> 2, sp = blockIdx.y & 3;
    const unsigned short* A = dir ? A_b : A_f;
    const unsigned short* W = dir ? Wb  : Wf;
    float* Cp = part + (size_t)blockIdx.y * MM * 64;
    const int kbeg = sp * 256, kend = kbeg + 256;

    const int strow = lane & 15;
    const int stkc  = lane >> 4;
    const int frow = lane & 15;
    const int fkc  = lane >> 4;

    floatx4 acc[2][4];
    #pragma unroll
    for (int i = 0; i < 2; ++i)
        #pragma unroll
        for (int j = 0; j < 4; ++j)
            acc[i][j] = (floatx4){0.f, 0.f, 0.f, 0.f};

    for (int k0 = kbeg; k0 < kend; k0 += 64) {
        __syncthreads();
        #pragma unroll
        for (int hh = 0; hh < 2; ++hh) {
            #pragma unroll
            for (int q = 0; q < 2; ++q) {
                int g = wave * 2 + q;
                GLOAD_LDS16(A + (size_t)(bm + g * 16 + strow) * DINNER + k0 + hh * 32 + stkc * 8,
                            As[hh] + g * 512);
            }
            GLOAD_LDS16(W + (size_t)(wave * 16 + strow) * DINNER + k0 + hh * 32 + stkc * 8,
                        Bs[hh] + wave * 512);
        }
        __syncthreads();

        #pragma unroll
        for (int hh = 0; hh < 2; ++hh) {
            bf16x8 af[2], bfr[4];
            #pragma unroll
            for (int i = 0; i < 2; ++i)
                af[i] = *(const bf16x8*)(As[hh] + (wave * 2 + i) * 512 + fkc * 128 + frow * 8);
            #pragma unroll
            for (int j = 0; j < 4; ++j)
                bfr[j] = *(const bf16x8*)(Bs[hh] + j * 512 + fkc * 128 + frow * 8);
            #pragma unroll
            for (int i = 0; i < 2; ++i)
                #pragma unroll
                for (int j = 0; j < 4; ++j)
                    acc[i][j] = __builtin_amdgcn_mfma_f32_16x16x32_bf16(
                        af[i], bfr[j], acc[i][j], 0, 0, 0);
        }
    }

    const int orow0 = bm + wave * 32 + (lane >> 4) * 4;
    #pragma unroll
    for (int j = 0; j < 4; ++j) {
        const int col = (lane & 15) + j * 16;
        #pragma unroll
        for (int i = 0; i < 2; ++i)
            #pragma unroll
            for (int r = 0; r < 4; ++r)
                Cp[(size_t)(orow0 + i * 16 + r) * 64 + col] = acc[i][j][r];
    }
}

// ---------------------------------------------------------------------------
// xproj reduce: cols 0..31 -> dbc[m][32] (dt rows); cols 32..63 -> bct[m][32].
// ---------------------------------------------------------------------------
__global__ __launch_bounds__(256) void xproj_reduce_kernel(
    const float* __restrict__ part,
    float* __restrict__ dbc_f, float* __restrict__ dbc_b,
    float* __restrict__ bct_f, float* __restrict__ bct_b)
{
    const int dir = blockIdx.y;
    const int i = (blockIdx.x * 256 + threadIdx.x) * 4;
    const float* p = part + (size_t)dir * 4 * (MM * 64);
    float4 a = *(const float4*)(p + i);
    #pragma unroll
    for (int s = 1; s < 4; ++s) {
        float4 t = *(const float4*)(p + (size_t)s * (MM * 64) + i);
        a.x += t.x; a.y += t.y; a.z += t.z; a.w += t.w;
    }
    const int m = i >> 6, c = i & 63;
    if (c < 32) {
        float* dbc = dir ? dbc_b : dbc_f;
        *(float4*)(dbc + (size_t)m * 32 + c) = a;
    } else {
        float* bct = dir ? bct_b : bct_f;
        *(float4*)(bct + (size_t)m * 32 + (c - 32)) = a;
    }
}

// ---------------------------------------------------------------------------
// Batched fp32 GEMM w/ softplus + row bias (dt-proj), bf16 output.
// ---------------------------------------------------------------------------
__global__ __launch_bounds__(256) void dtproj_batch_kernel(
    int M, int N, int K,
    const float* __restrict__ A0, const float* __restrict__ A1, int lda,
    const float* __restrict__ B0, const float* __restrict__ B1, int ldb,
    const float* __restrict__ bias0, const float* __restrict__ bias1,
    unsigned short* __restrict__ C0, unsigned short* __restrict__ C1, int ldc)
{
    __shared__ float As[16][64];
    __shared__ float Bs[16][64];
    const int z = blockIdx.z;
    const float* A = z ? A1 : A0;
    const float* B = z ? B1 : B0;
    const float* biasR = z ? bias1 : bias0;
    unsigned short* C = z ? C1 : C0;
    const int tid = threadIdx.x;
    const int tx = tid & 15, ty = tid >> 4;
    const int bm = blockIdx.y * 64, bn = blockIdx.x * 64;
    const int lm = tid & 63;
    const int lk = (tid >> 6) * 4;
    const float* Arow = A + (size_t)(bm + lm) * lda + lk;
    const float* Brow = B + (size_t)(bn + lm) * ldb + lk;
    float acc[4][4] = {};
    for (int k0 = 0; k0 < K; k0 += 16) {
        float4 av = *(const float4*)(Arow + k0);
        float4 bv = *(const float4*)(Brow + k0);
        __syncthreads();
        As[lk+0][lm] = av.x; As[lk+1][lm] = av.y; As[lk+2][lm] = av.z; As[lk+3][lm] = av.w;
        Bs[lk+0][lm] = bv.x; Bs[lk+1][lm] = bv.y; Bs[lk+2][lm] = bv.z; Bs[lk+3][lm] = bv.w;
        __syncthreads();
        #pragma unroll
        for (int k = 0; k < 16; ++k) {
            float4 a = *(const float4*)(&As[k][ty*4]);
            float4 b = *(const float4*)(&Bs[k][tx*4]);
            float ar[4] = {a.x,a.y,a.z,a.w};
            float br[4] = {b.x,b.y,b.z,b.w};
            #pragma unroll
            for (int i = 0; i < 4; ++i)
                #pragma unroll
                for (int j = 0; j < 4; ++j)
                    acc[i][j] = fmaf(ar[i], br[j], acc[i][j]);
        }
    }
    const int row0 = bm + ty*4, col0 = bn + tx*4;
    #pragma unroll
    for (int i = 0; i < 4; ++i) {
        float br = biasR[row0 + i];
        ushort4v o;
        #pragma unroll
        for (int j = 0; j < 4; ++j) {
            float t = acc[i][j] + br;
            o[j] = f2bf(fmaxf(t, 0.f) + log1pf(__expf(-fabsf(t))));
        }
        *(ushort4v*)(C + (size_t)(row0 + i) * ldc + col0) = o;
    }
}

// ---------------------------------------------------------------------------
// Segmented casts: 5 pre-GEMM arrays -> one contiguous bf16 block.
// ---------------------------------------------------------------------------
__global__ __launch_bounds__(256) void cast_pre_kernel(
    const float* __restrict__ x, const float* __restrict__ w0,
    const float* __restrict__ w1, const float* __restrict__ xp0,
    const float* __restrict__ xp1, unsigned short* __restrict__ dst)
{
    int i = (blockIdx.x * 256 + threadIdx.x) * 8;
    const float* src; int off;
    if      (i < 1048576) { src = x;   off = 0; }
    else if (i < 2097152) { src = w0;  off = 1048576; }
    else if (i < 3145728) { src = w1;  off = 2097152; }
    else if (i < 3211264) { src = xp0; off = 3145728; }
    else                  { src = xp1; off = 3211264; }
    float4 a = *(const float4*)(src + i - off);
    float4 b = *(const float4*)(src + i - off + 4);
    ushort8v o;
    o[0] = f2bf(a.x); o[1] = f2bf(a.y); o[2] = f2bf(a.z); o[3] = f2bf(a.w);
    o[4] = f2bf(b.x); o[5] = f2bf(b.y); o[6] = f2bf(b.z); o[7] = f2bf(b.w);
    *(ushort8v*)(dst + i) = o;
}

// Segments: outW_f(524288) outW_b(524288) W1(1048576) W2(1048576)
__global__ __launch_bounds__(256) void cast_post_kernel(
    const float* __restrict__ w0, const float* __restrict__ w1,
    const float* __restrict__ w2, const float* __restrict__ w3,
    unsigned short* __restrict__ dst)
{
    int i = (blockIdx.x * 256 + threadIdx.x) * 8;
    const float* src; int off;
    if      (i < 524288)  { src = w0; off = 0; }
    else if (i < 1048576) { src = w1; off = 524288; }
    else if (i < 2097152) { src = w2; off = 1048576; }
    else                  { src = w3; off = 2097152; }
    float4 a = *(const float4*)(src + i - off);
    float4 b = *(const float4*)(src + i - off + 4);
    ushort8v o;
    o[0] = f2bf(a.x); o[1] = f2bf(a.y); o[2] = f2bf(a.z); o[3] = f2bf(a.w);
    o[4] = f2bf(b.x); o[5] = f2bf(b.y); o[6] = f2bf(b.z); o[7] = f2bf(b.w);
    *(ushort8v*)(dst + i) = o;
}

// ---------------------------------------------------------------------------
// Fused depthwise conv + bias + silu + transpose: writes xm[m][d] (bf16) and
// xmT[d][m] (bf16) in one pass. 32x32 tile, blockIdx.z = dir.
// ---------------------------------------------------------------------------
__global__ __launch_bounds__(256) void conv_silu_tr_kernel(
    const float* __restrict__ x_f, const float* __restrict__ x_b,
    const float* __restrict__ Wf,  const float* __restrict__ Wb,
    const float* __restrict__ cbf, const float* __restrict__ cbb,
    unsigned short* __restrict__ of,  unsigned short* __restrict__ ob,
    unsigned short* __restrict__ otf, unsigned short* __restrict__ otb)
{
    __shared__ unsigned short t[32][34];
    const int dir = blockIdx.z;
    const float* xo = dir ? x_b : x_f;
    const float* convW = dir ? Wb : Wf;
    const float* convb = dir ? cbb : cbf;
    unsigned short* xm  = dir ? ob : of;
    unsigned short* xmT = dir ? otb : otf;
    const int m0 = blockIdx.x * 32, d0 = blockIdx.y * 32;
    const int tx = threadIdx.x & 31, ty = threadIdx.x >> 5;
    const int d = d0 + tx;
    float4 wv = *(const float4*)(convW + d * 4);
    float w[4] = {wv.x, wv.y, wv.z, wv.w};
    const float cb = convb[d];
    #pragma unroll
    for (int rr = 0; rr < 32; rr += 8) {
        int m = m0 + ty + rr;
        int b = m >> 10, l = m & (SEQ - 1);
        float acc = cb;
        #pragma unroll
        for (int j = 0; j < 4; ++j) {
            int p = dir ? (l + 3 - j) : (l - 3 + j);
            if (p >= 0 && p < SEQ)
                acc = fmaf(xo[(size_t)(b * SEQ + p) * DINNER + d], w[j], acc);
        }
        float sig = 1.f / (1.f + __expf(-acc));
        unsigned short v = f2bf(acc * sig);
        xm[(size_t)m * DINNER + d] = v;
        t[ty + rr][tx] = v;
    }
    __syncthreads();
    #pragma unroll
    for (int rr = 0; rr < 32; rr += 8)
        xmT[(size_t)(d0 + ty + rr) * MM + m0 + tx] = t[tx][ty + rr];
}

// ---------------------------------------------------------------------------
// Scan pass 1: local scan from zero state, 4 states per thread.
// lane = d_local*4 + state_quad; states sq*4..sq*4+3; quadsum4 for the
// cross-state reduce. Emits y0 (bf16, incl. D*x), running cumdl (fp32,
// sq==0 lane), chunk P = exp(A*sum dl) and H (float4 stores).
// Block 256 = 64 channels. Grid (DINNER/64, BATCH*NCHUNK, 2).
// ---------------------------------------------------------------------------
template<int DIR>
__device__ __forceinline__ void pass1_body(
    const unsigned short* __restrict__ deltaT, const unsigned short* __restrict__ xmT,
    const float* __restrict__ bct, const float* __restrict__ Alog,
    const float* __restrict__ Dv,
    unsigned short* __restrict__ y0T, float* __restrict__ cumT,
    float* __restrict__ Pout, float* __restrict__ Hout)
{
    const int tid = threadIdx.x;
    const int sq = tid & 3;
    const int dloc = tid >> 2;        // 0..63
    const int d = blockIdx.x * 64 + dloc;
    const int b = blockIdx.y / NCHUNK;
    const int c = blockIdx.y % NCHUNK;

    float4 Av = *(const float4*)(Alog + d * DSTATE + sq * 4);
    const float A0 = -__expf(Av.x), A1 = -__expf(Av.y);
    const float A2 = -__expf(Av.z), A3 = -__expf(Av.w);
    const float Dp = Dv[d];
    const unsigned short* dRow = deltaT + (size_t)d * MM + b * SEQ;
    const unsigned short* xRow = xmT + (size_t)d * MM + b * SEQ;
    const float* bcRow = bct + (size_t)(b * SEQ) * 32 + sq * 4;
    unsigned short* yRow = y0T + (size_t)d * MM + b * SEQ;
    float* uRow = cumT + (size_t)d * MM + b * SEQ;

    float h0 = 0.f, h1 = 0.f, h2 = 0.f, h3 = 0.f, sdl = 0.f;
    const int segBase = DIR ? (SEQ - CHUNK - c * CHUNK) : (c * CHUNK);
    for (int ii = 0; ii < CHUNK; ii += 8) {
        const int off = DIR ? (segBase + (CHUNK - 8) - ii) : (segBase + ii);
        ushort8v dl8 = *(const ushort8v*)(dRow + off);
        ushort8v x8  = *(const ushort8v*)(xRow + off);
        float yv[8], cu[8];
        #pragma unroll
        for (int u = 0; u < 8; ++u) {
            const int t = DIR ? (7 - u) : u;
            float4 Bv = *(const float4*)(bcRow + (size_t)(off + t) * 32);
            float4 Cv = *(const float4*)(bcRow + (size_t)(off + t) * 32 + 16);
            float dlv = bf2f(dl8[t]);
            float xv  = bf2f(x8[t]);
            sdl += dlv;
            float dx = dlv * xv;
            h0 = fmaf(__expf(dlv * A0), h0, dx * Bv.x);
            h1 = fmaf(__expf(dlv * A1), h1, dx * Bv.y);
            h2 = fmaf(__expf(dlv * A2), h2, dx * Bv.z);
            h3 = fmaf(__expf(dlv * A3), h3, dx * Bv.w);
            float part = h0 * Cv.x + h1 * Cv.y + h2 * Cv.z + h3 * Cv.w;
            part = quadsum4(part);
            yv[t] = fmaf(xv, Dp, part);
            cu[t] = sdl;
        }
        if (sq == 0) {
            ushort8v y8;
            #pragma unroll
            for (int u = 0; u < 8; ++u) y8[u] = f2bf(yv[u]);
            *(ushort8v*)(yRow + off) = y8;
            *(float4*)(uRow + off)     = (float4){cu[0], cu[1], cu[2], cu[3]};
            *(float4*)(uRow + off + 4) = (float4){cu[4], cu[5], cu[6], cu[7]};
        }
    }
    const size_t g4 = ((size_t)(DIR * BATCH + b) * DINNER + d) * DSTATE + sq * 4;
    *(float4*)(Pout + (size_t)c * GTOT + g4) =
        (float4){__expf(sdl * A0), __expf(sdl * A1), __expf(sdl * A2), __expf(sdl * A3)};
    *(float4*)(Hout + (size_t)c * GTOT + g4) = (float4){h0, h1, h2, h3};
}

__global__ __launch_bounds__(256) void scan_pass1_kernel(
    const unsigned short* __restrict__ dT_f, const unsigned short* __restrict__ dT_b,
    const unsigned short* __restrict__ xT_f, const unsigned short* __restrict__ xT_b,
    const float* __restrict__ bct_f, const float* __restrict__ bct_b,
    const float* __restrict__ Alog_f, const float* __restrict__ Alog_b,
    const float* __restrict__ D_f, const float* __restrict__ D_b,
    unsigned short* __restrict__ y0T_f, unsigned short* __restrict__ y0T_b,
    float* __restrict__ cumT_f, float* __restrict__ cumT_b,
    float* __restrict__ Pout, float* __restrict__ Hout)
{
    if (blockIdx.z == 0)
        pass1_body<0>(dT_f, xT_f, bct_f, Alog_f, D_f, y0T_f, cumT_f, Pout, Hout);
    else
        pass1_body<1>(dT_b, xT_b, bct_b, Alog_b, D_b, y0T_b, cumT_b, Pout, Hout);
}

// ---------------------------------------------------------------------------
// Phase 2: sequential combine over chunks. Preloads all P/H first so the
// 16 loads issue independently (1 round trip, not 16).
// ---------------------------------------------------------------------------
__global__ __launch_bounds__(256) void scan_carry_kernel(
    const float* __restrict__ P, const float* __restrict__ H,
    float* __restrict__ carry)
{
    const int g = blockIdx.x * 256 + threadIdx.x;
    float p[NCHUNK], hh[NCHUNK];
    #pragma unroll
    for (int c = 0; c < NCHUNK; ++c) {
        p[c]  = P[(size_t)c * GTOT + g];
        hh[c] = H[(size_t)c * GTOT + g];
    }
    float h = 0.f;
    #pragma unroll
    for (int c = 0; c < NCHUNK; ++c) {
        carry[(size_t)c * GTOT + g] = h;
        h = fmaf(p[c], h, hh[c]);
    }
}

// ---------------------------------------------------------------------------
// Correction pass (fully parallel):
//   y[m,d] = y0[m,d] + sum_s C[m,s]*carry[d,s]*exp(A[d,s]*cumdl[m,d])
// then *= silu(z), transpose -> ybf[m][d]. blockIdx.z = dir.
// ---------------------------------------------------------------------------
__global__ __launch_bounds__(256) void scan_correct_kernel(
    const unsigned short* __restrict__ y0T_f, const unsigned short* __restrict__ y0T_b,
    const float* __restrict__ cumT_f, const float* __restrict__ cumT_b,
    const float* __restrict__ bct_f, const float* __restrict__ bct_b,
    const float* __restrict__ Alog_f, const float* __restrict__ Alog_b,
    const float* __restrict__ carry,
    const float* __restrict__ z_f, const float* __restrict__ z_b,
    unsigned short* __restrict__ ybf_f, unsigned short* __restrict__ ybf_b)
{
    __shared__ float Cs[16][33];   // C[s][m-local]
    __shared__ float Asm[32][16];  // A per (d-local, s)
    __shared__ float Cy[32][16];   // carry per (d-local, s)
    __shared__ float t[32][33];    // transpose buffer

    const int dir = blockIdx.z;
    const unsigned short* y0T = dir ? y0T_b : y0T_f;
    const float* cumT = dir ? cumT_b : cumT_f;
    const float* bct  = dir ? bct_b  : bct_f;
    const float* Alog = dir ? Alog_b : Alog_f;
    const float* zon  = dir ? z_b    : z_f;
    unsigned short* ybf = dir ? ybf_b : ybf_f;

    const int m0 = blockIdx.x * 32, d0 = blockIdx.y * 32;
    const int b = m0 >> 10;
    const int l0 = m0 & (SEQ - 1);
    const int c = dir ? ((SEQ - 1 - l0) >> 6) : (l0 >> 6);

    for (int idx = threadIdx.x; idx < 512; idx += 256) {
        int s1 = idx & 15, ml = idx >> 4;
        Cs[s1][ml] = bct[(size_t)(m0 + ml) * 32 + 16 + s1];
        int dl2 = idx >> 4, s2 = idx & 15;
        Asm[dl2][s2] = -__expf(Alog[(d0 + dl2) * DSTATE + s2]);
        Cy[dl2][s2] = carry[(size_t)c * GTOT
            + ((size_t)(dir * BATCH + b) * DINNER + d0 + dl2) * DSTATE + s2];
    }
    __syncthreads();

    const int tx = threadIdx.x & 31, ty = threadIdx.x >> 5;
    #pragma unroll
    for (int rr = 0; rr < 32; rr += 8) {
        const int dloc = ty + rr;
        const size_t base = (size_t)(d0 + dloc) * MM + m0 + tx;
        float u  = cumT[base];
        float y0 = bf2f(y0T[base]);
        float corr = 0.f;
        #pragma unroll
        for (int s = 0; s < DSTATE; ++s)
            corr = fmaf(Cs[s][tx] * Cy[dloc][s], __expf(Asm[dloc][s] * u), corr);
        t[dloc][tx] = y0 + corr;
    }
    __syncthreads();
    #pragma unroll
    for (int rr = 0; rr < 32; rr += 8) {
        int m = m0 + ty + rr, d = d0 + tx;
        float z = zon[(size_t)m * DINNER + d];
        float sig = 1.f / (1.f + __expf(-z));
        ybf[(size_t)m * DINNER + d] = f2bf(t[tx][ty + rr] * (z * sig));
    }
}

// ---------------------------------------------------------------------------
// Fused split-K reduce + dual LN -> bf16.
// ---------------------------------------------------------------------------
__global__ __launch_bounds__(256) void ln_combine_fused_kernel(
    const float* __restrict__ xf, const float* __restrict__ part,
    const float* __restrict__ g1, const float* __restrict__ b1,
    const float* __restrict__ g2, const float* __restrict__ b2,
    unsigned short* __restrict__ out)
{
    const int m = blockIdx.x;
    const int tid = threadIdx.x;
    const float* xr = xf + (size_t)m * DMODEL;
    const float* p0 = part + (size_t)m * DMODEL;
    const float* p1 = p0 + (size_t)MM * DMODEL;
    const float* p2 = p1 + (size_t)MM * DMODEL;
    const float* p3 = p2 + (size_t)MM * DMODEL;
    float v1a = xr[tid]       + p0[tid]       + p1[tid];
    float v1b = xr[tid + 256] + p0[tid + 256] + p1[tid + 256];
    float v2a = xr[tid]       + p2[tid]       + p3[tid];
    float v2b = xr[tid + 256] + p2[tid + 256] + p3[tid + 256];
    float s1 = v1a + v1b, q1 = v1a*v1a + v1b*v1b;
    float s2 = v2a + v2b, q2 = v2a*v2a + v2b*v2b;
    #pragma unroll
    for (int off = 32; off; off >>= 1) {
        s1 += __shfl_xor(s1, off); q1 += __shfl_xor(q1, off);
        s2 += __shfl_xor(s2, off); q2 += __shfl_xor(q2, off);
    }
    __shared__ float sm[4][4];
    const int w = tid >> 6;
    if ((tid & 63) == 0) { sm[w][0] = s1; sm[w][1] = q1; sm[w][2] = s2; sm[w][3] = q2; }
    __syncthreads();
    s1 = sm[0][0] + sm[1][0] + sm[2][0] + sm[3][0];
    q1 = sm[0][1] + sm[1][1] + sm[2][1] + sm[3][1];
    s2 = sm[0][2] + sm[1][2] + sm[2][2] + sm[3][2];
    q2 = sm[0][3] + sm[1][3] + sm[2][3] + sm[3][3];
    const float inv = 1.f / DMODEL;
    float mu1 = s1 * inv, mu2 = s2 * inv;
    float rs1 = rsqrtf(q1 * inv - mu1 * mu1 + 1e-5f);
    float rs2 = rsqrtf(q2 * inv - mu2 * mu2 + 1e-5f);
    unsigned short* orow = out + (size_t)m * DMODEL;
    orow[tid]       = f2bf((v1a - mu1) * rs1 * g1[tid]       + b1[tid]
                         + (v2a - mu2) * rs2 * g2[tid]       + b2[tid]);
    orow[tid + 256] = f2bf((v1b - mu1) * rs1 * g1[tid + 256] + b1[tid + 256]
                         + (v2b - mu2) * rs2 * g2[tid + 256] + b2[tid + 256]);
}

// ---------------------------------------------------------------------------
// Fused FF2 split-K4 reduce + bias + LN(2*ff).
// ---------------------------------------------------------------------------
__global__ __launch_bounds__(256) void ln_final_fused_kernel(
    const float* __restrict__ part, const float* __restrict__ bias,
    const float* __restrict__ g, const float* __restrict__ b,
    float* __restrict__ out)
{
    const int m = blockIdx.x;
    const int tid = threadIdx.x;
    const size_t stride = (size_t)MM * DMODEL;
    const float* p = part + (size_t)m * DMODEL;
    float fa = bias[tid]       + p[tid]       + p[stride + tid]
             + p[2*stride + tid]       + p[3*stride + tid];
    float fb = bias[tid + 256] + p[tid + 256] + p[stride + tid + 256]
             + p[2*stride + tid + 256] + p[3*stride + tid + 256];
    float va = 2.f * fa, vb = 2.f * fb;
    float s = va + vb, q = va*va + vb*vb;
    #pragma unroll
    for (int off = 32; off; off >>= 1) {
        s += __shfl_xor(s, off); q += __shfl_xor(q, off);
    }
    __shared__ float sm[4][2];
    const int w = tid >> 6;
    if ((tid & 63) == 0) { sm[w][0] = s; sm[w][1] = q; }
    __syncthreads();
    s = sm[0][0] + sm[1][0] + sm[2][0] + sm[3][0];
    q = sm[0][1] + sm[1][1] + sm[2][1] + sm[3][1];
    const float inv = 1.f / DMODEL;
    float mu = s * inv;
    float rs = rsqrtf(q * inv - mu * mu + 1e-5f);
    float* orow = out + (size_t)m * DMODEL;
    orow[tid]       = (va - mu) * rs * g[tid]       + b[tid];
    orow[tid + 256] = (vb - mu) * rs * g[tid + 256] + b[tid + 256];
}

// ---------------------------------------------------------------------------
extern "C" void kernel_launch(void* const* d_in, const int* in_sizes, int n_in,
                              void* d_out, int out_size, void* d_ws, size_t ws_size,
                              hipStream_t stream)
{
    const float* x         = (const float*)d_in[0];
    const float* fm_in_W   = (const float*)d_in[1];
    const float* fm_conv_W = (const float*)d_in[2];
    const float* fm_conv_b = (const float*)d_in[3];
    const float* fm_xproj_W= (const float*)d_in[4];
    const float* fm_dt_W   = (const float*)d_in[5];
    const float* fm_dt_b   = (const float*)d_in[6];
    const float* fm_A_log  = (const float*)d_in[7];
    const float* fm_D      = (const float*)d_in[8];
    const float* fm_out_W  = (const float*)d_in[9];
    const float* bm_in_W   = (const float*)d_in[10];
    const float* bm_conv_W = (const float*)d_in[11];
    const float* bm_conv_b = (const float*)d_in[12];
    const float* bm_xproj_W= (const float*)d_in[13];
    const float* bm_dt_W   = (const float*)d_in[14];
    const float* bm_dt_b   = (const float*)d_in[15];
    const float* bm_A_log  = (const float*)d_in[16];
    const float* bm_D      = (const float*)d_in[17];
    const float* bm_out_W  = (const float*)d_in[18];
    const float* ln1_g     = (const float*)d_in[19];
    const float* ln1_b     = (const float*)d_in[20];
    const float* ln2_g     = (const float*)d_in[21];
    const float* ln2_b     = (const float*)d_in[22];
    const float* ln3_g     = (const float*)d_in[23];
    const float* ln3_b     = (const float*)d_in[24];
    const float* ff_W1     = (const float*)d_in[25];
    const float* ff_b1     = (const float*)d_in[26];
    const float* ff_W2     = (const float*)d_in[27];
    const float* ff_b2     = (const float*)d_in[28];
    float* out = (float*)d_out;

    // ---- Workspace layout (floats; total 23,330,816 fl = 93.3 MB) ----
    float* ws = (float*)d_ws;
    size_t o = 0;
    float* xonly_f = ws + o; o += (size_t)MM * DINNER;     // 2,097,152
    float* xonly_b = ws + o; o += (size_t)MM * DINNER;
    float* zonly_f = ws + o; o += (size_t)MM * DINNER;
    float* zonly_b = ws + o; o += (size_t)MM * DINNER;
    unsigned short* xm_bf_f = (unsigned short*)(ws + o); o += (size_t)MM * DINNER / 2;
    unsigned short* xm_bf_b = (unsigned short*)(ws + o); o += (size_t)MM * DINNER / 2;
    unsigned short* xmT_f   = (unsigned short*)(ws + o); o += (size_t)MM * DINNER / 2;
    unsigned short* xmT_b   = (unsigned short*)(ws + o); o += (size_t)MM * DINNER / 2;
    unsigned short* deltaT_f= (unsigned short*)(ws + o); o += (size_t)MM * DINNER / 2;
    unsigned short* deltaT_b= (unsigned short*)(ws + o); o += (size_t)MM * DINNER / 2;
    float* dbc_f    = ws + o; o += (size_t)MM * 32;        // 65,536
    float* dbc_b    = ws + o; o += (size_t)MM * 32;
    float* bct_f    = ws + o; o += (size_t)MM * 32;
    float* bct_b    = ws + o; o += (size_t)MM * 32;
    unsigned short* y0T_f = (unsigned short*)(ws + o); o += (size_t)MM * DINNER / 2;
    unsigned short* y0T_b = (unsigned short*)(ws + o); o += (size_t)MM * DINNER / 2;
    float* scanP    = ws + o; o += (size_t)NCHUNK * (GTOT / 16) * 16;  // 1,048,576
    float* scanH    = ws + o; o += (size_t)NCHUNK * (GTOT / 16) * 16;
    float* scanCy   = ws + o; o += (size_t)NCHUNK * (GTOT / 16) * 16;
    float* gpart    = ws + o; o += (size_t)4 * MM * DMODEL;            // 4,194,304

    // ---- Overlays ----
    float* cumT_f = xonly_f;   // xonly dead after conv
    float* cumT_b = xonly_b;
    unsigned short* x_bf       = (unsigned short*)scanP;   // dead until pass1
    unsigned short* fm_inW_bf  = x_bf + 1048576;
    unsigned short* bm_inW_bf  = fm_inW_bf + 1048576;
    unsigned short* fm_xpW_bf  = bm_inW_bf + 1048576;
    unsigned short* bm_xpW_bf  = fm_xpW_bf + 65536;
    unsigned short* ybf_f = (unsigned short*)scanP;        // P/H dead after carry
    unsigned short* ybf_b = (unsigned short*)scanH;
    unsigned short* fm_outW_bf = (unsigned short*)zonly_f; // zonly dead after correct
    unsigned short* bm_outW_bf = fm_outW_bf + 524288;
    unsigned short* W1_bf      = bm_outW_bf + 524288;
    unsigned short* W2_bf      = W1_bf + 1048576;
    unsigned short* outsum_bf  = (unsigned short*)xonly_b; // cumT_b dead after correct
    unsigned short* h_bf = (unsigned short*)deltaT_f;      // deltaT dead after pass1

    // ---- 0. pre-GEMM casts ----
    cast_pre_kernel<<<3276800 / 2048, 256, 0, stream>>>(
        x, fm_in_W, bm_in_W, fm_xproj_W, bm_xproj_W, x_bf);

    // ---- 1. in-proj GEMMs, split x/z outputs, both dirs (512 blocks) ----
    gemm_inproj_kernel<<<dim3(2048/128, MM/128, 2), 256, 0, stream>>>(
        x_bf, fm_inW_bf, bm_inW_bf, xonly_f, zonly_f, xonly_b, zonly_b);

    // ---- 2. fused conv + silu + transpose -> xm[m][d], xmT[d][m] ----
    conv_silu_tr_kernel<<<dim3(MM/32, DINNER/32, 2), 256, 0, stream>>>(
        xonly_f, xonly_b, fm_conv_W, bm_conv_W, fm_conv_b, bm_conv_b,
        xm_bf_f, xm_bf_b, xmT_f, xmT_b);

    // ---- 3. x-proj: split-K x4, both dirs + reduce -> dbc[m][32], bct[m][32] ----
    xproj_splitk_kernel<<<dim3(MM/128, 8), 256, 0, stream>>>(
        xm_bf_f, xm_bf_b, fm_xpW_bf, bm_xpW_bf, gpart);
    xproj_reduce_kernel<<<dim3((MM*64)/1024, 2), 256, 0, stream>>>(
        gpart, dbc_f, dbc_b, bct_f, bct_b);

    // ---- 4. dt-proj, both dirs -> deltaT bf16 [d][m], softplus ----
    dtproj_batch_kernel<<<dim3(MM/64, DINNER/64, 2), 256, 0, stream>>>(
        DINNER, MM, DTRANK, fm_dt_W, bm_dt_W, DTRANK, dbc_f, dbc_b, 32,
        fm_dt_b, bm_dt_b, deltaT_f, deltaT_b, MM);

    // ---- 5. scan: pass1 (4 states/thread) + carry + parallel correction ----
    scan_pass1_kernel<<<dim3(DINNER/64, BATCH*NCHUNK, 2), 256, 0, stream>>>(
        deltaT_f, deltaT_b, xmT_f, xmT_b, bct_f, bct_b,
        fm_A_log, bm_A_log, fm_D, bm_D,
        y0T_f, y0T_b, cumT_f, cumT_b, scanP, scanH);
    scan_carry_kernel<<<GTOT/256, 256, 0, stream>>>(scanP, scanH, scanCy);
    scan_correct_kernel<<<dim3(MM/32, DINNER/32, 2), 256, 0, stream>>>(
        y0T_f, y0T_b, cumT_f, cumT_b, bct_f, bct_b, fm_A_log, bm_A_log,
        scanCy, zonly_f, zonly_b, ybf_f, ybf_b);

    // ---- 6. post weight casts (zonly dead) ----
    cast_post_kernel<<<3145728 / 2048, 256, 0, stream>>>(
        fm_out_W, bm_out_W, ff_W1, ff_W2, fm_outW_bf);

    // ---- 7. out-proj: dirs x splitK2 (256 blocks) -> gpart ----
    gemm_mfma_splitk<2><<<dim3(DMODEL/128, MM/128, 4), 256, 0, stream>>>(
        MM, DMODEL, DINNER, ybf_f, ybf_b, DINNER, fm_outW_bf, bm_outW_bf, DINNER,
        gpart, DMODEL);

    // ---- 8. fused reduce + dual LN -> bf16 outsum ----
    ln_combine_fused_kernel<<<MM, 256, 0, stream>>>(
        x, gpart, ln1_g, ln1_b, ln2_g, ln2_b, outsum_bf);

    // ---- 9. FF1 (256 blocks) ----
    gemm_mfma_batch<1,1><<<dim3(DFF/128, MM/128, 1), 256, 0, stream>>>(
        MM, DFF, DMODEL, outsum_bf, outsum_bf, DMODEL, W1_bf, W1_bf, DMODEL,
        ff_b1, h_bf, h_bf, DFF);

    // ---- 10. FF2: splitK4 (256 blocks) -> gpart ----
    gemm_mfma_splitk<4><<<dim3(DMODEL/128, MM/128, 4), 256, 0, stream>>>(
        MM, DMODEL, DFF, h_bf, h_bf, DFF, W2_bf, W2_bf, DFF, gpart, DMODEL);

    // ---- 11. fused reduce + bias + final LN(2*ff) ----
    ln_final_fused_kernel<<<MM, 256, 0, stream>>>(
        gpart, ff_b2, ln3_g, ln3_b, out);
}